// Round 10
// baseline (713.829 us; speedup 1.0000x reference)
//
#include <hip/hip_runtime.h>
#include <hip/hip_bf16.h>
#include <math.h>

using bf16 = __hip_bfloat16;
typedef __attribute__((ext_vector_type(4))) float f32x4;
typedef __attribute__((ext_vector_type(8))) short s16x8;

#define MFMA16(a,b,c) __builtin_amdgcn_mfma_f32_16x16x32_bf16((a),(b),(c),0,0,0)

// ---------------------------------------------------------------------------
// VQ-VAE forward. B=128, L=4096, H=128, RH=64, D=64, K=512.
// Channel-last bf16. Row-fragment wave split: each wave owns a 16-row frag
// and computes ALL channels (weights from L1/L2, 4x fewer LDS reads).
// ---------------------------------------------------------------------------

__device__ inline float bf2f(unsigned short u) {
    union { float f; unsigned v; } c; c.v = ((unsigned)u) << 16; return c.f;
}
__device__ inline unsigned short bfbits(float f) {
    union { bf16 h; unsigned short u; } c; c.h = __float2bfloat16(f); return c.u;
}
__device__ inline s16x8 relu8(s16x8 v) {
#pragma unroll
    for (int j = 0; j < 8; ++j)
        v[j] = (short)(((unsigned short)v[j] & 0x8000u) ? 0 : (unsigned short)v[j]);
    return v;
}
__device__ inline uint2 pack4(float a, float b, float c, float d) {
    uint2 p;
    p.x = (unsigned)bfbits(a) | ((unsigned)bfbits(b) << 16);
    p.y = (unsigned)bfbits(c) | ((unsigned)bfbits(d) << 16);
    return p;
}

// ===========================================================================
// encmid: enc3 (128->128 K3) + res1 + res2 + final relu.  Bbf -> Abf.
// sY 80x272B @0; sX 96x272B @21760; sH 80x144B aliases sX.
// ===========================================================================
__global__ __launch_bounds__(256, 3) void encmid_k(
    const bf16* __restrict__ in, const bf16* __restrict__ w3t,
    const float* __restrict__ b3, const bf16* __restrict__ r1w1,
    const bf16* __restrict__ r1w2, const bf16* __restrict__ r2w1,
    const bf16* __restrict__ r2w2, bf16* __restrict__ out)
{
    __shared__ __align__(16) char smem[47872];
    char* sY = smem;
    char* sX = smem + 21760;
    char* sH = smem + 21760;
    const int tid = threadIdx.x;
    const int b   = blockIdx.y;
    const int l0  = blockIdx.x * 64;
    const bf16* inb = in + (size_t)b * 1024 * 128;

    for (int i = tid; i < 96 * 16; i += 256) {
        int t = i >> 4, c0 = (i & 15) * 8;
        int g = l0 - 16 + t;
        s16x8 v = {};
        if (g >= 0 && g < 1024) v = *(const s16x8*)(inb + (size_t)g * 128 + c0);
        *(s16x8*)(sX + ((t * 136 + c0) << 1)) = v;
    }
    __syncthreads();

    const int lane = tid & 63;
    const int wid  = __builtin_amdgcn_readfirstlane(tid >> 6);
    const int lr   = lane & 15;
    const int kg   = lane >> 4;
    const f32x4 zf4 = {0.f, 0.f, 0.f, 0.f};

    // ---- phase 1: enc3 (CIN=128, CO=128). own frag rows wid*16+lr; frag4
    // rows 64+lr with cf in {2wid, 2wid+1}. ----
    {
        f32x4 accO[8], acc4[2];
#pragma unroll
        for (int cf = 0; cf < 8; ++cf) accO[cf] = zf4;
        acc4[0] = zf4; acc4[1] = zf4;
#pragma unroll
        for (int k = 0; k < 3; ++k) {
            const bf16* Ab = w3t + (size_t)k * 128 * 128;
#pragma unroll
            for (int ks = 0; ks < 4; ++ks) {
                const int cc = ks * 32 + kg * 8;
                s16x8 af[8];
#pragma unroll
                for (int cf = 0; cf < 8; ++cf)
                    af[cf] = *(const s16x8*)(Ab + (cf * 16 + lr) * 128 + cc);
                s16x8 a40 = *(const s16x8*)(Ab + ((wid * 2 + 0) * 16 + lr) * 128 + cc);
                s16x8 a41 = *(const s16x8*)(Ab + ((wid * 2 + 1) * 16 + lr) * 128 + cc);
                s16x8 b0 = *(const s16x8*)(sX + (((wid * 16 + lr + 7 + k) * 136 + cc) << 1));
                s16x8 b4 = *(const s16x8*)(sX + (((64 + lr + 7 + k) * 136 + cc) << 1));
#pragma unroll
                for (int cf = 0; cf < 8; ++cf)
                    accO[cf] = MFMA16(af[cf], b0, accO[cf]);
                acc4[0] = MFMA16(a40, b4, acc4[0]);
                acc4[1] = MFMA16(a41, b4, acc4[1]);
            }
        }
        {
            int row = wid * 16 + lr;
            int p   = l0 - 8 + row;
            bool ok = (p >= 0 && p < 1024);
#pragma unroll
            for (int cf = 0; cf < 8; ++cf) {
                int ch0 = cf * 16 + kg * 4;
                float r[4];
#pragma unroll
                for (int j = 0; j < 4; ++j)
                    r[j] = ok ? (accO[cf][j] + b3[ch0 + j]) : 0.f;
                *(uint2*)(sY + ((row * 136 + ch0) << 1)) = pack4(r[0], r[1], r[2], r[3]);
            }
            int row4 = 64 + lr;
            bool ok4 = (l0 - 8 + row4 < 1024);
#pragma unroll
            for (int c2 = 0; c2 < 2; ++c2) {
                int ch0 = (wid * 2 + c2) * 16 + kg * 4;
                float r[4];
#pragma unroll
                for (int j = 0; j < 4; ++j)
                    r[j] = ok4 ? (acc4[c2][j] + b3[ch0 + j]) : 0.f;
                *(uint2*)(sY + ((row4 * 136 + ch0) << 1)) = pack4(r[0], r[1], r[2], r[3]);
            }
        }
    }
    __syncthreads();

    // ---- res blocks ----
#pragma unroll 1
    for (int blk2 = 0; blk2 < 2; ++blk2) {
        const bf16* w1 = blk2 ? r2w1 : r1w1;
        const bf16* w2 = blk2 ? r2w2 : r1w2;
        // stage1: H = relu(w1 (x) relu(Y)), CIN=128, CO=64
        {
            f32x4 accO[4], acc4;
#pragma unroll
            for (int cf = 0; cf < 4; ++cf) accO[cf] = zf4;
            acc4 = zf4;
#pragma unroll
            for (int k = 0; k < 3; ++k) {
                const bf16* Ab = w1 + (size_t)k * 64 * 128;
#pragma unroll
                for (int ks = 0; ks < 4; ++ks) {
                    const int cc = ks * 32 + kg * 8;
                    s16x8 af[4];
#pragma unroll
                    for (int cf = 0; cf < 4; ++cf)
                        af[cf] = *(const s16x8*)(Ab + (cf * 16 + lr) * 128 + cc);
                    s16x8 a4 = *(const s16x8*)(Ab + (wid * 16 + lr) * 128 + cc);
                    int ry0 = wid * 16 + lr + k - 1;
                    ry0 = (ry0 < 0) ? 0 : (ry0 > 79 ? 79 : ry0);
                    int ry4 = 64 + lr + k - 1;
                    ry4 = (ry4 > 79) ? 79 : ry4;
                    s16x8 b0 = relu8(*(const s16x8*)(sY + ((ry0 * 136 + cc) << 1)));
                    s16x8 b4 = relu8(*(const s16x8*)(sY + ((ry4 * 136 + cc) << 1)));
#pragma unroll
                    for (int cf = 0; cf < 4; ++cf)
                        accO[cf] = MFMA16(af[cf], b0, accO[cf]);
                    acc4 = MFMA16(a4, b4, acc4);
                }
            }
            int row = wid * 16 + lr;
#pragma unroll
            for (int cf = 0; cf < 4; ++cf) {
                int ch0 = cf * 16 + kg * 4;
                *(uint2*)(sH + ((row * 72 + ch0) << 1)) =
                    pack4(fmaxf(accO[cf][0], 0.f), fmaxf(accO[cf][1], 0.f),
                          fmaxf(accO[cf][2], 0.f), fmaxf(accO[cf][3], 0.f));
            }
            int row4 = 64 + lr;
            int ch4 = wid * 16 + kg * 4;
            *(uint2*)(sH + ((row4 * 72 + ch4) << 1)) =
                pack4(fmaxf(acc4[0], 0.f), fmaxf(acc4[1], 0.f),
                      fmaxf(acc4[2], 0.f), fmaxf(acc4[3], 0.f));
        }
        __syncthreads();

        if (blk2 == 0) {
            // stage2: Y += w2*H on all 80 rows
            f32x4 accO[8], acc4[2];
#pragma unroll
            for (int cf = 0; cf < 8; ++cf) accO[cf] = zf4;
            acc4[0] = zf4; acc4[1] = zf4;
#pragma unroll
            for (int ks = 0; ks < 2; ++ks) {
                const int cc = ks * 32 + kg * 8;
                s16x8 af[8];
#pragma unroll
                for (int cf = 0; cf < 8; ++cf)
                    af[cf] = *(const s16x8*)(w2 + (size_t)(cf * 16 + lr) * 64 + cc);
                s16x8 a40 = *(const s16x8*)(w2 + (size_t)((wid * 2 + 0) * 16 + lr) * 64 + cc);
                s16x8 a41 = *(const s16x8*)(w2 + (size_t)((wid * 2 + 1) * 16 + lr) * 64 + cc);
                s16x8 b0 = *(const s16x8*)(sH + (((wid * 16 + lr) * 72 + cc) << 1));
                s16x8 b4 = *(const s16x8*)(sH + (((64 + lr) * 72 + cc) << 1));
#pragma unroll
                for (int cf = 0; cf < 8; ++cf)
                    accO[cf] = MFMA16(af[cf], b0, accO[cf]);
                acc4[0] = MFMA16(a40, b4, acc4[0]);
                acc4[1] = MFMA16(a41, b4, acc4[1]);
            }
            int row = wid * 16 + lr;
            bool ok = (l0 - 8 + row >= 0 && l0 - 8 + row < 1024);
#pragma unroll
            for (int cf = 0; cf < 8; ++cf) {
                int ch0 = cf * 16 + kg * 4;
                uint2 old = *(const uint2*)(sY + ((row * 136 + ch0) << 1));
                float r0 = accO[cf][0] + bf2f((unsigned short)(old.x & 0xffff));
                float r1 = accO[cf][1] + bf2f((unsigned short)(old.x >> 16));
                float r2 = accO[cf][2] + bf2f((unsigned short)(old.y & 0xffff));
                float r3 = accO[cf][3] + bf2f((unsigned short)(old.y >> 16));
                uint2 pk = pack4(r0, r1, r2, r3);
                if (!ok) { pk.x = 0u; pk.y = 0u; }
                *(uint2*)(sY + ((row * 136 + ch0) << 1)) = pk;
            }
            int row4 = 64 + lr;
            bool ok4 = (l0 - 8 + row4 < 1024);
#pragma unroll
            for (int c2 = 0; c2 < 2; ++c2) {
                int ch0 = (wid * 2 + c2) * 16 + kg * 4;
                uint2 old = *(const uint2*)(sY + ((row4 * 136 + ch0) << 1));
                float r0 = acc4[c2][0] + bf2f((unsigned short)(old.x & 0xffff));
                float r1 = acc4[c2][1] + bf2f((unsigned short)(old.x >> 16));
                float r2 = acc4[c2][2] + bf2f((unsigned short)(old.y & 0xffff));
                float r3 = acc4[c2][3] + bf2f((unsigned short)(old.y >> 16));
                uint2 pk = pack4(r0, r1, r2, r3);
                if (!ok4) { pk.x = 0u; pk.y = 0u; }
                *(uint2*)(sY + ((row4 * 136 + ch0) << 1)) = pk;
            }
            __syncthreads();
        } else {
            // final: out = relu(Y + w2*H) rows 8..71 (frag per wave), CO=128
            f32x4 acc[8];
#pragma unroll
            for (int cf = 0; cf < 8; ++cf) acc[cf] = zf4;
#pragma unroll
            for (int ks = 0; ks < 2; ++ks) {
                const int cc = ks * 32 + kg * 8;
                s16x8 af[8];
#pragma unroll
                for (int cf = 0; cf < 8; ++cf)
                    af[cf] = *(const s16x8*)(w2 + (size_t)(cf * 16 + lr) * 64 + cc);
                s16x8 b0 = *(const s16x8*)(sH + (((8 + wid * 16 + lr) * 72 + cc) << 1));
#pragma unroll
                for (int cf = 0; cf < 8; ++cf)
                    acc[cf] = MFMA16(af[cf], b0, acc[cf]);
            }
            int row = 8 + wid * 16 + lr;
#pragma unroll
            for (int cf = 0; cf < 8; ++cf) {
                int ch0 = cf * 16 + kg * 4;
                uint2 old = *(const uint2*)(sY + ((row * 136 + ch0) << 1));
                float r0 = fmaxf(acc[cf][0] + bf2f((unsigned short)(old.x & 0xffff)), 0.f);
                float r1 = fmaxf(acc[cf][1] + bf2f((unsigned short)(old.x >> 16)), 0.f);
                float r2 = fmaxf(acc[cf][2] + bf2f((unsigned short)(old.y & 0xffff)), 0.f);
                float r3 = fmaxf(acc[cf][3] + bf2f((unsigned short)(old.y >> 16)), 0.f);
                *(uint2*)(out + ((size_t)b * 1024 + l0 + wid * 16 + lr) * 128 + ch0) =
                    pack4(r0, r1, r2, r3);
            }
        }
    }
}

// ===========================================================================
// decmid: dec1 + res1 + res2(+relu) + ct1 convT (LDS-bounced stores).
// sY 80x272B @0; sQ 96x144B @21760; sH aliases sQ. Total 35584B.
// ===========================================================================
__global__ __launch_bounds__(256, 4) void decmid_k(
    const bf16* __restrict__ qin, const bf16* __restrict__ dw1,
    const float* __restrict__ db1, const bf16* __restrict__ r1w1,
    const bf16* __restrict__ r1w2, const bf16* __restrict__ r2w1,
    const bf16* __restrict__ r2w2, const bf16* __restrict__ ct1w,
    const float* __restrict__ ct1b, bf16* __restrict__ out)
{
    __shared__ __align__(16) char smem[35584];
    char* sY = smem;
    char* sQ = smem + 21760;
    char* sH = smem + 21760;
    const int tid = threadIdx.x;
    const int b   = blockIdx.y;
    const int l0  = blockIdx.x * 64;
    const bf16* inb = qin + (size_t)b * 1024 * 64;

    for (int i = tid; i < 96 * 8; i += 256) {
        int t = i >> 3, c0 = (i & 7) * 8;
        int g = l0 - 16 + t;
        s16x8 v = {};
        if (g >= 0 && g < 1024) v = *(const s16x8*)(inb + (size_t)g * 64 + c0);
        *(s16x8*)(sQ + ((t * 72 + c0) << 1)) = v;
    }
    __syncthreads();

    const int lane = tid & 63;
    const int wid  = __builtin_amdgcn_readfirstlane(tid >> 6);
    const int lr   = lane & 15;
    const int kg   = lane >> 4;
    const f32x4 zf4 = {0.f, 0.f, 0.f, 0.f};

    // ---- phase 1: dec1 (CIN=64, CO=128) ----
    {
        f32x4 accO[8], acc4[2];
#pragma unroll
        for (int cf = 0; cf < 8; ++cf) accO[cf] = zf4;
        acc4[0] = zf4; acc4[1] = zf4;
#pragma unroll
        for (int k = 0; k < 3; ++k) {
            const bf16* Ab = dw1 + (size_t)k * 128 * 64;
#pragma unroll
            for (int ks = 0; ks < 2; ++ks) {
                const int cc = ks * 32 + kg * 8;
                s16x8 af[8];
#pragma unroll
                for (int cf = 0; cf < 8; ++cf)
                    af[cf] = *(const s16x8*)(Ab + (cf * 16 + lr) * 64 + cc);
                s16x8 a40 = *(const s16x8*)(Ab + ((wid * 2 + 0) * 16 + lr) * 64 + cc);
                s16x8 a41 = *(const s16x8*)(Ab + ((wid * 2 + 1) * 16 + lr) * 64 + cc);
                s16x8 b0 = *(const s16x8*)(sQ + (((wid * 16 + lr + 7 + k) * 72 + cc) << 1));
                s16x8 b4 = *(const s16x8*)(sQ + (((64 + lr + 7 + k) * 72 + cc) << 1));
#pragma unroll
                for (int cf = 0; cf < 8; ++cf)
                    accO[cf] = MFMA16(af[cf], b0, accO[cf]);
                acc4[0] = MFMA16(a40, b4, acc4[0]);
                acc4[1] = MFMA16(a41, b4, acc4[1]);
            }
        }
        int row = wid * 16 + lr;
        bool ok = (l0 - 8 + row >= 0 && l0 - 8 + row < 1024);
#pragma unroll
        for (int cf = 0; cf < 8; ++cf) {
            int ch0 = cf * 16 + kg * 4;
            float r[4];
#pragma unroll
            for (int j = 0; j < 4; ++j)
                r[j] = ok ? (accO[cf][j] + db1[ch0 + j]) : 0.f;
            *(uint2*)(sY + ((row * 136 + ch0) << 1)) = pack4(r[0], r[1], r[2], r[3]);
        }
        int row4 = 64 + lr;
        bool ok4 = (l0 - 8 + row4 < 1024);
#pragma unroll
        for (int c2 = 0; c2 < 2; ++c2) {
            int ch0 = (wid * 2 + c2) * 16 + kg * 4;
            float r[4];
#pragma unroll
            for (int j = 0; j < 4; ++j)
                r[j] = ok4 ? (acc4[c2][j] + db1[ch0 + j]) : 0.f;
            *(uint2*)(sY + ((row4 * 136 + ch0) << 1)) = pack4(r[0], r[1], r[2], r[3]);
        }
    }
    __syncthreads();

    // ---- res blocks (identical structure to encmid) ----
#pragma unroll 1
    for (int blk2 = 0; blk2 < 2; ++blk2) {
        const bf16* w1 = blk2 ? r2w1 : r1w1;
        const bf16* w2 = blk2 ? r2w2 : r1w2;
        {
            f32x4 accO[4], acc4;
#pragma unroll
            for (int cf = 0; cf < 4; ++cf) accO[cf] = zf4;
            acc4 = zf4;
#pragma unroll
            for (int k = 0; k < 3; ++k) {
                const bf16* Ab = w1 + (size_t)k * 64 * 128;
#pragma unroll
                for (int ks = 0; ks < 4; ++ks) {
                    const int cc = ks * 32 + kg * 8;
                    s16x8 af[4];
#pragma unroll
                    for (int cf = 0; cf < 4; ++cf)
                        af[cf] = *(const s16x8*)(Ab + (cf * 16 + lr) * 128 + cc);
                    s16x8 a4 = *(const s16x8*)(Ab + (wid * 16 + lr) * 128 + cc);
                    int ry0 = wid * 16 + lr + k - 1;
                    ry0 = (ry0 < 0) ? 0 : (ry0 > 79 ? 79 : ry0);
                    int ry4 = 64 + lr + k - 1;
                    ry4 = (ry4 > 79) ? 79 : ry4;
                    s16x8 b0 = relu8(*(const s16x8*)(sY + ((ry0 * 136 + cc) << 1)));
                    s16x8 b4 = relu8(*(const s16x8*)(sY + ((ry4 * 136 + cc) << 1)));
#pragma unroll
                    for (int cf = 0; cf < 4; ++cf)
                        accO[cf] = MFMA16(af[cf], b0, accO[cf]);
                    acc4 = MFMA16(a4, b4, acc4);
                }
            }
            int row = wid * 16 + lr;
#pragma unroll
            for (int cf = 0; cf < 4; ++cf) {
                int ch0 = cf * 16 + kg * 4;
                *(uint2*)(sH + ((row * 72 + ch0) << 1)) =
                    pack4(fmaxf(accO[cf][0], 0.f), fmaxf(accO[cf][1], 0.f),
                          fmaxf(accO[cf][2], 0.f), fmaxf(accO[cf][3], 0.f));
            }
            int row4 = 64 + lr;
            int ch4 = wid * 16 + kg * 4;
            *(uint2*)(sH + ((row4 * 72 + ch4) << 1)) =
                pack4(fmaxf(acc4[0], 0.f), fmaxf(acc4[1], 0.f),
                      fmaxf(acc4[2], 0.f), fmaxf(acc4[3], 0.f));
        }
        __syncthreads();
        {
            f32x4 accO[8], acc4[2];
#pragma unroll
            for (int cf = 0; cf < 8; ++cf) accO[cf] = zf4;
            acc4[0] = zf4; acc4[1] = zf4;
#pragma unroll
            for (int ks = 0; ks < 2; ++ks) {
                const int cc = ks * 32 + kg * 8;
                s16x8 af[8];
#pragma unroll
                for (int cf = 0; cf < 8; ++cf)
                    af[cf] = *(const s16x8*)(w2 + (size_t)(cf * 16 + lr) * 64 + cc);
                s16x8 a40 = *(const s16x8*)(w2 + (size_t)((wid * 2 + 0) * 16 + lr) * 64 + cc);
                s16x8 a41 = *(const s16x8*)(w2 + (size_t)((wid * 2 + 1) * 16 + lr) * 64 + cc);
                s16x8 b0 = *(const s16x8*)(sH + (((wid * 16 + lr) * 72 + cc) << 1));
                s16x8 b4 = *(const s16x8*)(sH + (((64 + lr) * 72 + cc) << 1));
#pragma unroll
                for (int cf = 0; cf < 8; ++cf)
                    accO[cf] = MFMA16(af[cf], b0, accO[cf]);
                acc4[0] = MFMA16(a40, b4, acc4[0]);
                acc4[1] = MFMA16(a41, b4, acc4[1]);
            }
            int row = wid * 16 + lr;
            bool ok = (l0 - 8 + row >= 0 && l0 - 8 + row < 1024);
#pragma unroll
            for (int cf = 0; cf < 8; ++cf) {
                int ch0 = cf * 16 + kg * 4;
                uint2 old = *(const uint2*)(sY + ((row * 136 + ch0) << 1));
                float r0 = accO[cf][0] + bf2f((unsigned short)(old.x & 0xffff));
                float r1 = accO[cf][1] + bf2f((unsigned short)(old.x >> 16));
                float r2 = accO[cf][2] + bf2f((unsigned short)(old.y & 0xffff));
                float r3 = accO[cf][3] + bf2f((unsigned short)(old.y >> 16));
                if (blk2 == 1) {
                    r0 = fmaxf(r0, 0.f); r1 = fmaxf(r1, 0.f);
                    r2 = fmaxf(r2, 0.f); r3 = fmaxf(r3, 0.f);
                }
                uint2 pk = pack4(r0, r1, r2, r3);
                if (!ok) { pk.x = 0u; pk.y = 0u; }
                *(uint2*)(sY + ((row * 136 + ch0) << 1)) = pk;
            }
            int row4 = 64 + lr;
            bool ok4 = (l0 - 8 + row4 < 1024);
#pragma unroll
            for (int c2 = 0; c2 < 2; ++c2) {
                int ch0 = (wid * 2 + c2) * 16 + kg * 4;
                uint2 old = *(const uint2*)(sY + ((row4 * 136 + ch0) << 1));
                float r0 = acc4[c2][0] + bf2f((unsigned short)(old.x & 0xffff));
                float r1 = acc4[c2][1] + bf2f((unsigned short)(old.x >> 16));
                float r2 = acc4[c2][2] + bf2f((unsigned short)(old.y & 0xffff));
                float r3 = acc4[c2][3] + bf2f((unsigned short)(old.y >> 16));
                if (blk2 == 1) {
                    r0 = fmaxf(r0, 0.f); r1 = fmaxf(r1, 0.f);
                    r2 = fmaxf(r2, 0.f); r3 = fmaxf(r3, 0.f);
                }
                uint2 pk = pack4(r0, r1, r2, r3);
                if (!ok4) { pk.x = 0u; pk.y = 0u; }
                *(uint2*)(sY + ((row4 * 136 + ch0) << 1)) = pk;
            }
        }
        __syncthreads();
    }

    // ---- ct1 convT (CO=64): wave owns m-frag wid (m = wid*16+lr) ----
    {
        f32x4 acc[2][4];
#pragma unroll
        for (int g = 0; g < 2; ++g)
#pragma unroll
            for (int cf = 0; cf < 4; ++cf) acc[g][cf] = zf4;
#pragma unroll
        for (int g = 0; g < 2; ++g)
#pragma unroll
            for (int k = 0; k < 2; ++k) {
                const bf16* Ab = ct1w + (size_t)(g * 2 + k) * 64 * 128;
                const int doff = (g == 0) ? (k - 1) : k;
#pragma unroll
                for (int ks = 0; ks < 4; ++ks) {
                    const int cc = ks * 32 + kg * 8;
                    s16x8 af[4];
#pragma unroll
                    for (int cf = 0; cf < 4; ++cf)
                        af[cf] = *(const s16x8*)(Ab + (cf * 16 + lr) * 128 + cc);
                    int ty = 8 + wid * 16 + lr + doff;
                    s16x8 bfr = *(const s16x8*)(sY + ((ty * 136 + cc) << 1));
#pragma unroll
                    for (int cf = 0; cf < 4; ++cf)
                        acc[g][cf] = MFMA16(af[cf], bfr, acc[g][cf]);
                }
            }
        __syncthreads();   // all sY reads done before bounce overwrite

        // bounce: sY region becomes [128 rows][64ch] linear (16KB)
#pragma unroll
        for (int g = 0; g < 2; ++g)
#pragma unroll
            for (int cf = 0; cf < 4; ++cf) {
                int rr  = 2 * (wid * 16 + lr) + g;
                int ch0 = cf * 16 + kg * 4;
                float r[4];
#pragma unroll
                for (int j = 0; j < 4; ++j)
                    r[j] = fmaxf(acc[g][cf][j] + ct1b[ch0 + j], 0.f);
                *(uint2*)(sY + rr * 128 + ch0 * 2) = pack4(r[0], r[1], r[2], r[3]);
            }
        __syncthreads();

        bf16* ob = out + ((size_t)b * 2048 + 2 * l0) * 64;
        for (int i = tid; i < 1024; i += 256)
            *(s16x8*)(ob + i * 8) = *(const s16x8*)(sY + i * 16);
    }
}

// Fused enc1+enc2: x fp32 -> h1 (LDS, stride 72) -> enc2 GEMM -> bf16 relu.
__global__ __launch_bounds__(256) void enc12_k(
    const float* __restrict__ x, const float* __restrict__ w1,
    const float* __restrict__ b1, const bf16* __restrict__ w2t,
    const float* __restrict__ b2, bf16* __restrict__ out)
{
    __shared__ float sXf[268];
    __shared__ float sW1[256];
    __shared__ float sB1[64];
    __shared__ __align__(16) char sX[132 * 144];
    const int tid = threadIdx.x;
    const int b   = blockIdx.y;
    const int l0  = blockIdx.x * 64;
    const float* xb = x + (size_t)b * 4096;

    for (int i = tid; i < 266; i += 256) {
        int g = 4 * l0 - 3 + i;
        sXf[i] = (g >= 0 && g < 4096) ? xb[g] : 0.f;
    }
    if (tid < 256) sW1[tid] = w1[tid];
    if (tid < 64)  sB1[tid] = b1[tid];
    __syncthreads();

    for (int i = tid; i < 132 * 64; i += 256) {
        int t = i >> 6, c = i & 63;
        int p = (t < 66) ? 2 * (l0 + t) : 2 * (l0 + t - 66) - 1;
        float v = 0.f;
        if (p >= 0 && p < 2048) {
            int xi = 2 * p - 4 * l0 + 2;
            float a = sB1[c];
#pragma unroll
            for (int k = 0; k < 4; ++k) a = fmaf(sXf[xi + k], sW1[c * 4 + k], a);
            v = fmaxf(a, 0.f);
        }
        *(bf16*)(sX + ((t * 72 + c) << 1)) = __float2bfloat16(v);
    }
    __syncthreads();

    const int lane = tid & 63;
    const int wid  = __builtin_amdgcn_readfirstlane(tid >> 6);
    const int co0  = wid * 32;
    const int lr   = lane & 15;
    const int kg   = lane >> 4;

    f32x4 acc[2][4];
#pragma unroll
    for (int cf = 0; cf < 2; ++cf)
#pragma unroll
        for (int lf = 0; lf < 4; ++lf) acc[cf][lf] = (f32x4){0.f, 0.f, 0.f, 0.f};

#pragma unroll
    for (int k = 0; k < 4; ++k) {
        const int roff = (k == 0) ? 66 : (k == 1) ? 0 : (k == 2) ? 67 : 1;
        const bf16* Ab = w2t + (size_t)k * 128 * 64;
#pragma unroll
        for (int ks = 0; ks < 2; ++ks) {
            s16x8 af[2];
#pragma unroll
            for (int cf = 0; cf < 2; ++cf)
                af[cf] = *(const s16x8*)(Ab + (co0 + cf * 16 + lr) * 64 + ks * 32 + kg * 8);
            s16x8 bfr[4];
#pragma unroll
            for (int lf = 0; lf < 4; ++lf) {
                int t = roff + lf * 16 + lr;
                bfr[lf] = *(const s16x8*)(sX + ((t * 72 + ks * 32 + kg * 8) << 1));
            }
#pragma unroll
            for (int cf = 0; cf < 2; ++cf)
#pragma unroll
                for (int lf = 0; lf < 4; ++lf)
                    acc[cf][lf] = MFMA16(af[cf], bfr[lf], acc[cf][lf]);
        }
    }

#pragma unroll
    for (int cf = 0; cf < 2; ++cf)
#pragma unroll
        for (int lf = 0; lf < 4; ++lf) {
            int cb0  = co0 + cf * 16 + kg * 4;
            int lcol = lf * 16 + lr;
            float r[4];
#pragma unroll
            for (int j = 0; j < 4; ++j)
                r[j] = fmaxf(acc[cf][lf][j] + b2[cb0 + j], 0.f);
            *(uint2*)(out + ((size_t)b * 1024 + l0 + lcol) * 128 + cb0) =
                pack4(r[0], r[1], r[2], r[3]);
        }
}

// Final convT: 64->1 ch, x2 upsample; fp32 out.
__global__ __launch_bounds__(256) void ct2_k(
    const bf16* __restrict__ in, const float* __restrict__ w,
    const float* __restrict__ bias, float* __restrict__ out)
{
    __shared__ __align__(16) char sX[258 * 144];
    const int tid = threadIdx.x;
    const int b   = blockIdx.y;
    const int m0  = blockIdx.x * 256;
    const bf16* inb = in + (size_t)b * 2048 * 64;
    for (int i = tid; i < 258 * 8; i += 256) {
        int t = i >> 3, c0 = (i & 7) * 8;
        int g = m0 - 1 + t;
        s16x8 v = {};
        if (g >= 0 && g < 2048) v = *(const s16x8*)(inb + (size_t)g * 64 + c0);
        *(s16x8*)(sX + ((t * 72 + c0) << 1)) = v;
    }
    __syncthreads();
    float e = bias[0], o = bias[0];
#pragma unroll
    for (int c0 = 0; c0 < 64; c0 += 8) {
        s16x8 vm1 = *(const s16x8*)(sX + (((tid + 0) * 72 + c0) << 1));
        s16x8 v0  = *(const s16x8*)(sX + (((tid + 1) * 72 + c0) << 1));
        s16x8 vp1 = *(const s16x8*)(sX + (((tid + 2) * 72 + c0) << 1));
#pragma unroll
        for (int j = 0; j < 8; ++j) {
            int ci = c0 + j;
            float xm1 = bf2f((unsigned short)vm1[j]);
            float x0  = bf2f((unsigned short)v0[j]);
            float xp1 = bf2f((unsigned short)vp1[j]);
            e = fmaf(x0,  w[ci * 4 + 1], fmaf(xm1, w[ci * 4 + 3], e));
            o = fmaf(xp1, w[ci * 4 + 0], fmaf(x0,  w[ci * 4 + 2], o));
        }
    }
    int m = m0 + tid;
    out[(size_t)b * 4096 + 2 * m]     = e;
    out[(size_t)b * 4096 + 2 * m + 1] = o;
}

// Weight transform: fp32 conv weights -> bf16 [tap][co][ci] matrices.
__global__ __launch_bounds__(256) void wx_k(
    const float* ew2, const float* ew3, const float* er1a, const float* er1b,
    const float* er2a, const float* er2b, const float* pvw, const float* dw1,
    const float* dr1a, const float* dr1b, const float* dr2a, const float* dr2b,
    const float* ct1w, bf16* wb)
{
    const int job = blockIdx.x;
    bf16* dst = wb + (size_t)job * 65536;
    const float* src; int CO, CI, K;
    switch (job) {
        case 0:  src = ew2;  CO = 128; CI = 64;  K = 4; break;
        case 1:  src = ew3;  CO = 128; CI = 128; K = 3; break;
        case 2:  src = er1a; CO = 64;  CI = 128; K = 3; break;
        case 3:  src = er1b; CO = 128; CI = 64;  K = 1; break;
        case 4:  src = er2a; CO = 64;  CI = 128; K = 3; break;
        case 5:  src = er2b; CO = 128; CI = 64;  K = 1; break;
        case 6:  src = pvw;  CO = 64;  CI = 128; K = 1; break;
        case 7:  src = dw1;  CO = 128; CI = 64;  K = 3; break;
        case 8:  src = dr1a; CO = 64;  CI = 128; K = 3; break;
        case 9:  src = dr1b; CO = 128; CI = 64;  K = 1; break;
        case 10: src = dr2a; CO = 64;  CI = 128; K = 3; break;
        case 11: src = dr2b; CO = 128; CI = 64;  K = 1; break;
        default: src = ct1w; CO = 64;  CI = 128; K = 4; break;
    }
    const int tot = CO * CI * K;
    for (int i = blockIdx.y * 256 + threadIdx.x; i < tot; i += gridDim.y * 256) {
        if (job < 12) {
            int k = i / (CO * CI); int r = i - k * CO * CI;
            int co = r / CI; int ci = r - co * CI;
            dst[i] = __float2bfloat16(src[((size_t)co * CI + ci) * K + k]);
        } else {
            const int TAP[4] = {3, 1, 2, 0};
            int g = i / (64 * 128); int r = i - g * 64 * 128;
            int co = r / 128; int ci = r - co * 128;
            dst[i] = __float2bfloat16(src[((size_t)ci * 64 + co) * 4 + TAP[g]]);
        }
    }
}

// codebook prep: fp32 norms + hi/lo bf16 split
__global__ __launch_bounds__(256) void cbprep_k(
    const float* __restrict__ cb, bf16* __restrict__ cbh, bf16* __restrict__ cbl,
    float* __restrict__ sc)
{
    int k = blockIdx.x * 256 + threadIdx.x;
    const float* c = cb + (size_t)k * 64;
    float s = 0.f;
#pragma unroll
    for (int d = 0; d < 64; ++d) s = fmaf(c[d], c[d], s);
    sc[k] = s;
#pragma unroll
    for (int c0 = 0; c0 < 64; c0 += 8) {
        union { unsigned short u[8]; s16x8 v; } ph, pl;
#pragma unroll
        for (int j = 0; j < 8; ++j) {
            float v = c[c0 + j];
            unsigned short h = bfbits(v);
            ph.u[j] = h;
            pl.u[j] = bfbits(v - bf2f(h));
        }
        *(s16x8*)(cbh + (size_t)k * 64 + c0) = ph.v;
        *(s16x8*)(cbl + (size_t)k * 64 + c0) = pl.v;
    }
}

// Fused pre_vq + VQ. 1024 blocks x 128 positions. A tile / z tile alias.
__global__ __launch_bounds__(256, 4) void vqf_k(
    const bf16* __restrict__ A, const bf16* __restrict__ pvw,
    const float* __restrict__ pvb, const float* __restrict__ cbf,
    const bf16* __restrict__ cbh, const bf16* __restrict__ cbl,
    const float* __restrict__ sc, bf16* __restrict__ q,
    float* __restrict__ counts, float* __restrict__ loss_sum)
{
    __shared__ __align__(16) char sMem[34816];
    __shared__ float sSC[512];
    __shared__ float sHist[512];
    __shared__ int   sBK[128];
    __shared__ float sWS[4];
    const int tid = threadIdx.x;
    sSC[tid] = sc[tid]; sSC[tid + 256] = sc[tid + 256];
    sHist[tid] = 0.f;   sHist[tid + 256] = 0.f;

    const int n0 = blockIdx.x * 128;
    for (int i = tid; i < 128 * 16; i += 256) {
        int t = i >> 4, c0 = (i & 15) * 8;
        s16x8 v = *(const s16x8*)(A + (size_t)(n0 + t) * 128 + c0);
        *(s16x8*)(sMem + ((t * 136 + c0) << 1)) = v;
    }
    __syncthreads();

    const int lane = tid & 63, wid = tid >> 6;
    const int lr = lane & 15, kg = lane >> 4;
    const int pw0 = wid * 32;
    const f32x4 zf4 = {0.f, 0.f, 0.f, 0.f};

    f32x4 zacc[4][2];
#pragma unroll
    for (int cf = 0; cf < 4; ++cf)
#pragma unroll
        for (int lf = 0; lf < 2; ++lf) zacc[cf][lf] = zf4;
#pragma unroll
    for (int ks = 0; ks < 4; ++ks) {
        s16x8 af[4];
#pragma unroll
        for (int cf = 0; cf < 4; ++cf)
            af[cf] = *(const s16x8*)(pvw + (size_t)(cf * 16 + lr) * 128 + ks * 32 + kg * 8);
        s16x8 bfr[2];
#pragma unroll
        for (int lf = 0; lf < 2; ++lf) {
            int t = pw0 + lf * 16 + lr;
            bfr[lf] = *(const s16x8*)(sMem + ((t * 136 + ks * 32 + kg * 8) << 1));
        }
#pragma unroll
        for (int cf = 0; cf < 4; ++cf)
#pragma unroll
            for (int lf = 0; lf < 2; ++lf)
                zacc[cf][lf] = MFMA16(af[cf], bfr[lf], zacc[cf][lf]);
    }
    __syncthreads();

#pragma unroll
    for (int cf = 0; cf < 4; ++cf)
#pragma unroll
        for (int lf = 0; lf < 2; ++lf) {
            int pos = pw0 + lf * 16 + lr;
            int ch  = cf * 16 + kg * 4;
            float4 v = make_float4(zacc[cf][lf][0] + pvb[ch],
                                   zacc[cf][lf][1] + pvb[ch + 1],
                                   zacc[cf][lf][2] + pvb[ch + 2],
                                   zacc[cf][lf][3] + pvb[ch + 3]);
            *(float4*)(sMem + (pos * 68 + ch) * 4) = v;
        }
    __syncthreads();

    s16x8 bh[2][2], bl[2][2];
#pragma unroll
    for (int lf = 0; lf < 2; ++lf)
#pragma unroll
        for (int ks = 0; ks < 2; ++ks) {
            int t = pw0 + lf * 16 + lr;
            int ch = ks * 32 + kg * 8;
            float4 v0 = *(const float4*)(sMem + (t * 68 + ch) * 4);
            float4 v1 = *(const float4*)(sMem + (t * 68 + ch) * 4 + 16);
            float v[8] = {v0.x, v0.y, v0.z, v0.w, v1.x, v1.y, v1.z, v1.w};
            union { unsigned short u[8]; s16x8 s; } ph, pl;
#pragma unroll
            for (int j = 0; j < 8; ++j) {
                unsigned short h = bfbits(v[j]);
                ph.u[j] = h;
                pl.u[j] = bfbits(v[j] - bf2f(h));
            }
            bh[lf][ks] = ph.s; bl[lf][ks] = pl.s;
        }

    float bestd[2] = {3.4e38f, 3.4e38f};
    int   bestk[2] = {0, 0};
#pragma unroll 2
    for (int cf = 0; cf < 32; ++cf) {
        int code = cf * 16 + lr;
        const bf16* ph = cbh + code * 64 + kg * 8;
        const bf16* pl = cbl + code * 64 + kg * 8;
        s16x8 ah0 = *(const s16x8*)ph;
        s16x8 ah1 = *(const s16x8*)(ph + 32);
        s16x8 al0 = *(const s16x8*)pl;
        s16x8 al1 = *(const s16x8*)(pl + 32);
        float s0 = sSC[cf * 16 + kg * 4 + 0];
        float s1 = sSC[cf * 16 + kg * 4 + 1];
        float s2 = sSC[cf * 16 + kg * 4 + 2];
        float s3 = sSC[cf * 16 + kg * 4 + 3];
        int kb = cf * 16 + kg * 4;
#pragma unroll
        for (int lf = 0; lf < 2; ++lf) {
            f32x4 acc = MFMA16(ah0, bh[lf][0], zf4);
            acc = MFMA16(ah1, bh[lf][1], acc);
            acc = MFMA16(al0, bh[lf][0], acc);
            acc = MFMA16(al1, bh[lf][1], acc);
            acc = MFMA16(ah0, bl[lf][0], acc);
            acc = MFMA16(ah1, bl[lf][1], acc);
            float d0 = fmaf(acc[0], -2.f, s0);
            float d1 = fmaf(acc[1], -2.f, s1);
            float d2 = fmaf(acc[2], -2.f, s2);
            float d3 = fmaf(acc[3], -2.f, s3);
            if (d0 < bestd[lf]) { bestd[lf] = d0; bestk[lf] = kb; }
            if (d1 < bestd[lf]) { bestd[lf] = d1; bestk[lf] = kb + 1; }
            if (d2 < bestd[lf]) { bestd[lf] = d2; bestk[lf] = kb + 2; }
            if (d3 < bestd[lf]) { bestd[lf] = d3; bestk[lf] = kb + 3; }
        }
    }
#pragma unroll
    for (int lf = 0; lf < 2; ++lf) {
#pragma unroll
        for (int off = 16; off <= 32; off <<= 1) {
            float od = __shfl_xor(bestd[lf], off, 64);
            int   ok = __shfl_xor(bestk[lf], off, 64);
            if (od < bestd[lf] || (od == bestd[lf] && ok < bestk[lf])) {
                bestd[lf] = od; bestk[lf] = ok;
            }
        }
        if (kg == 0) sBK[pw0 + lf * 16 + lr] = bestk[lf];
    }
    __syncthreads();

    const int pos  = tid >> 1;
    const int half = tid & 1;
    const int k = sBK[pos];
    if (half == 0) atomicAdd(&sHist[k], 1.f);
    float lsum = 0.f;
    const float* qp = cbf + (size_t)k * 64 + half * 32;
    bf16* qo = q + (size_t)(n0 + pos) * 64 + half * 32;
#pragma unroll
    for (int c0 = 0; c0 < 32; c0 += 8) {
        int zb = (pos * 68 + half * 32 + c0) * 4;
        float4 z0 = *(const float4*)(sMem + zb);
        float4 z1 = *(const float4*)(sMem + zb + 16);
        float4 q0 = *(const float4*)(qp + c0);
        float4 q1 = *(const float4*)(qp + c0 + 4);
        float qv[8] = {q0.x, q0.y, q0.z, q0.w, q1.x, q1.y, q1.z, q1.w};
        float zv[8] = {z0.x, z0.y, z0.z, z0.w, z1.x, z1.y, z1.z, z1.w};
        union { unsigned short u[8]; s16x8 v; } pk;
#pragma unroll
        for (int j = 0; j < 8; ++j) {
            float d = qv[j] - zv[j];
            lsum = fmaf(d, d, lsum);
            pk.u[j] = bfbits(qv[j]);
        }
        *(s16x8*)(qo + c0) = pk.v;
    }
#pragma unroll
    for (int off = 32; off > 0; off >>= 1) lsum += __shfl_down(lsum, off, 64);
    if ((tid & 63) == 0) sWS[tid >> 6] = lsum;
    __syncthreads();
    if (tid == 0) atomicAdd(loss_sum, sWS[0] + sWS[1] + sWS[2] + sWS[3]);
    float c0v = sHist[tid];       if (c0v != 0.f) atomicAdd(&counts[tid], c0v);
    float c1v = sHist[tid + 256]; if (c1v != 0.f) atomicAdd(&counts[tid + 256], c1v);
}

__global__ __launch_bounds__(512) void finalize_k(
    const float* __restrict__ counts, const float* __restrict__ loss_sum,
    float* __restrict__ d_out, int out_size)
{
    __shared__ float ws2[8];
    const int tid = threadIdx.x;
    float p = counts[tid] * (1.f / 131072.f);
    float e = p * logf(p + 1e-10f);
#pragma unroll
    for (int off = 32; off > 0; off >>= 1) e += __shfl_down(e, off, 64);
    const int lane = tid & 63, wid = tid >> 6;
    if (lane == 0) ws2[wid] = e;
    __syncthreads();
    if (tid == 0) {
        float s = 0.f;
        for (int i = 0; i < 8; ++i) s += ws2[i];
        d_out[0] = 1.25f * loss_sum[0] * (1.f / 8388608.f);  // (1+BETA)*mean
        d_out[out_size - 1] = expf(-s);
    }
}

extern "C" void kernel_launch(void* const* d_in, const int* in_sizes, int n_in,
                              void* d_out, int out_size, void* d_ws, size_t ws_size,
                              hipStream_t stream)
{
    const float* x        = (const float*)d_in[0];
    const float* enc_w1   = (const float*)d_in[1];
    const float* enc_b1   = (const float*)d_in[2];
    const float* enc_b2   = (const float*)d_in[4];
    const float* enc_b3   = (const float*)d_in[6];
    const float* pre_vq_b = (const float*)d_in[12];
    const float* cb       = (const float*)d_in[13];
    const float* dec_b1   = (const float*)d_in[15];
    const float* ct1_b    = (const float*)d_in[21];
    const float* ct2_w    = (const float*)d_in[22];
    const float* ct2_b    = (const float*)d_in[23];
    float* out = (float*)d_out;

    char* base = (char*)d_ws;
    bf16*  wb   = (bf16*)base;
    bf16*  Abf  = (bf16*)(base + ((size_t)2   << 20));
    bf16*  Bbf  = (bf16*)(base + ((size_t)40  << 20));
    bf16*  Qbf  = (bf16*)(base + ((size_t)78  << 20));
    bf16*  cbh  = (bf16*)(base + ((size_t)96  << 20));
    bf16*  cbl  = (bf16*)(base + ((size_t)96  << 20) + 65536);
    float* sc   = (float*)(base + ((size_t)96  << 20) + 131072);
    float* cnt  = sc + 512;
    float* lsum = cnt + 512;

    (void)hipMemsetAsync(cnt, 0, 513 * sizeof(float), stream);

    dim3 blk(256);
    dim3 g16(16, 128);

    wx_k<<<dim3(13, 8), blk, 0, stream>>>(
        (const float*)d_in[3], (const float*)d_in[5], (const float*)d_in[7],
        (const float*)d_in[8], (const float*)d_in[9], (const float*)d_in[10],
        (const float*)d_in[11], (const float*)d_in[14], (const float*)d_in[16],
        (const float*)d_in[17], (const float*)d_in[18], (const float*)d_in[19],
        (const float*)d_in[20], wb);
    cbprep_k<<<2, blk, 0, stream>>>(cb, cbh, cbl, sc);

    enc12_k<<<g16, blk, 0, stream>>>(x, enc_w1, enc_b1, wb + 0 * 65536, enc_b2, Bbf);
    encmid_k<<<g16, blk, 0, stream>>>(Bbf, wb + 1 * 65536, enc_b3,
        wb + 2 * 65536, wb + 3 * 65536, wb + 4 * 65536, wb + 5 * 65536, Abf);

    vqf_k<<<1024, blk, 0, stream>>>(Abf, wb + 6 * 65536, pre_vq_b, cb,
                                    cbh, cbl, sc, Qbf, cnt, lsum);

    decmid_k<<<g16, blk, 0, stream>>>(Qbf, wb + 7 * 65536, dec_b1,
        wb + 8 * 65536, wb + 9 * 65536, wb + 10 * 65536, wb + 11 * 65536,
        wb + 12 * 65536, ct1_b, Bbf);

    ct2_k<<<dim3(8, 128), blk, 0, stream>>>(Bbf, ct2_w, ct2_b, out + 1);
    finalize_k<<<1, 512, 0, stream>>>(cnt, lsum, out, out_size);
}

// Round 11
// 450.909 us; speedup vs baseline: 1.5831x; 1.5831x over previous
//
#include <hip/hip_runtime.h>
#include <hip/hip_bf16.h>
#include <math.h>

using bf16 = __hip_bfloat16;
typedef __attribute__((ext_vector_type(4))) float f32x4;
typedef __attribute__((ext_vector_type(8))) short s16x8;

#define MFMA16(a,b,c) __builtin_amdgcn_mfma_f32_16x16x32_bf16((a),(b),(c),0,0,0)

// ---------------------------------------------------------------------------
// VQ-VAE forward. B=128, L=4096, H=128, RH=64, D=64, K=512.
// Channel-last bf16. 2x2 wave split (co-half x row-group) halves redundant
// LDS B-fragment reads; <=4 global weight loads per inner step.
// ---------------------------------------------------------------------------

__device__ inline float bf2f(unsigned short u) {
    union { float f; unsigned v; } c; c.v = ((unsigned)u) << 16; return c.f;
}
__device__ inline unsigned short bfbits(float f) {
    union { bf16 h; unsigned short u; } c; c.h = __float2bfloat16(f); return c.u;
}
__device__ inline s16x8 relu8(s16x8 v) {
#pragma unroll
    for (int j = 0; j < 8; ++j)
        v[j] = (short)(((unsigned short)v[j] & 0x8000u) ? 0 : (unsigned short)v[j]);
    return v;
}
__device__ inline uint2 pack4(float a, float b, float c, float d) {
    uint2 p;
    p.x = (unsigned)bfbits(a) | ((unsigned)bfbits(b) << 16);
    p.y = (unsigned)bfbits(c) | ((unsigned)bfbits(d) << 16);
    return p;
}

// ===========================================================================
// encmid: enc3 (128->128 K3) + res1 + res2 + final relu.  Bbf -> Abf.
// sY 80x272B @0; sX 96x272B @21760; sH 80x144B aliases sX.
// Waves: ci = wid&1 (channel half), rj = wid>>1 (row frags {0,1,2} | {3,4}).
// ===========================================================================
__global__ __launch_bounds__(256, 3) void encmid_k(
    const bf16* __restrict__ in, const bf16* __restrict__ w3t,
    const float* __restrict__ b3, const bf16* __restrict__ r1w1,
    const bf16* __restrict__ r1w2, const bf16* __restrict__ r2w1,
    const bf16* __restrict__ r2w2, bf16* __restrict__ out)
{
    __shared__ __align__(16) char smem[47872];
    char* sY = smem;
    char* sX = smem + 21760;
    char* sH = smem + 21760;
    const int tid = threadIdx.x;
    const int b   = blockIdx.y;
    const int l0  = blockIdx.x * 64;
    const bf16* inb = in + (size_t)b * 1024 * 128;

    for (int i = tid; i < 96 * 16; i += 256) {
        int t = i >> 4, c0 = (i & 15) * 8;
        int g = l0 - 16 + t;
        s16x8 v = {};
        if (g >= 0 && g < 1024) v = *(const s16x8*)(inb + (size_t)g * 128 + c0);
        *(s16x8*)(sX + ((t * 136 + c0) << 1)) = v;
    }
    __syncthreads();

    const int lane = tid & 63;
    const int wid  = __builtin_amdgcn_readfirstlane(tid >> 6);
    const int lr   = lane & 15;
    const int kg   = lane >> 4;
    const int ci   = wid & 1;
    const int rj   = wid >> 1;
    const int nrf  = rj ? 2 : 3;
    const int rf0  = rj ? 3 : 0;
    const f32x4 zf4 = {0.f, 0.f, 0.f, 0.f};

    // ---- phase 1: enc3 (CIN=128, CO=128) -> sY, bias, OOR-zero ----
    {
        f32x4 acc[4][3];
#pragma unroll
        for (int cf = 0; cf < 4; ++cf)
#pragma unroll
            for (int rr = 0; rr < 3; ++rr) acc[cf][rr] = zf4;
#pragma unroll
        for (int k = 0; k < 3; ++k) {
            const bf16* Ab = w3t + (size_t)k * 128 * 128;
#pragma unroll
            for (int ks = 0; ks < 4; ++ks) {
                const int cc = ks * 32 + kg * 8;
                s16x8 af[4];
#pragma unroll
                for (int cf = 0; cf < 4; ++cf)
                    af[cf] = *(const s16x8*)(Ab + (ci * 64 + cf * 16 + lr) * 128 + cc);
                s16x8 bfr[3];
#pragma unroll
                for (int rr = 0; rr < 3; ++rr)
                    if (rr < nrf) {
                        int tx = (rf0 + rr) * 16 + lr + 7 + k;
                        bfr[rr] = *(const s16x8*)(sX + ((tx * 136 + cc) << 1));
                    }
#pragma unroll
                for (int cf = 0; cf < 4; ++cf)
#pragma unroll
                    for (int rr = 0; rr < 3; ++rr)
                        if (rr < nrf)
                            acc[cf][rr] = MFMA16(af[cf], bfr[rr], acc[cf][rr]);
            }
        }
#pragma unroll
        for (int rr = 0; rr < 3; ++rr)
            if (rr < nrf) {
                int row = (rf0 + rr) * 16 + lr;
                int p   = l0 - 8 + row;
                bool ok = (p >= 0 && p < 1024);
#pragma unroll
                for (int cf = 0; cf < 4; ++cf) {
                    int ch0 = ci * 64 + cf * 16 + kg * 4;
                    float r[4];
#pragma unroll
                    for (int j = 0; j < 4; ++j)
                        r[j] = ok ? (acc[cf][rr][j] + b3[ch0 + j]) : 0.f;
                    *(uint2*)(sY + ((row * 136 + ch0) << 1)) = pack4(r[0], r[1], r[2], r[3]);
                }
            }
    }
    __syncthreads();

    // ---- res blocks ----
#pragma unroll 1
    for (int blk2 = 0; blk2 < 2; ++blk2) {
        const bf16* w1 = blk2 ? r2w1 : r1w1;
        const bf16* w2 = blk2 ? r2w2 : r1w2;
        // stage1: H = relu(w1 (x) relu(Y)), CIN=128, CO=64
        {
            f32x4 acc[2][3];
#pragma unroll
            for (int cf = 0; cf < 2; ++cf)
#pragma unroll
                for (int rr = 0; rr < 3; ++rr) acc[cf][rr] = zf4;
#pragma unroll
            for (int k = 0; k < 3; ++k) {
                const bf16* Ab = w1 + (size_t)k * 64 * 128;
#pragma unroll
                for (int ks = 0; ks < 4; ++ks) {
                    const int cc = ks * 32 + kg * 8;
                    s16x8 af[2];
#pragma unroll
                    for (int cf = 0; cf < 2; ++cf)
                        af[cf] = *(const s16x8*)(Ab + (ci * 32 + cf * 16 + lr) * 128 + cc);
                    s16x8 bfr[3];
#pragma unroll
                    for (int rr = 0; rr < 3; ++rr)
                        if (rr < nrf) {
                            int ry = (rf0 + rr) * 16 + lr + k - 1;
                            ry = (ry < 0) ? 0 : (ry > 79 ? 79 : ry);
                            bfr[rr] = relu8(*(const s16x8*)(sY + ((ry * 136 + cc) << 1)));
                        }
#pragma unroll
                    for (int cf = 0; cf < 2; ++cf)
#pragma unroll
                        for (int rr = 0; rr < 3; ++rr)
                            if (rr < nrf)
                                acc[cf][rr] = MFMA16(af[cf], bfr[rr], acc[cf][rr]);
                }
            }
#pragma unroll
            for (int rr = 0; rr < 3; ++rr)
                if (rr < nrf) {
                    int row = (rf0 + rr) * 16 + lr;
#pragma unroll
                    for (int cf = 0; cf < 2; ++cf) {
                        int ch0 = ci * 32 + cf * 16 + kg * 4;
                        *(uint2*)(sH + ((row * 72 + ch0) << 1)) =
                            pack4(fmaxf(acc[cf][rr][0], 0.f), fmaxf(acc[cf][rr][1], 0.f),
                                  fmaxf(acc[cf][rr][2], 0.f), fmaxf(acc[cf][rr][3], 0.f));
                    }
                }
        }
        __syncthreads();

        if (blk2 == 0) {
            // stage2: Y += w2*H on all 80 rows (in place, OOR-zero)
            f32x4 acc[4][3];
#pragma unroll
            for (int cf = 0; cf < 4; ++cf)
#pragma unroll
                for (int rr = 0; rr < 3; ++rr) acc[cf][rr] = zf4;
#pragma unroll
            for (int ks = 0; ks < 2; ++ks) {
                const int cc = ks * 32 + kg * 8;
                s16x8 af[4];
#pragma unroll
                for (int cf = 0; cf < 4; ++cf)
                    af[cf] = *(const s16x8*)(w2 + (size_t)(ci * 64 + cf * 16 + lr) * 64 + cc);
                s16x8 bfr[3];
#pragma unroll
                for (int rr = 0; rr < 3; ++rr)
                    if (rr < nrf) {
                        int row = (rf0 + rr) * 16 + lr;
                        bfr[rr] = *(const s16x8*)(sH + ((row * 72 + cc) << 1));
                    }
#pragma unroll
                for (int cf = 0; cf < 4; ++cf)
#pragma unroll
                    for (int rr = 0; rr < 3; ++rr)
                        if (rr < nrf)
                            acc[cf][rr] = MFMA16(af[cf], bfr[rr], acc[cf][rr]);
            }
#pragma unroll
            for (int rr = 0; rr < 3; ++rr)
                if (rr < nrf) {
                    int row = (rf0 + rr) * 16 + lr;
                    bool ok = (l0 - 8 + row >= 0 && l0 - 8 + row < 1024);
#pragma unroll
                    for (int cf = 0; cf < 4; ++cf) {
                        int ch0 = ci * 64 + cf * 16 + kg * 4;
                        uint2 old = *(const uint2*)(sY + ((row * 136 + ch0) << 1));
                        float r0 = acc[cf][rr][0] + bf2f((unsigned short)(old.x & 0xffff));
                        float r1 = acc[cf][rr][1] + bf2f((unsigned short)(old.x >> 16));
                        float r2 = acc[cf][rr][2] + bf2f((unsigned short)(old.y & 0xffff));
                        float r3 = acc[cf][rr][3] + bf2f((unsigned short)(old.y >> 16));
                        uint2 pk = pack4(r0, r1, r2, r3);
                        if (!ok) { pk.x = 0u; pk.y = 0u; }
                        *(uint2*)(sY + ((row * 136 + ch0) << 1)) = pk;
                    }
                }
            __syncthreads();
        } else {
            // final: out = relu(Y + w2*H) rows 8..71; 2x2 balanced split
            f32x4 acc[4][2];
#pragma unroll
            for (int cf = 0; cf < 4; ++cf)
#pragma unroll
                for (int rr = 0; rr < 2; ++rr) acc[cf][rr] = zf4;
#pragma unroll
            for (int ks = 0; ks < 2; ++ks) {
                const int cc = ks * 32 + kg * 8;
                s16x8 af[4];
#pragma unroll
                for (int cf = 0; cf < 4; ++cf)
                    af[cf] = *(const s16x8*)(w2 + (size_t)(ci * 64 + cf * 16 + lr) * 64 + cc);
                s16x8 bfr[2];
#pragma unroll
                for (int rr = 0; rr < 2; ++rr) {
                    int row = 8 + (2 * rj + rr) * 16 + lr;
                    bfr[rr] = *(const s16x8*)(sH + ((row * 72 + cc) << 1));
                }
#pragma unroll
                for (int cf = 0; cf < 4; ++cf)
#pragma unroll
                    for (int rr = 0; rr < 2; ++rr)
                        acc[cf][rr] = MFMA16(af[cf], bfr[rr], acc[cf][rr]);
            }
#pragma unroll
            for (int rr = 0; rr < 2; ++rr) {
                int lf  = 2 * rj + rr;
                int row = 8 + lf * 16 + lr;
#pragma unroll
                for (int cf = 0; cf < 4; ++cf) {
                    int ch0 = ci * 64 + cf * 16 + kg * 4;
                    uint2 old = *(const uint2*)(sY + ((row * 136 + ch0) << 1));
                    float r0 = fmaxf(acc[cf][rr][0] + bf2f((unsigned short)(old.x & 0xffff)), 0.f);
                    float r1 = fmaxf(acc[cf][rr][1] + bf2f((unsigned short)(old.x >> 16)), 0.f);
                    float r2 = fmaxf(acc[cf][rr][2] + bf2f((unsigned short)(old.y & 0xffff)), 0.f);
                    float r3 = fmaxf(acc[cf][rr][3] + bf2f((unsigned short)(old.y >> 16)), 0.f);
                    *(uint2*)(out + ((size_t)b * 1024 + l0 + lf * 16 + lr) * 128 + ch0) =
                        pack4(r0, r1, r2, r3);
                }
            }
        }
    }
}

// ===========================================================================
// decmid: dec1 + res1 + res2(+relu) + ct1 convT (LDS-bounced stores).
// sY 80x272B @0; sQ 96x144B @21760; sH aliases sQ. Total 35584B.
// ===========================================================================
__global__ __launch_bounds__(256, 4) void decmid_k(
    const bf16* __restrict__ qin, const bf16* __restrict__ dw1,
    const float* __restrict__ db1, const bf16* __restrict__ r1w1,
    const bf16* __restrict__ r1w2, const bf16* __restrict__ r2w1,
    const bf16* __restrict__ r2w2, const bf16* __restrict__ ct1w,
    const float* __restrict__ ct1b, bf16* __restrict__ out)
{
    __shared__ __align__(16) char smem[35584];
    char* sY = smem;
    char* sQ = smem + 21760;
    char* sH = smem + 21760;
    const int tid = threadIdx.x;
    const int b   = blockIdx.y;
    const int l0  = blockIdx.x * 64;
    const bf16* inb = qin + (size_t)b * 1024 * 64;

    for (int i = tid; i < 96 * 8; i += 256) {
        int t = i >> 3, c0 = (i & 7) * 8;
        int g = l0 - 16 + t;
        s16x8 v = {};
        if (g >= 0 && g < 1024) v = *(const s16x8*)(inb + (size_t)g * 64 + c0);
        *(s16x8*)(sQ + ((t * 72 + c0) << 1)) = v;
    }
    __syncthreads();

    const int lane = tid & 63;
    const int wid  = __builtin_amdgcn_readfirstlane(tid >> 6);
    const int lr   = lane & 15;
    const int kg   = lane >> 4;
    const int ci   = wid & 1;
    const int rj   = wid >> 1;
    const int nrf  = rj ? 2 : 3;
    const int rf0  = rj ? 3 : 0;
    const f32x4 zf4 = {0.f, 0.f, 0.f, 0.f};

    // ---- phase 1: dec1 (CIN=64, CO=128) -> sY ----
    {
        f32x4 acc[4][3];
#pragma unroll
        for (int cf = 0; cf < 4; ++cf)
#pragma unroll
            for (int rr = 0; rr < 3; ++rr) acc[cf][rr] = zf4;
#pragma unroll
        for (int k = 0; k < 3; ++k) {
            const bf16* Ab = dw1 + (size_t)k * 128 * 64;
#pragma unroll
            for (int ks = 0; ks < 2; ++ks) {
                const int cc = ks * 32 + kg * 8;
                s16x8 af[4];
#pragma unroll
                for (int cf = 0; cf < 4; ++cf)
                    af[cf] = *(const s16x8*)(Ab + (ci * 64 + cf * 16 + lr) * 64 + cc);
                s16x8 bfr[3];
#pragma unroll
                for (int rr = 0; rr < 3; ++rr)
                    if (rr < nrf) {
                        int tx = (rf0 + rr) * 16 + lr + 7 + k;
                        bfr[rr] = *(const s16x8*)(sQ + ((tx * 72 + cc) << 1));
                    }
#pragma unroll
                for (int cf = 0; cf < 4; ++cf)
#pragma unroll
                    for (int rr = 0; rr < 3; ++rr)
                        if (rr < nrf)
                            acc[cf][rr] = MFMA16(af[cf], bfr[rr], acc[cf][rr]);
            }
        }
        __syncthreads();   // sQ reads complete before sH alias overwrite
#pragma unroll
        for (int rr = 0; rr < 3; ++rr)
            if (rr < nrf) {
                int row = (rf0 + rr) * 16 + lr;
                int p   = l0 - 8 + row;
                bool ok = (p >= 0 && p < 1024);
#pragma unroll
                for (int cf = 0; cf < 4; ++cf) {
                    int ch0 = ci * 64 + cf * 16 + kg * 4;
                    float r[4];
#pragma unroll
                    for (int j = 0; j < 4; ++j)
                        r[j] = ok ? (acc[cf][rr][j] + db1[ch0 + j]) : 0.f;
                    *(uint2*)(sY + ((row * 136 + ch0) << 1)) = pack4(r[0], r[1], r[2], r[3]);
                }
            }
    }
    __syncthreads();

    // ---- res blocks ----
#pragma unroll 1
    for (int blk2 = 0; blk2 < 2; ++blk2) {
        const bf16* w1 = blk2 ? r2w1 : r1w1;
        const bf16* w2 = blk2 ? r2w2 : r1w2;
        {
            f32x4 acc[2][3];
#pragma unroll
            for (int cf = 0; cf < 2; ++cf)
#pragma unroll
                for (int rr = 0; rr < 3; ++rr) acc[cf][rr] = zf4;
#pragma unroll
            for (int k = 0; k < 3; ++k) {
                const bf16* Ab = w1 + (size_t)k * 64 * 128;
#pragma unroll
                for (int ks = 0; ks < 4; ++ks) {
                    const int cc = ks * 32 + kg * 8;
                    s16x8 af[2];
#pragma unroll
                    for (int cf = 0; cf < 2; ++cf)
                        af[cf] = *(const s16x8*)(Ab + (ci * 32 + cf * 16 + lr) * 128 + cc);
                    s16x8 bfr[3];
#pragma unroll
                    for (int rr = 0; rr < 3; ++rr)
                        if (rr < nrf) {
                            int ry = (rf0 + rr) * 16 + lr + k - 1;
                            ry = (ry < 0) ? 0 : (ry > 79 ? 79 : ry);
                            bfr[rr] = relu8(*(const s16x8*)(sY + ((ry * 136 + cc) << 1)));
                        }
#pragma unroll
                    for (int cf = 0; cf < 2; ++cf)
#pragma unroll
                        for (int rr = 0; rr < 3; ++rr)
                            if (rr < nrf)
                                acc[cf][rr] = MFMA16(af[cf], bfr[rr], acc[cf][rr]);
                }
            }
#pragma unroll
            for (int rr = 0; rr < 3; ++rr)
                if (rr < nrf) {
                    int row = (rf0 + rr) * 16 + lr;
#pragma unroll
                    for (int cf = 0; cf < 2; ++cf) {
                        int ch0 = ci * 32 + cf * 16 + kg * 4;
                        *(uint2*)(sH + ((row * 72 + ch0) << 1)) =
                            pack4(fmaxf(acc[cf][rr][0], 0.f), fmaxf(acc[cf][rr][1], 0.f),
                                  fmaxf(acc[cf][rr][2], 0.f), fmaxf(acc[cf][rr][3], 0.f));
                    }
                }
        }
        __syncthreads();
        {
            // stage2: Y = [relu](Y + w2*H), 80 rows, in place
            f32x4 acc[4][3];
#pragma unroll
            for (int cf = 0; cf < 4; ++cf)
#pragma unroll
                for (int rr = 0; rr < 3; ++rr) acc[cf][rr] = zf4;
#pragma unroll
            for (int ks = 0; ks < 2; ++ks) {
                const int cc = ks * 32 + kg * 8;
                s16x8 af[4];
#pragma unroll
                for (int cf = 0; cf < 4; ++cf)
                    af[cf] = *(const s16x8*)(w2 + (size_t)(ci * 64 + cf * 16 + lr) * 64 + cc);
                s16x8 bfr[3];
#pragma unroll
                for (int rr = 0; rr < 3; ++rr)
                    if (rr < nrf) {
                        int row = (rf0 + rr) * 16 + lr;
                        bfr[rr] = *(const s16x8*)(sH + ((row * 72 + cc) << 1));
                    }
#pragma unroll
                for (int cf = 0; cf < 4; ++cf)
#pragma unroll
                    for (int rr = 0; rr < 3; ++rr)
                        if (rr < nrf)
                            acc[cf][rr] = MFMA16(af[cf], bfr[rr], acc[cf][rr]);
            }
#pragma unroll
            for (int rr = 0; rr < 3; ++rr)
                if (rr < nrf) {
                    int row = (rf0 + rr) * 16 + lr;
                    bool ok = (l0 - 8 + row >= 0 && l0 - 8 + row < 1024);
#pragma unroll
                    for (int cf = 0; cf < 4; ++cf) {
                        int ch0 = ci * 64 + cf * 16 + kg * 4;
                        uint2 old = *(const uint2*)(sY + ((row * 136 + ch0) << 1));
                        float r0 = acc[cf][rr][0] + bf2f((unsigned short)(old.x & 0xffff));
                        float r1 = acc[cf][rr][1] + bf2f((unsigned short)(old.x >> 16));
                        float r2 = acc[cf][rr][2] + bf2f((unsigned short)(old.y & 0xffff));
                        float r3 = acc[cf][rr][3] + bf2f((unsigned short)(old.y >> 16));
                        if (blk2 == 1) {
                            r0 = fmaxf(r0, 0.f); r1 = fmaxf(r1, 0.f);
                            r2 = fmaxf(r2, 0.f); r3 = fmaxf(r3, 0.f);
                        }
                        uint2 pk = pack4(r0, r1, r2, r3);
                        if (!ok) { pk.x = 0u; pk.y = 0u; }
                        *(uint2*)(sY + ((row * 136 + ch0) << 1)) = pk;
                    }
                }
        }
        __syncthreads();
    }

    // ---- ct1 convT (CO=64), 2D split (co-half x m-half) + LDS store bounce --
    {
        const int co0 = (wid & 1) * 32;
        const int mh  = wid >> 1;
        f32x4 acc[2][2][2];
#pragma unroll
        for (int g = 0; g < 2; ++g)
#pragma unroll
            for (int cf = 0; cf < 2; ++cf)
#pragma unroll
                for (int j = 0; j < 2; ++j) acc[g][cf][j] = zf4;
#pragma unroll
        for (int g = 0; g < 2; ++g)
#pragma unroll
            for (int k = 0; k < 2; ++k) {
                const bf16* Ab = ct1w + (size_t)(g * 2 + k) * 64 * 128;
                const int doff = (g == 0) ? (k - 1) : k;
#pragma unroll
                for (int ks = 0; ks < 4; ++ks) {
                    const int cc = ks * 32 + kg * 8;
                    s16x8 af[2];
#pragma unroll
                    for (int cf = 0; cf < 2; ++cf)
                        af[cf] = *(const s16x8*)(Ab + (co0 + cf * 16 + lr) * 128 + cc);
                    s16x8 bfr[2];
#pragma unroll
                    for (int j = 0; j < 2; ++j) {
                        int ty = 8 + (mh * 2 + j) * 16 + lr + doff;
                        bfr[j] = *(const s16x8*)(sY + ((ty * 136 + cc) << 1));
                    }
#pragma unroll
                    for (int cf = 0; cf < 2; ++cf)
#pragma unroll
                        for (int j = 0; j < 2; ++j)
                            acc[g][cf][j] = MFMA16(af[cf], bfr[j], acc[g][cf][j]);
                }
            }
        __syncthreads();   // all sY reads done before bounce overwrite

        // bounce: sY region becomes [128 rows][64ch] linear (16KB)
#pragma unroll
        for (int g = 0; g < 2; ++g)
#pragma unroll
            for (int cf = 0; cf < 2; ++cf)
#pragma unroll
                for (int j = 0; j < 2; ++j) {
                    int m   = (mh * 2 + j) * 16 + lr;
                    int rr  = 2 * m + g;
                    int ch0 = co0 + cf * 16 + kg * 4;
                    float r[4];
#pragma unroll
                    for (int jj = 0; jj < 4; ++jj)
                        r[jj] = fmaxf(acc[g][cf][j][jj] + ct1b[ch0 + jj], 0.f);
                    *(uint2*)(sY + rr * 128 + ch0 * 2) = pack4(r[0], r[1], r[2], r[3]);
                }
        __syncthreads();

        bf16* ob = out + ((size_t)b * 2048 + 2 * l0) * 64;
        for (int i = tid; i < 1024; i += 256)
            *(s16x8*)(ob + i * 8) = *(const s16x8*)(sY + i * 16);
    }
}

// Fused enc1+enc2: x fp32 -> h1 (LDS, stride 72) -> enc2 GEMM -> bf16 relu.
__global__ __launch_bounds__(256) void enc12_k(
    const float* __restrict__ x, const float* __restrict__ w1,
    const float* __restrict__ b1, const bf16* __restrict__ w2t,
    const float* __restrict__ b2, bf16* __restrict__ out)
{
    __shared__ float sXf[268];
    __shared__ float sW1[256];
    __shared__ float sB1[64];
    __shared__ __align__(16) char sX[132 * 144];
    const int tid = threadIdx.x;
    const int b   = blockIdx.y;
    const int l0  = blockIdx.x * 64;
    const float* xb = x + (size_t)b * 4096;

    for (int i = tid; i < 266; i += 256) {
        int g = 4 * l0 - 3 + i;
        sXf[i] = (g >= 0 && g < 4096) ? xb[g] : 0.f;
    }
    if (tid < 256) sW1[tid] = w1[tid];
    if (tid < 64)  sB1[tid] = b1[tid];
    __syncthreads();

    for (int i = tid; i < 132 * 64; i += 256) {
        int t = i >> 6, c = i & 63;
        int p = (t < 66) ? 2 * (l0 + t) : 2 * (l0 + t - 66) - 1;
        float v = 0.f;
        if (p >= 0 && p < 2048) {
            int xi = 2 * p - 4 * l0 + 2;
            float a = sB1[c];
#pragma unroll
            for (int k = 0; k < 4; ++k) a = fmaf(sXf[xi + k], sW1[c * 4 + k], a);
            v = fmaxf(a, 0.f);
        }
        *(bf16*)(sX + ((t * 72 + c) << 1)) = __float2bfloat16(v);
    }
    __syncthreads();

    const int lane = tid & 63;
    const int wid  = __builtin_amdgcn_readfirstlane(tid >> 6);
    const int co0  = wid * 32;
    const int lr   = lane & 15;
    const int kg   = lane >> 4;

    f32x4 acc[2][4];
#pragma unroll
    for (int cf = 0; cf < 2; ++cf)
#pragma unroll
        for (int lf = 0; lf < 4; ++lf) acc[cf][lf] = (f32x4){0.f, 0.f, 0.f, 0.f};

#pragma unroll
    for (int k = 0; k < 4; ++k) {
        const int roff = (k == 0) ? 66 : (k == 1) ? 0 : (k == 2) ? 67 : 1;
        const bf16* Ab = w2t + (size_t)k * 128 * 64;
#pragma unroll
        for (int ks = 0; ks < 2; ++ks) {
            s16x8 af[2];
#pragma unroll
            for (int cf = 0; cf < 2; ++cf)
                af[cf] = *(const s16x8*)(Ab + (co0 + cf * 16 + lr) * 64 + ks * 32 + kg * 8);
            s16x8 bfr[4];
#pragma unroll
            for (int lf = 0; lf < 4; ++lf) {
                int t = roff + lf * 16 + lr;
                bfr[lf] = *(const s16x8*)(sX + ((t * 72 + ks * 32 + kg * 8) << 1));
            }
#pragma unroll
            for (int cf = 0; cf < 2; ++cf)
#pragma unroll
                for (int lf = 0; lf < 4; ++lf)
                    acc[cf][lf] = MFMA16(af[cf], bfr[lf], acc[cf][lf]);
        }
    }

#pragma unroll
    for (int cf = 0; cf < 2; ++cf)
#pragma unroll
        for (int lf = 0; lf < 4; ++lf) {
            int cb0  = co0 + cf * 16 + kg * 4;
            int lcol = lf * 16 + lr;
            float r[4];
#pragma unroll
            for (int j = 0; j < 4; ++j)
                r[j] = fmaxf(acc[cf][lf][j] + b2[cb0 + j], 0.f);
            *(uint2*)(out + ((size_t)b * 1024 + l0 + lcol) * 128 + cb0) =
                pack4(r[0], r[1], r[2], r[3]);
        }
}

// Final convT: 64->1 ch, x2 upsample; fp32 out.
__global__ __launch_bounds__(256) void ct2_k(
    const bf16* __restrict__ in, const float* __restrict__ w,
    const float* __restrict__ bias, float* __restrict__ out)
{
    __shared__ __align__(16) char sX[258 * 144];
    const int tid = threadIdx.x;
    const int b   = blockIdx.y;
    const int m0  = blockIdx.x * 256;
    const bf16* inb = in + (size_t)b * 2048 * 64;
    for (int i = tid; i < 258 * 8; i += 256) {
        int t = i >> 3, c0 = (i & 7) * 8;
        int g = m0 - 1 + t;
        s16x8 v = {};
        if (g >= 0 && g < 2048) v = *(const s16x8*)(inb + (size_t)g * 64 + c0);
        *(s16x8*)(sX + ((t * 72 + c0) << 1)) = v;
    }
    __syncthreads();
    float e = bias[0], o = bias[0];
#pragma unroll
    for (int c0 = 0; c0 < 64; c0 += 8) {
        s16x8 vm1 = *(const s16x8*)(sX + (((tid + 0) * 72 + c0) << 1));
        s16x8 v0  = *(const s16x8*)(sX + (((tid + 1) * 72 + c0) << 1));
        s16x8 vp1 = *(const s16x8*)(sX + (((tid + 2) * 72 + c0) << 1));
#pragma unroll
        for (int j = 0; j < 8; ++j) {
            int ci = c0 + j;
            float xm1 = bf2f((unsigned short)vm1[j]);
            float x0  = bf2f((unsigned short)v0[j]);
            float xp1 = bf2f((unsigned short)vp1[j]);
            e = fmaf(x0,  w[ci * 4 + 1], fmaf(xm1, w[ci * 4 + 3], e));
            o = fmaf(xp1, w[ci * 4 + 0], fmaf(x0,  w[ci * 4 + 2], o));
        }
    }
    int m = m0 + tid;
    out[(size_t)b * 4096 + 2 * m]     = e;
    out[(size_t)b * 4096 + 2 * m + 1] = o;
}

// Weight transform: fp32 conv weights -> bf16 [tap][co][ci] matrices.
__global__ __launch_bounds__(256) void wx_k(
    const float* ew2, const float* ew3, const float* er1a, const float* er1b,
    const float* er2a, const float* er2b, const float* pvw, const float* dw1,
    const float* dr1a, const float* dr1b, const float* dr2a, const float* dr2b,
    const float* ct1w, bf16* wb)
{
    const int job = blockIdx.x;
    bf16* dst = wb + (size_t)job * 65536;
    const float* src; int CO, CI, K;
    switch (job) {
        case 0:  src = ew2;  CO = 128; CI = 64;  K = 4; break;
        case 1:  src = ew3;  CO = 128; CI = 128; K = 3; break;
        case 2:  src = er1a; CO = 64;  CI = 128; K = 3; break;
        case 3:  src = er1b; CO = 128; CI = 64;  K = 1; break;
        case 4:  src = er2a; CO = 64;  CI = 128; K = 3; break;
        case 5:  src = er2b; CO = 128; CI = 64;  K = 1; break;
        case 6:  src = pvw;  CO = 64;  CI = 128; K = 1; break;
        case 7:  src = dw1;  CO = 128; CI = 64;  K = 3; break;
        case 8:  src = dr1a; CO = 64;  CI = 128; K = 3; break;
        case 9:  src = dr1b; CO = 128; CI = 64;  K = 1; break;
        case 10: src = dr2a; CO = 64;  CI = 128; K = 3; break;
        case 11: src = dr2b; CO = 128; CI = 64;  K = 1; break;
        default: src = ct1w; CO = 64;  CI = 128; K = 4; break;
    }
    const int tot = CO * CI * K;
    for (int i = blockIdx.y * 256 + threadIdx.x; i < tot; i += gridDim.y * 256) {
        if (job < 12) {
            int k = i / (CO * CI); int r = i - k * CO * CI;
            int co = r / CI; int ci = r - co * CI;
            dst[i] = __float2bfloat16(src[((size_t)co * CI + ci) * K + k]);
        } else {
            const int TAP[4] = {3, 1, 2, 0};
            int g = i / (64 * 128); int r = i - g * 64 * 128;
            int co = r / 128; int ci = r - co * 128;
            dst[i] = __float2bfloat16(src[((size_t)ci * 64 + co) * 4 + TAP[g]]);
        }
    }
}

// codebook prep: fp32 norms + hi/lo bf16 split
__global__ __launch_bounds__(256) void cbprep_k(
    const float* __restrict__ cb, bf16* __restrict__ cbh, bf16* __restrict__ cbl,
    float* __restrict__ sc)
{
    int k = blockIdx.x * 256 + threadIdx.x;
    const float* c = cb + (size_t)k * 64;
    float s = 0.f;
#pragma unroll
    for (int d = 0; d < 64; ++d) s = fmaf(c[d], c[d], s);
    sc[k] = s;
#pragma unroll
    for (int c0 = 0; c0 < 64; c0 += 8) {
        union { unsigned short u[8]; s16x8 v; } ph, pl;
#pragma unroll
        for (int j = 0; j < 8; ++j) {
            float v = c[c0 + j];
            unsigned short h = bfbits(v);
            ph.u[j] = h;
            pl.u[j] = bfbits(v - bf2f(h));
        }
        *(s16x8*)(cbh + (size_t)k * 64 + c0) = ph.v;
        *(s16x8*)(cbl + (size_t)k * 64 + c0) = pl.v;
    }
}

// Fused pre_vq + VQ. 1024 blocks x 128 positions. A tile / z tile alias.
__global__ __launch_bounds__(256, 4) void vqf_k(
    const bf16* __restrict__ A, const bf16* __restrict__ pvw,
    const float* __restrict__ pvb, const float* __restrict__ cbf,
    const bf16* __restrict__ cbh, const bf16* __restrict__ cbl,
    const float* __restrict__ sc, bf16* __restrict__ q,
    float* __restrict__ counts, float* __restrict__ loss_sum)
{
    __shared__ __align__(16) char sMem[34816];
    __shared__ float sSC[512];
    __shared__ float sHist[512];
    __shared__ int   sBK[128];
    __shared__ float sWS[4];
    const int tid = threadIdx.x;
    sSC[tid] = sc[tid]; sSC[tid + 256] = sc[tid + 256];
    sHist[tid] = 0.f;   sHist[tid + 256] = 0.f;

    const int n0 = blockIdx.x * 128;
    for (int i = tid; i < 128 * 16; i += 256) {
        int t = i >> 4, c0 = (i & 15) * 8;
        s16x8 v = *(const s16x8*)(A + (size_t)(n0 + t) * 128 + c0);
        *(s16x8*)(sMem + ((t * 136 + c0) << 1)) = v;
    }
    __syncthreads();

    const int lane = tid & 63, wid = tid >> 6;
    const int lr = lane & 15, kg = lane >> 4;
    const int pw0 = wid * 32;
    const f32x4 zf4 = {0.f, 0.f, 0.f, 0.f};

    f32x4 zacc[4][2];
#pragma unroll
    for (int cf = 0; cf < 4; ++cf)
#pragma unroll
        for (int lf = 0; lf < 2; ++lf) zacc[cf][lf] = zf4;
#pragma unroll
    for (int ks = 0; ks < 4; ++ks) {
        s16x8 af[4];
#pragma unroll
        for (int cf = 0; cf < 4; ++cf)
            af[cf] = *(const s16x8*)(pvw + (size_t)(cf * 16 + lr) * 128 + ks * 32 + kg * 8);
        s16x8 bfr[2];
#pragma unroll
        for (int lf = 0; lf < 2; ++lf) {
            int t = pw0 + lf * 16 + lr;
            bfr[lf] = *(const s16x8*)(sMem + ((t * 136 + ks * 32 + kg * 8) << 1));
        }
#pragma unroll
        for (int cf = 0; cf < 4; ++cf)
#pragma unroll
            for (int lf = 0; lf < 2; ++lf)
                zacc[cf][lf] = MFMA16(af[cf], bfr[lf], zacc[cf][lf]);
    }
    __syncthreads();

#pragma unroll
    for (int cf = 0; cf < 4; ++cf)
#pragma unroll
        for (int lf = 0; lf < 2; ++lf) {
            int pos = pw0 + lf * 16 + lr;
            int ch  = cf * 16 + kg * 4;
            float4 v = make_float4(zacc[cf][lf][0] + pvb[ch],
                                   zacc[cf][lf][1] + pvb[ch + 1],
                                   zacc[cf][lf][2] + pvb[ch + 2],
                                   zacc[cf][lf][3] + pvb[ch + 3]);
            *(float4*)(sMem + (pos * 68 + ch) * 4) = v;
        }
    __syncthreads();

    s16x8 bh[2][2], bl[2][2];
#pragma unroll
    for (int lf = 0; lf < 2; ++lf)
#pragma unroll
        for (int ks = 0; ks < 2; ++ks) {
            int t = pw0 + lf * 16 + lr;
            int ch = ks * 32 + kg * 8;
            float4 v0 = *(const float4*)(sMem + (t * 68 + ch) * 4);
            float4 v1 = *(const float4*)(sMem + (t * 68 + ch) * 4 + 16);
            float v[8] = {v0.x, v0.y, v0.z, v0.w, v1.x, v1.y, v1.z, v1.w};
            union { unsigned short u[8]; s16x8 s; } ph, pl;
#pragma unroll
            for (int j = 0; j < 8; ++j) {
                unsigned short h = bfbits(v[j]);
                ph.u[j] = h;
                pl.u[j] = bfbits(v[j] - bf2f(h));
            }
            bh[lf][ks] = ph.s; bl[lf][ks] = pl.s;
        }

    float bestd[2] = {3.4e38f, 3.4e38f};
    int   bestk[2] = {0, 0};
#pragma unroll 2
    for (int cf = 0; cf < 32; ++cf) {
        int code = cf * 16 + lr;
        const bf16* ph = cbh + code * 64 + kg * 8;
        const bf16* pl = cbl + code * 64 + kg * 8;
        s16x8 ah0 = *(const s16x8*)ph;
        s16x8 ah1 = *(const s16x8*)(ph + 32);
        s16x8 al0 = *(const s16x8*)pl;
        s16x8 al1 = *(const s16x8*)(pl + 32);
        float s0 = sSC[cf * 16 + kg * 4 + 0];
        float s1 = sSC[cf * 16 + kg * 4 + 1];
        float s2 = sSC[cf * 16 + kg * 4 + 2];
        float s3 = sSC[cf * 16 + kg * 4 + 3];
        int kb = cf * 16 + kg * 4;
#pragma unroll
        for (int lf = 0; lf < 2; ++lf) {
            f32x4 acc = MFMA16(ah0, bh[lf][0], zf4);
            acc = MFMA16(ah1, bh[lf][1], acc);
            acc = MFMA16(al0, bh[lf][0], acc);
            acc = MFMA16(al1, bh[lf][1], acc);
            acc = MFMA16(ah0, bl[lf][0], acc);
            acc = MFMA16(ah1, bl[lf][1], acc);
            float d0 = fmaf(acc[0], -2.f, s0);
            float d1 = fmaf(acc[1], -2.f, s1);
            float d2 = fmaf(acc[2], -2.f, s2);
            float d3 = fmaf(acc[3], -2.f, s3);
            if (d0 < bestd[lf]) { bestd[lf] = d0; bestk[lf] = kb; }
            if (d1 < bestd[lf]) { bestd[lf] = d1; bestk[lf] = kb + 1; }
            if (d2 < bestd[lf]) { bestd[lf] = d2; bestk[lf] = kb + 2; }
            if (d3 < bestd[lf]) { bestd[lf] = d3; bestk[lf] = kb + 3; }
        }
    }
#pragma unroll
    for (int lf = 0; lf < 2; ++lf) {
#pragma unroll
        for (int off = 16; off <= 32; off <<= 1) {
            float od = __shfl_xor(bestd[lf], off, 64);
            int   ok = __shfl_xor(bestk[lf], off, 64);
            if (od < bestd[lf] || (od == bestd[lf] && ok < bestk[lf])) {
                bestd[lf] = od; bestk[lf] = ok;
            }
        }
        if (kg == 0) sBK[pw0 + lf * 16 + lr] = bestk[lf];
    }
    __syncthreads();

    const int pos  = tid >> 1;
    const int half = tid & 1;
    const int k = sBK[pos];
    if (half == 0) atomicAdd(&sHist[k], 1.f);
    float lsum = 0.f;
    const float* qp = cbf + (size_t)k * 64 + half * 32;
    bf16* qo = q + (size_t)(n0 + pos) * 64 + half * 32;
#pragma unroll
    for (int c0 = 0; c0 < 32; c0 += 8) {
        int zb = (pos * 68 + half * 32 + c0) * 4;
        float4 z0 = *(const float4*)(sMem + zb);
        float4 z1 = *(const float4*)(sMem + zb + 16);
        float4 q0 = *(const float4*)(qp + c0);
        float4 q1 = *(const float4*)(qp + c0 + 4);
        float qv[8] = {q0.x, q0.y, q0.z, q0.w, q1.x, q1.y, q1.z, q1.w};
        float zv[8] = {z0.x, z0.y, z0.z, z0.w, z1.x, z1.y, z1.z, z1.w};
        union { unsigned short u[8]; s16x8 v; } pk;
#pragma unroll
        for (int j = 0; j < 8; ++j) {
            float d = qv[j] - zv[j];
            lsum = fmaf(d, d, lsum);
            pk.u[j] = bfbits(qv[j]);
        }
        *(s16x8*)(qo + c0) = pk.v;
    }
#pragma unroll
    for (int off = 32; off > 0; off >>= 1) lsum += __shfl_down(lsum, off, 64);
    if ((tid & 63) == 0) sWS[tid >> 6] = lsum;
    __syncthreads();
    if (tid == 0) atomicAdd(loss_sum, sWS[0] + sWS[1] + sWS[2] + sWS[3]);
    float c0v = sHist[tid];       if (c0v != 0.f) atomicAdd(&counts[tid], c0v);
    float c1v = sHist[tid + 256]; if (c1v != 0.f) atomicAdd(&counts[tid + 256], c1v);
}

__global__ __launch_bounds__(512) void finalize_k(
    const float* __restrict__ counts, const float* __restrict__ loss_sum,
    float* __restrict__ d_out, int out_size)
{
    __shared__ float ws2[8];
    const int tid = threadIdx.x;
    float p = counts[tid] * (1.f / 131072.f);
    float e = p * logf(p + 1e-10f);
#pragma unroll
    for (int off = 32; off > 0; off >>= 1) e += __shfl_down(e, off, 64);
    const int lane = tid & 63, wid = tid >> 6;
    if (lane == 0) ws2[wid] = e;
    __syncthreads();
    if (tid == 0) {
        float s = 0.f;
        for (int i = 0; i < 8; ++i) s += ws2[i];
        d_out[0] = 1.25f * loss_sum[0] * (1.f / 8388608.f);  // (1+BETA)*mean
        d_out[out_size - 1] = expf(-s);
    }
}

extern "C" void kernel_launch(void* const* d_in, const int* in_sizes, int n_in,
                              void* d_out, int out_size, void* d_ws, size_t ws_size,
                              hipStream_t stream)
{
    const float* x        = (const float*)d_in[0];
    const float* enc_w1   = (const float*)d_in[1];
    const float* enc_b1   = (const float*)d_in[2];
    const float* enc_b2   = (const float*)d_in[4];
    const float* enc_b3   = (const float*)d_in[6];
    const float* pre_vq_b = (const float*)d_in[12];
    const float* cb       = (const float*)d_in[13];
    const float* dec_b1   = (const float*)d_in[15];
    const float* ct1_b    = (const float*)d_in[21];
    const float* ct2_w    = (const float*)d_in[22];
    const float* ct2_b    = (const float*)d_in[23];
    float* out = (float*)d_out;

    char* base = (char*)d_ws;
    bf16*  wb   = (bf16*)base;
    bf16*  Abf  = (bf16*)(base + ((size_t)2   << 20));
    bf16*  Bbf  = (bf16*)(base + ((size_t)40  << 20));
    bf16*  Qbf  = (bf16*)(base + ((size_t)78  << 20));
    bf16*  cbh  = (bf16*)(base + ((size_t)96  << 20));
    bf16*  cbl  = (bf16*)(base + ((size_t)96  << 20) + 65536);
    float* sc   = (float*)(base + ((size_t)96  << 20) + 131072);
    float* cnt  = sc + 512;
    float* lsum = cnt + 512;

    (void)hipMemsetAsync(cnt, 0, 513 * sizeof(float), stream);

    dim3 blk(256);
    dim3 g16(16, 128);

    wx_k<<<dim3(13, 8), blk, 0, stream>>>(
        (const float*)d_in[3], (const float*)d_in[5], (const float*)d_in[7],
        (const float*)d_in[8], (const float*)d_in[9], (const float*)d_in[10],
        (const float*)d_in[11], (const float*)d_in[14], (const float*)d_in[16],
        (const float*)d_in[17], (const float*)d_in[18], (const float*)d_in[19],
        (const float*)d_in[20], wb);
    cbprep_k<<<2, blk, 0, stream>>>(cb, cbh, cbl, sc);

    enc12_k<<<g16, blk, 0, stream>>>(x, enc_w1, enc_b1, wb + 0 * 65536, enc_b2, Bbf);
    encmid_k<<<g16, blk, 0, stream>>>(Bbf, wb + 1 * 65536, enc_b3,
        wb + 2 * 65536, wb + 3 * 65536, wb + 4 * 65536, wb + 5 * 65536, Abf);

    vqf_k<<<1024, blk, 0, stream>>>(Abf, wb + 6 * 65536, pre_vq_b, cb,
                                    cbh, cbl, sc, Qbf, cnt, lsum);

    decmid_k<<<g16, blk, 0, stream>>>(Qbf, wb + 7 * 65536, dec_b1,
        wb + 8 * 65536, wb + 9 * 65536, wb + 10 * 65536, wb + 11 * 65536,
        wb + 12 * 65536, ct1_b, Bbf);

    ct2_k<<<dim3(8, 128), blk, 0, stream>>>(Bbf, ct2_w, ct2_b, out + 1);
    finalize_k<<<1, 512, 0, stream>>>(cnt, lsum, out, out_size);
}

// Round 12
// 444.511 us; speedup vs baseline: 1.6059x; 1.0144x over previous
//
#include <hip/hip_runtime.h>
#include <hip/hip_bf16.h>
#include <math.h>

using bf16 = __hip_bfloat16;
typedef __attribute__((ext_vector_type(4))) float f32x4;
typedef __attribute__((ext_vector_type(8))) short s16x8;

#define MFMA16(a,b,c) __builtin_amdgcn_mfma_f32_16x16x32_bf16((a),(b),(c),0,0,0)

// ---------------------------------------------------------------------------
// VQ-VAE forward. B=128, L=4096, H=128, RH=64, D=64, K=512.
// Channel-last bf16. Round-9 GEMM phases; minimal halo windows for occupancy
// (encmid 4 blocks/CU, decmid 5 blocks/CU); ct1 stores bounced via LDS.
// ---------------------------------------------------------------------------

__device__ inline float bf2f(unsigned short u) {
    union { float f; unsigned v; } c; c.v = ((unsigned)u) << 16; return c.f;
}
__device__ inline unsigned short bfbits(float f) {
    union { bf16 h; unsigned short u; } c; c.h = __float2bfloat16(f); return c.u;
}
__device__ inline s16x8 relu8(s16x8 v) {
#pragma unroll
    for (int j = 0; j < 8; ++j)
        v[j] = (short)(((unsigned short)v[j] & 0x8000u) ? 0 : (unsigned short)v[j]);
    return v;
}
__device__ inline uint2 pack4(float a, float b, float c, float d) {
    uint2 p;
    p.x = (unsigned)bfbits(a) | ((unsigned)bfbits(b) << 16);
    p.y = (unsigned)bfbits(c) | ((unsigned)bfbits(d) << 16);
    return p;
}

// ===========================================================================
// encmid: enc3 (128->128 K3) + res1 + res2 + final relu.  Bbf -> Abf.
// Y row r <-> pos l0-2+r, r in [0,68). X row t <-> pos l0-3+t, t in [0,70).
// sY 68x272B @0 (18496); sX 70x272B @18496 (19040); sH 68x144B aliases sX.
// Total 37536B -> 4 blocks/CU.
// ===========================================================================
__global__ __launch_bounds__(256, 4) void encmid_k(
    const bf16* __restrict__ in, const bf16* __restrict__ w3t,
    const float* __restrict__ b3, const bf16* __restrict__ r1w1,
    const bf16* __restrict__ r1w2, const bf16* __restrict__ r2w1,
    const bf16* __restrict__ r2w2, bf16* __restrict__ out)
{
    __shared__ __align__(16) char smem[37536];
    char* sY = smem;
    char* sX = smem + 18496;
    char* sH = smem + 18496;
    const int tid = threadIdx.x;
    const int b   = blockIdx.y;
    const int l0  = blockIdx.x * 64;
    const bf16* inb = in + (size_t)b * 1024 * 128;

    for (int i = tid; i < 70 * 16; i += 256) {
        int t = i >> 4, c0 = (i & 15) * 8;
        int g = l0 - 3 + t;
        s16x8 v = {};
        if (g >= 0 && g < 1024) v = *(const s16x8*)(inb + (size_t)g * 128 + c0);
        *(s16x8*)(sX + ((t * 136 + c0) << 1)) = v;
    }
    __syncthreads();

    const int lane = tid & 63;
    const int wid  = __builtin_amdgcn_readfirstlane(tid >> 6);
    const int lr   = lane & 15;
    const int kg   = lane >> 4;
    const f32x4 zf4 = {0.f, 0.f, 0.f, 0.f};

    // ---- phase 1: enc3 -> sY rows [0,68), bias, OOR-zero ----
    {
        const int co0 = wid * 32;
        f32x4 acc[2][5];
#pragma unroll
        for (int cf = 0; cf < 2; ++cf)
#pragma unroll
            for (int lf = 0; lf < 5; ++lf) acc[cf][lf] = zf4;
#pragma unroll
        for (int k = 0; k < 3; ++k) {
            const bf16* Ab = w3t + (size_t)k * 128 * 128;
#pragma unroll
            for (int ks = 0; ks < 4; ++ks) {
                s16x8 af[2];
#pragma unroll
                for (int cf = 0; cf < 2; ++cf)
                    af[cf] = *(const s16x8*)(Ab + (co0 + cf * 16 + lr) * 128 + ks * 32 + kg * 8);
                s16x8 bfr[5];
#pragma unroll
                for (int lf = 0; lf < 5; ++lf) {
                    int tx = lf * 16 + lr + k;         // t = r + k
                    tx = (tx > 69) ? 69 : tx;
                    bfr[lf] = *(const s16x8*)(sX + ((tx * 136 + ks * 32 + kg * 8) << 1));
                }
#pragma unroll
                for (int cf = 0; cf < 2; ++cf)
#pragma unroll
                    for (int lf = 0; lf < 5; ++lf)
                        acc[cf][lf] = MFMA16(af[cf], bfr[lf], acc[cf][lf]);
            }
        }
        __syncthreads();   // all sX reads done before sH alias writes later
#pragma unroll
        for (int cf = 0; cf < 2; ++cf)
#pragma unroll
            for (int lf = 0; lf < 5; ++lf) {
                int row = lf * 16 + lr;
                if (row < 68) {
                    int p   = l0 - 2 + row;
                    int cb0 = co0 + cf * 16 + kg * 4;
                    bool ok = (p >= 0 && p < 1024);
                    float r[4];
#pragma unroll
                    for (int j = 0; j < 4; ++j)
                        r[j] = ok ? (acc[cf][lf][j] + b3[cb0 + j]) : 0.f;
                    *(uint2*)(sY + ((row * 136 + cb0) << 1)) = pack4(r[0], r[1], r[2], r[3]);
                }
            }
    }
    __syncthreads();

    // ---- phases 2..5: two res blocks ----
#pragma unroll 1
    for (int blk2 = 0; blk2 < 2; ++blk2) {
        const bf16* w1 = blk2 ? r2w1 : r1w1;
        const bf16* w2 = blk2 ? r2w2 : r1w2;
        {
            const int co0 = wid * 16;
            f32x4 acc[5];
#pragma unroll
            for (int lf = 0; lf < 5; ++lf) acc[lf] = zf4;
#pragma unroll
            for (int k = 0; k < 3; ++k) {
                const bf16* Ab = w1 + (size_t)k * 64 * 128;
#pragma unroll
                for (int ks = 0; ks < 4; ++ks) {
                    s16x8 a = *(const s16x8*)(Ab + (co0 + lr) * 128 + ks * 32 + kg * 8);
                    s16x8 bfr[5];
#pragma unroll
                    for (int lf = 0; lf < 5; ++lf) {
                        int ry = lf * 16 + lr + k - 1;
                        ry = (ry < 0) ? 0 : (ry > 67 ? 67 : ry);
                        bfr[lf] = relu8(*(const s16x8*)(sY + ((ry * 136 + ks * 32 + kg * 8) << 1)));
                    }
#pragma unroll
                    for (int lf = 0; lf < 5; ++lf)
                        acc[lf] = MFMA16(a, bfr[lf], acc[lf]);
                }
            }
#pragma unroll
            for (int lf = 0; lf < 5; ++lf) {
                int row = lf * 16 + lr;
                if (row < 68) {
                    int ch0 = co0 + kg * 4;
                    *(uint2*)(sH + ((row * 72 + ch0) << 1)) =
                        pack4(fmaxf(acc[lf][0], 0.f), fmaxf(acc[lf][1], 0.f),
                              fmaxf(acc[lf][2], 0.f), fmaxf(acc[lf][3], 0.f));
                }
            }
        }
        __syncthreads();

        if (blk2 == 0) {
            const int co0 = wid * 32;
            f32x4 acc[2][5];
#pragma unroll
            for (int cf = 0; cf < 2; ++cf)
#pragma unroll
                for (int lf = 0; lf < 5; ++lf) acc[cf][lf] = zf4;
#pragma unroll
            for (int ks = 0; ks < 2; ++ks) {
                s16x8 af[2];
#pragma unroll
                for (int cf = 0; cf < 2; ++cf)
                    af[cf] = *(const s16x8*)(r1w2 + (size_t)(co0 + cf * 16 + lr) * 64 + ks * 32 + kg * 8);
                s16x8 bfr[5];
#pragma unroll
                for (int lf = 0; lf < 5; ++lf) {
                    int row = lf * 16 + lr;
                    int rc  = (row > 67) ? 67 : row;
                    bfr[lf] = *(const s16x8*)(sH + ((rc * 72 + ks * 32 + kg * 8) << 1));
                }
#pragma unroll
                for (int cf = 0; cf < 2; ++cf)
#pragma unroll
                    for (int lf = 0; lf < 5; ++lf)
                        acc[cf][lf] = MFMA16(af[cf], bfr[lf], acc[cf][lf]);
            }
#pragma unroll
            for (int cf = 0; cf < 2; ++cf)
#pragma unroll
                for (int lf = 0; lf < 5; ++lf) {
                    int row = lf * 16 + lr;
                    if (row < 68) {
                        int p   = l0 - 2 + row;
                        int cb0 = co0 + cf * 16 + kg * 4;
                        uint2 old = *(const uint2*)(sY + ((row * 136 + cb0) << 1));
                        bool ok = (p >= 0 && p < 1024);
                        float r0 = acc[cf][lf][0] + bf2f((unsigned short)(old.x & 0xffff));
                        float r1 = acc[cf][lf][1] + bf2f((unsigned short)(old.x >> 16));
                        float r2 = acc[cf][lf][2] + bf2f((unsigned short)(old.y & 0xffff));
                        float r3 = acc[cf][lf][3] + bf2f((unsigned short)(old.y >> 16));
                        uint2 pk = pack4(r0, r1, r2, r3);
                        if (!ok) { pk.x = 0u; pk.y = 0u; }
                        *(uint2*)(sY + ((row * 136 + cb0) << 1)) = pk;
                    }
                }
            __syncthreads();
        } else {
            // final: out = relu(Y + w2*H) rows 2..65 -> global
            const int co0 = wid * 32;
            f32x4 acc[2][4];
#pragma unroll
            for (int cf = 0; cf < 2; ++cf)
#pragma unroll
                for (int lf = 0; lf < 4; ++lf) acc[cf][lf] = zf4;
#pragma unroll
            for (int ks = 0; ks < 2; ++ks) {
                s16x8 af[2];
#pragma unroll
                for (int cf = 0; cf < 2; ++cf)
                    af[cf] = *(const s16x8*)(r2w2 + (size_t)(co0 + cf * 16 + lr) * 64 + ks * 32 + kg * 8);
                s16x8 bfr[4];
#pragma unroll
                for (int lf = 0; lf < 4; ++lf) {
                    int row = 2 + lf * 16 + lr;
                    bfr[lf] = *(const s16x8*)(sH + ((row * 72 + ks * 32 + kg * 8) << 1));
                }
#pragma unroll
                for (int cf = 0; cf < 2; ++cf)
#pragma unroll
                    for (int lf = 0; lf < 4; ++lf)
                        acc[cf][lf] = MFMA16(af[cf], bfr[lf], acc[cf][lf]);
            }
#pragma unroll
            for (int cf = 0; cf < 2; ++cf)
#pragma unroll
                for (int lf = 0; lf < 4; ++lf) {
                    int row = 2 + lf * 16 + lr;
                    int cb0 = co0 + cf * 16 + kg * 4;
                    uint2 old = *(const uint2*)(sY + ((row * 136 + cb0) << 1));
                    float r0 = fmaxf(acc[cf][lf][0] + bf2f((unsigned short)(old.x & 0xffff)), 0.f);
                    float r1 = fmaxf(acc[cf][lf][1] + bf2f((unsigned short)(old.x >> 16)), 0.f);
                    float r2 = fmaxf(acc[cf][lf][2] + bf2f((unsigned short)(old.y & 0xffff)), 0.f);
                    float r3 = fmaxf(acc[cf][lf][3] + bf2f((unsigned short)(old.y >> 16)), 0.f);
                    *(uint2*)(out + ((size_t)b * 1024 + l0 + lf * 16 + lr) * 128 + cb0) =
                        pack4(r0, r1, r2, r3);
                }
        }
    }
}

// ===========================================================================
// decmid: dec1 + res1 + res2(+relu) + ct1 convT (LDS-bounced stores).
// Y row r <-> pos l0-3+r, r in [0,70). Q row t <-> pos l0-4+t, t in [0,72).
// sY 70x272B @0 (19040); sQ 72x144B @19040 (10368); sH 70x144 aliases sQ.
// Total 29408B -> 5 blocks/CU.
// ===========================================================================
__global__ __launch_bounds__(256, 5) void decmid_k(
    const bf16* __restrict__ qin, const bf16* __restrict__ dw1,
    const float* __restrict__ db1, const bf16* __restrict__ r1w1,
    const bf16* __restrict__ r1w2, const bf16* __restrict__ r2w1,
    const bf16* __restrict__ r2w2, const bf16* __restrict__ ct1w,
    const float* __restrict__ ct1b, bf16* __restrict__ out)
{
    __shared__ __align__(16) char smem[29408];
    char* sY = smem;
    char* sQ = smem + 19040;
    char* sH = smem + 19040;
    const int tid = threadIdx.x;
    const int b   = blockIdx.y;
    const int l0  = blockIdx.x * 64;
    const bf16* inb = qin + (size_t)b * 1024 * 64;

    for (int i = tid; i < 72 * 8; i += 256) {
        int t = i >> 3, c0 = (i & 7) * 8;
        int g = l0 - 4 + t;
        s16x8 v = {};
        if (g >= 0 && g < 1024) v = *(const s16x8*)(inb + (size_t)g * 64 + c0);
        *(s16x8*)(sQ + ((t * 72 + c0) << 1)) = v;
    }
    __syncthreads();

    const int lane = tid & 63;
    const int wid  = __builtin_amdgcn_readfirstlane(tid >> 6);
    const int lr   = lane & 15;
    const int kg   = lane >> 4;
    const f32x4 zf4 = {0.f, 0.f, 0.f, 0.f};

    // ---- phase 1: dec1 -> sY rows [0,70), bias, OOR-zero ----
    {
        const int co0 = wid * 32;
        f32x4 acc[2][5];
#pragma unroll
        for (int cf = 0; cf < 2; ++cf)
#pragma unroll
            for (int lf = 0; lf < 5; ++lf) acc[cf][lf] = zf4;
#pragma unroll
        for (int k = 0; k < 3; ++k) {
            const bf16* Ab = dw1 + (size_t)k * 128 * 64;
#pragma unroll
            for (int ks = 0; ks < 2; ++ks) {
                s16x8 af[2];
#pragma unroll
                for (int cf = 0; cf < 2; ++cf)
                    af[cf] = *(const s16x8*)(Ab + (co0 + cf * 16 + lr) * 64 + ks * 32 + kg * 8);
                s16x8 bfr[5];
#pragma unroll
                for (int lf = 0; lf < 5; ++lf) {
                    int tx = lf * 16 + lr + k;         // t = r + k
                    tx = (tx > 71) ? 71 : tx;
                    bfr[lf] = *(const s16x8*)(sQ + ((tx * 72 + ks * 32 + kg * 8) << 1));
                }
#pragma unroll
                for (int cf = 0; cf < 2; ++cf)
#pragma unroll
                    for (int lf = 0; lf < 5; ++lf)
                        acc[cf][lf] = MFMA16(af[cf], bfr[lf], acc[cf][lf]);
            }
        }
        __syncthreads();   // sQ reads complete before sH alias overwrite
#pragma unroll
        for (int cf = 0; cf < 2; ++cf)
#pragma unroll
            for (int lf = 0; lf < 5; ++lf) {
                int row = lf * 16 + lr;
                if (row < 70) {
                    int p   = l0 - 3 + row;
                    int cb0 = co0 + cf * 16 + kg * 4;
                    bool ok = (p >= 0 && p < 1024);
                    float r[4];
#pragma unroll
                    for (int j = 0; j < 4; ++j)
                        r[j] = ok ? (acc[cf][lf][j] + db1[cb0 + j]) : 0.f;
                    *(uint2*)(sY + ((row * 136 + cb0) << 1)) = pack4(r[0], r[1], r[2], r[3]);
                }
            }
    }
    __syncthreads();

    // ---- res blocks ----
#pragma unroll 1
    for (int blk2 = 0; blk2 < 2; ++blk2) {
        const bf16* w1 = blk2 ? r2w1 : r1w1;
        const bf16* w2 = blk2 ? r2w2 : r1w2;
        {
            const int co0 = wid * 16;
            f32x4 acc[5];
#pragma unroll
            for (int lf = 0; lf < 5; ++lf) acc[lf] = zf4;
#pragma unroll
            for (int k = 0; k < 3; ++k) {
                const bf16* Ab = w1 + (size_t)k * 64 * 128;
#pragma unroll
                for (int ks = 0; ks < 4; ++ks) {
                    s16x8 a = *(const s16x8*)(Ab + (co0 + lr) * 128 + ks * 32 + kg * 8);
                    s16x8 bfr[5];
#pragma unroll
                    for (int lf = 0; lf < 5; ++lf) {
                        int ry = lf * 16 + lr + k - 1;
                        ry = (ry < 0) ? 0 : (ry > 69 ? 69 : ry);
                        bfr[lf] = relu8(*(const s16x8*)(sY + ((ry * 136 + ks * 32 + kg * 8) << 1)));
                    }
#pragma unroll
                    for (int lf = 0; lf < 5; ++lf)
                        acc[lf] = MFMA16(a, bfr[lf], acc[lf]);
                }
            }
#pragma unroll
            for (int lf = 0; lf < 5; ++lf) {
                int row = lf * 16 + lr;
                if (row < 70) {
                    int ch0 = co0 + kg * 4;
                    *(uint2*)(sH + ((row * 72 + ch0) << 1)) =
                        pack4(fmaxf(acc[lf][0], 0.f), fmaxf(acc[lf][1], 0.f),
                              fmaxf(acc[lf][2], 0.f), fmaxf(acc[lf][3], 0.f));
                }
            }
        }
        __syncthreads();
        {
            const int co0 = wid * 32;
            f32x4 acc[2][5];
#pragma unroll
            for (int cf = 0; cf < 2; ++cf)
#pragma unroll
                for (int lf = 0; lf < 5; ++lf) acc[cf][lf] = zf4;
#pragma unroll
            for (int ks = 0; ks < 2; ++ks) {
                s16x8 af[2];
#pragma unroll
                for (int cf = 0; cf < 2; ++cf)
                    af[cf] = *(const s16x8*)(w2 + (size_t)(co0 + cf * 16 + lr) * 64 + ks * 32 + kg * 8);
                s16x8 bfr[5];
#pragma unroll
                for (int lf = 0; lf < 5; ++lf) {
                    int row = lf * 16 + lr;
                    int rc  = (row > 69) ? 69 : row;
                    bfr[lf] = *(const s16x8*)(sH + ((rc * 72 + ks * 32 + kg * 8) << 1));
                }
#pragma unroll
                for (int cf = 0; cf < 2; ++cf)
#pragma unroll
                    for (int lf = 0; lf < 5; ++lf)
                        acc[cf][lf] = MFMA16(af[cf], bfr[lf], acc[cf][lf]);
            }
#pragma unroll
            for (int cf = 0; cf < 2; ++cf)
#pragma unroll
                for (int lf = 0; lf < 5; ++lf) {
                    int row = lf * 16 + lr;
                    if (row < 70) {
                        int p   = l0 - 3 + row;
                        int cb0 = co0 + cf * 16 + kg * 4;
                        uint2 old = *(const uint2*)(sY + ((row * 136 + cb0) << 1));
                        bool ok = (p >= 0 && p < 1024);
                        float r0 = acc[cf][lf][0] + bf2f((unsigned short)(old.x & 0xffff));
                        float r1 = acc[cf][lf][1] + bf2f((unsigned short)(old.x >> 16));
                        float r2 = acc[cf][lf][2] + bf2f((unsigned short)(old.y & 0xffff));
                        float r3 = acc[cf][lf][3] + bf2f((unsigned short)(old.y >> 16));
                        if (blk2 == 1) {
                            r0 = fmaxf(r0, 0.f); r1 = fmaxf(r1, 0.f);
                            r2 = fmaxf(r2, 0.f); r3 = fmaxf(r3, 0.f);
                        }
                        uint2 pk = pack4(r0, r1, r2, r3);
                        if (!ok) { pk.x = 0u; pk.y = 0u; }
                        *(uint2*)(sY + ((row * 136 + cb0) << 1)) = pk;
                    }
                }
        }
        __syncthreads();
    }

    // ---- ct1 convT (CO=64): Y row for pos m+doff is (m-l0)+3+doff ----
    {
        const int co0 = (wid & 1) * 32;
        const int mh  = wid >> 1;
        f32x4 acc[2][2][2];
#pragma unroll
        for (int g = 0; g < 2; ++g)
#pragma unroll
            for (int cf = 0; cf < 2; ++cf)
#pragma unroll
                for (int j = 0; j < 2; ++j) acc[g][cf][j] = zf4;
#pragma unroll
        for (int g = 0; g < 2; ++g)
#pragma unroll
            for (int k = 0; k < 2; ++k) {
                const bf16* Ab = ct1w + (size_t)(g * 2 + k) * 64 * 128;
                const int doff = (g == 0) ? (k - 1) : k;
#pragma unroll
                for (int ks = 0; ks < 4; ++ks) {
                    s16x8 af[2];
#pragma unroll
                    for (int cf = 0; cf < 2; ++cf)
                        af[cf] = *(const s16x8*)(Ab + (co0 + cf * 16 + lr) * 128 + ks * 32 + kg * 8);
                    s16x8 bfr[2];
#pragma unroll
                    for (int j = 0; j < 2; ++j) {
                        int ty = 3 + (mh * 2 + j) * 16 + lr + doff;
                        bfr[j] = *(const s16x8*)(sY + ((ty * 136 + ks * 32 + kg * 8) << 1));
                    }
#pragma unroll
                    for (int cf = 0; cf < 2; ++cf)
#pragma unroll
                        for (int j = 0; j < 2; ++j)
                            acc[g][cf][j] = MFMA16(af[cf], bfr[j], acc[g][cf][j]);
                }
            }
        __syncthreads();   // all sY reads done before bounce overwrite

        // bounce: sY region becomes [128 rows][64ch] linear (16KB)
#pragma unroll
        for (int g = 0; g < 2; ++g)
#pragma unroll
            for (int cf = 0; cf < 2; ++cf)
#pragma unroll
                for (int j = 0; j < 2; ++j) {
                    int m   = (mh * 2 + j) * 16 + lr;
                    int rr  = 2 * m + g;
                    int ch0 = co0 + cf * 16 + kg * 4;
                    float r[4];
#pragma unroll
                    for (int jj = 0; jj < 4; ++jj)
                        r[jj] = fmaxf(acc[g][cf][j][jj] + ct1b[ch0 + jj], 0.f);
                    *(uint2*)(sY + rr * 128 + ch0 * 2) = pack4(r[0], r[1], r[2], r[3]);
                }
        __syncthreads();

        bf16* ob = out + ((size_t)b * 2048 + 2 * l0) * 64;
        for (int i = tid; i < 1024; i += 256)
            *(s16x8*)(ob + i * 8) = *(const s16x8*)(sY + i * 16);
    }
}

// Fused enc1+enc2: x fp32 -> h1 (LDS, stride 72) -> enc2 GEMM -> bf16 relu.
__global__ __launch_bounds__(256) void enc12_k(
    const float* __restrict__ x, const float* __restrict__ w1,
    const float* __restrict__ b1, const bf16* __restrict__ w2t,
    const float* __restrict__ b2, bf16* __restrict__ out)
{
    __shared__ float sXf[268];
    __shared__ float sW1[256];
    __shared__ float sB1[64];
    __shared__ __align__(16) char sX[132 * 144];
    const int tid = threadIdx.x;
    const int b   = blockIdx.y;
    const int l0  = blockIdx.x * 64;
    const float* xb = x + (size_t)b * 4096;

    for (int i = tid; i < 266; i += 256) {
        int g = 4 * l0 - 3 + i;
        sXf[i] = (g >= 0 && g < 4096) ? xb[g] : 0.f;
    }
    if (tid < 256) sW1[tid] = w1[tid];
    if (tid < 64)  sB1[tid] = b1[tid];
    __syncthreads();

    for (int i = tid; i < 132 * 64; i += 256) {
        int t = i >> 6, c = i & 63;
        int p = (t < 66) ? 2 * (l0 + t) : 2 * (l0 + t - 66) - 1;
        float v = 0.f;
        if (p >= 0 && p < 2048) {
            int xi = 2 * p - 4 * l0 + 2;
            float a = sB1[c];
#pragma unroll
            for (int k = 0; k < 4; ++k) a = fmaf(sXf[xi + k], sW1[c * 4 + k], a);
            v = fmaxf(a, 0.f);
        }
        *(bf16*)(sX + ((t * 72 + c) << 1)) = __float2bfloat16(v);
    }
    __syncthreads();

    const int lane = tid & 63;
    const int wid  = __builtin_amdgcn_readfirstlane(tid >> 6);
    const int co0  = wid * 32;
    const int lr   = lane & 15;
    const int kg   = lane >> 4;

    f32x4 acc[2][4];
#pragma unroll
    for (int cf = 0; cf < 2; ++cf)
#pragma unroll
        for (int lf = 0; lf < 4; ++lf) acc[cf][lf] = (f32x4){0.f, 0.f, 0.f, 0.f};

#pragma unroll
    for (int k = 0; k < 4; ++k) {
        const int roff = (k == 0) ? 66 : (k == 1) ? 0 : (k == 2) ? 67 : 1;
        const bf16* Ab = w2t + (size_t)k * 128 * 64;
#pragma unroll
        for (int ks = 0; ks < 2; ++ks) {
            s16x8 af[2];
#pragma unroll
            for (int cf = 0; cf < 2; ++cf)
                af[cf] = *(const s16x8*)(Ab + (co0 + cf * 16 + lr) * 64 + ks * 32 + kg * 8);
            s16x8 bfr[4];
#pragma unroll
            for (int lf = 0; lf < 4; ++lf) {
                int t = roff + lf * 16 + lr;
                bfr[lf] = *(const s16x8*)(sX + ((t * 72 + ks * 32 + kg * 8) << 1));
            }
#pragma unroll
            for (int cf = 0; cf < 2; ++cf)
#pragma unroll
                for (int lf = 0; lf < 4; ++lf)
                    acc[cf][lf] = MFMA16(af[cf], bfr[lf], acc[cf][lf]);
        }
    }

#pragma unroll
    for (int cf = 0; cf < 2; ++cf)
#pragma unroll
        for (int lf = 0; lf < 4; ++lf) {
            int cb0  = co0 + cf * 16 + kg * 4;
            int lcol = lf * 16 + lr;
            float r[4];
#pragma unroll
            for (int j = 0; j < 4; ++j)
                r[j] = fmaxf(acc[cf][lf][j] + b2[cb0 + j], 0.f);
            *(uint2*)(out + ((size_t)b * 1024 + l0 + lcol) * 128 + cb0) =
                pack4(r[0], r[1], r[2], r[3]);
        }
}

// Final convT: 64->1 ch, x2 upsample; fp32 out.
__global__ __launch_bounds__(256) void ct2_k(
    const bf16* __restrict__ in, const float* __restrict__ w,
    const float* __restrict__ bias, float* __restrict__ out)
{
    __shared__ __align__(16) char sX[258 * 144];
    const int tid = threadIdx.x;
    const int b   = blockIdx.y;
    const int m0  = blockIdx.x * 256;
    const bf16* inb = in + (size_t)b * 2048 * 64;
    for (int i = tid; i < 258 * 8; i += 256) {
        int t = i >> 3, c0 = (i & 7) * 8;
        int g = m0 - 1 + t;
        s16x8 v = {};
        if (g >= 0 && g < 2048) v = *(const s16x8*)(inb + (size_t)g * 64 + c0);
        *(s16x8*)(sX + ((t * 72 + c0) << 1)) = v;
    }
    __syncthreads();
    float e = bias[0], o = bias[0];
#pragma unroll
    for (int c0 = 0; c0 < 64; c0 += 8) {
        s16x8 vm1 = *(const s16x8*)(sX + (((tid + 0) * 72 + c0) << 1));
        s16x8 v0  = *(const s16x8*)(sX + (((tid + 1) * 72 + c0) << 1));
        s16x8 vp1 = *(const s16x8*)(sX + (((tid + 2) * 72 + c0) << 1));
#pragma unroll
        for (int j = 0; j < 8; ++j) {
            int ci = c0 + j;
            float xm1 = bf2f((unsigned short)vm1[j]);
            float x0  = bf2f((unsigned short)v0[j]);
            float xp1 = bf2f((unsigned short)vp1[j]);
            e = fmaf(x0,  w[ci * 4 + 1], fmaf(xm1, w[ci * 4 + 3], e));
            o = fmaf(xp1, w[ci * 4 + 0], fmaf(x0,  w[ci * 4 + 2], o));
        }
    }
    int m = m0 + tid;
    out[(size_t)b * 4096 + 2 * m]     = e;
    out[(size_t)b * 4096 + 2 * m + 1] = o;
}

// Weight transform: fp32 conv weights -> bf16 [tap][co][ci] matrices.
__global__ __launch_bounds__(256) void wx_k(
    const float* ew2, const float* ew3, const float* er1a, const float* er1b,
    const float* er2a, const float* er2b, const float* pvw, const float* dw1,
    const float* dr1a, const float* dr1b, const float* dr2a, const float* dr2b,
    const float* ct1w, bf16* wb)
{
    const int job = blockIdx.x;
    bf16* dst = wb + (size_t)job * 65536;
    const float* src; int CO, CI, K;
    switch (job) {
        case 0:  src = ew2;  CO = 128; CI = 64;  K = 4; break;
        case 1:  src = ew3;  CO = 128; CI = 128; K = 3; break;
        case 2:  src = er1a; CO = 64;  CI = 128; K = 3; break;
        case 3:  src = er1b; CO = 128; CI = 64;  K = 1; break;
        case 4:  src = er2a; CO = 64;  CI = 128; K = 3; break;
        case 5:  src = er2b; CO = 128; CI = 64;  K = 1; break;
        case 6:  src = pvw;  CO = 64;  CI = 128; K = 1; break;
        case 7:  src = dw1;  CO = 128; CI = 64;  K = 3; break;
        case 8:  src = dr1a; CO = 64;  CI = 128; K = 3; break;
        case 9:  src = dr1b; CO = 128; CI = 64;  K = 1; break;
        case 10: src = dr2a; CO = 64;  CI = 128; K = 3; break;
        case 11: src = dr2b; CO = 128; CI = 64;  K = 1; break;
        default: src = ct1w; CO = 64;  CI = 128; K = 4; break;
    }
    const int tot = CO * CI * K;
    for (int i = blockIdx.y * 256 + threadIdx.x; i < tot; i += gridDim.y * 256) {
        if (job < 12) {
            int k = i / (CO * CI); int r = i - k * CO * CI;
            int co = r / CI; int ci = r - co * CI;
            dst[i] = __float2bfloat16(src[((size_t)co * CI + ci) * K + k]);
        } else {
            const int TAP[4] = {3, 1, 2, 0};
            int g = i / (64 * 128); int r = i - g * 64 * 128;
            int co = r / 128; int ci = r - co * 128;
            dst[i] = __float2bfloat16(src[((size_t)ci * 64 + co) * 4 + TAP[g]]);
        }
    }
}

// codebook prep: fp32 norms + hi/lo bf16 split
__global__ __launch_bounds__(256) void cbprep_k(
    const float* __restrict__ cb, bf16* __restrict__ cbh, bf16* __restrict__ cbl,
    float* __restrict__ sc)
{
    int k = blockIdx.x * 256 + threadIdx.x;
    const float* c = cb + (size_t)k * 64;
    float s = 0.f;
#pragma unroll
    for (int d = 0; d < 64; ++d) s = fmaf(c[d], c[d], s);
    sc[k] = s;
#pragma unroll
    for (int c0 = 0; c0 < 64; c0 += 8) {
        union { unsigned short u[8]; s16x8 v; } ph, pl;
#pragma unroll
        for (int j = 0; j < 8; ++j) {
            float v = c[c0 + j];
            unsigned short h = bfbits(v);
            ph.u[j] = h;
            pl.u[j] = bfbits(v - bf2f(h));
        }
        *(s16x8*)(cbh + (size_t)k * 64 + c0) = ph.v;
        *(s16x8*)(cbl + (size_t)k * 64 + c0) = pl.v;
    }
}

// Fused pre_vq + VQ. 1024 blocks x 128 positions. A tile / z tile alias.
__global__ __launch_bounds__(256, 4) void vqf_k(
    const bf16* __restrict__ A, const bf16* __restrict__ pvw,
    const float* __restrict__ pvb, const float* __restrict__ cbf,
    const bf16* __restrict__ cbh, const bf16* __restrict__ cbl,
    const float* __restrict__ sc, bf16* __restrict__ q,
    float* __restrict__ counts, float* __restrict__ loss_sum)
{
    __shared__ __align__(16) char sMem[34816];
    __shared__ float sSC[512];
    __shared__ float sHist[512];
    __shared__ int   sBK[128];
    __shared__ float sWS[4];
    const int tid = threadIdx.x;
    sSC[tid] = sc[tid]; sSC[tid + 256] = sc[tid + 256];
    sHist[tid] = 0.f;   sHist[tid + 256] = 0.f;

    const int n0 = blockIdx.x * 128;
    for (int i = tid; i < 128 * 16; i += 256) {
        int t = i >> 4, c0 = (i & 15) * 8;
        s16x8 v = *(const s16x8*)(A + (size_t)(n0 + t) * 128 + c0);
        *(s16x8*)(sMem + ((t * 136 + c0) << 1)) = v;
    }
    __syncthreads();

    const int lane = tid & 63, wid = tid >> 6;
    const int lr = lane & 15, kg = lane >> 4;
    const int pw0 = wid * 32;
    const f32x4 zf4 = {0.f, 0.f, 0.f, 0.f};

    f32x4 zacc[4][2];
#pragma unroll
    for (int cf = 0; cf < 4; ++cf)
#pragma unroll
        for (int lf = 0; lf < 2; ++lf) zacc[cf][lf] = zf4;
#pragma unroll
    for (int ks = 0; ks < 4; ++ks) {
        s16x8 af[4];
#pragma unroll
        for (int cf = 0; cf < 4; ++cf)
            af[cf] = *(const s16x8*)(pvw + (size_t)(cf * 16 + lr) * 128 + ks * 32 + kg * 8);
        s16x8 bfr[2];
#pragma unroll
        for (int lf = 0; lf < 2; ++lf) {
            int t = pw0 + lf * 16 + lr;
            bfr[lf] = *(const s16x8*)(sMem + ((t * 136 + ks * 32 + kg * 8) << 1));
        }
#pragma unroll
        for (int cf = 0; cf < 4; ++cf)
#pragma unroll
            for (int lf = 0; lf < 2; ++lf)
                zacc[cf][lf] = MFMA16(af[cf], bfr[lf], zacc[cf][lf]);
    }
    __syncthreads();

#pragma unroll
    for (int cf = 0; cf < 4; ++cf)
#pragma unroll
        for (int lf = 0; lf < 2; ++lf) {
            int pos = pw0 + lf * 16 + lr;
            int ch  = cf * 16 + kg * 4;
            float4 v = make_float4(zacc[cf][lf][0] + pvb[ch],
                                   zacc[cf][lf][1] + pvb[ch + 1],
                                   zacc[cf][lf][2] + pvb[ch + 2],
                                   zacc[cf][lf][3] + pvb[ch + 3]);
            *(float4*)(sMem + (pos * 68 + ch) * 4) = v;
        }
    __syncthreads();

    s16x8 bh[2][2], bl[2][2];
#pragma unroll
    for (int lf = 0; lf < 2; ++lf)
#pragma unroll
        for (int ks = 0; ks < 2; ++ks) {
            int t = pw0 + lf * 16 + lr;
            int ch = ks * 32 + kg * 8;
            float4 v0 = *(const float4*)(sMem + (t * 68 + ch) * 4);
            float4 v1 = *(const float4*)(sMem + (t * 68 + ch) * 4 + 16);
            float v[8] = {v0.x, v0.y, v0.z, v0.w, v1.x, v1.y, v1.z, v1.w};
            union { unsigned short u[8]; s16x8 s; } ph, pl;
#pragma unroll
            for (int j = 0; j < 8; ++j) {
                unsigned short h = bfbits(v[j]);
                ph.u[j] = h;
                pl.u[j] = bfbits(v[j] - bf2f(h));
            }
            bh[lf][ks] = ph.s; bl[lf][ks] = pl.s;
        }

    float bestd[2] = {3.4e38f, 3.4e38f};
    int   bestk[2] = {0, 0};
#pragma unroll 2
    for (int cf = 0; cf < 32; ++cf) {
        int code = cf * 16 + lr;
        const bf16* ph = cbh + code * 64 + kg * 8;
        const bf16* pl = cbl + code * 64 + kg * 8;
        s16x8 ah0 = *(const s16x8*)ph;
        s16x8 ah1 = *(const s16x8*)(ph + 32);
        s16x8 al0 = *(const s16x8*)pl;
        s16x8 al1 = *(const s16x8*)(pl + 32);
        float s0 = sSC[cf * 16 + kg * 4 + 0];
        float s1 = sSC[cf * 16 + kg * 4 + 1];
        float s2 = sSC[cf * 16 + kg * 4 + 2];
        float s3 = sSC[cf * 16 + kg * 4 + 3];
        int kb = cf * 16 + kg * 4;
#pragma unroll
        for (int lf = 0; lf < 2; ++lf) {
            f32x4 acc = MFMA16(ah0, bh[lf][0], zf4);
            acc = MFMA16(ah1, bh[lf][1], acc);
            acc = MFMA16(al0, bh[lf][0], acc);
            acc = MFMA16(al1, bh[lf][1], acc);
            acc = MFMA16(ah0, bl[lf][0], acc);
            acc = MFMA16(ah1, bl[lf][1], acc);
            float d0 = fmaf(acc[0], -2.f, s0);
            float d1 = fmaf(acc[1], -2.f, s1);
            float d2 = fmaf(acc[2], -2.f, s2);
            float d3 = fmaf(acc[3], -2.f, s3);
            if (d0 < bestd[lf]) { bestd[lf] = d0; bestk[lf] = kb; }
            if (d1 < bestd[lf]) { bestd[lf] = d1; bestk[lf] = kb + 1; }
            if (d2 < bestd[lf]) { bestd[lf] = d2; bestk[lf] = kb + 2; }
            if (d3 < bestd[lf]) { bestd[lf] = d3; bestk[lf] = kb + 3; }
        }
    }
#pragma unroll
    for (int lf = 0; lf < 2; ++lf) {
#pragma unroll
        for (int off = 16; off <= 32; off <<= 1) {
            float od = __shfl_xor(bestd[lf], off, 64);
            int   ok = __shfl_xor(bestk[lf], off, 64);
            if (od < bestd[lf] || (od == bestd[lf] && ok < bestk[lf])) {
                bestd[lf] = od; bestk[lf] = ok;
            }
        }
        if (kg == 0) sBK[pw0 + lf * 16 + lr] = bestk[lf];
    }
    __syncthreads();

    const int pos  = tid >> 1;
    const int half = tid & 1;
    const int k = sBK[pos];
    if (half == 0) atomicAdd(&sHist[k], 1.f);
    float lsum = 0.f;
    const float* qp = cbf + (size_t)k * 64 + half * 32;
    bf16* qo = q + (size_t)(n0 + pos) * 64 + half * 32;
#pragma unroll
    for (int c0 = 0; c0 < 32; c0 += 8) {
        int zb = (pos * 68 + half * 32 + c0) * 4;
        float4 z0 = *(const float4*)(sMem + zb);
        float4 z1 = *(const float4*)(sMem + zb + 16);
        float4 q0 = *(const float4*)(qp + c0);
        float4 q1 = *(const float4*)(qp + c0 + 4);
        float qv[8] = {q0.x, q0.y, q0.z, q0.w, q1.x, q1.y, q1.z, q1.w};
        float zv[8] = {z0.x, z0.y, z0.z, z0.w, z1.x, z1.y, z1.z, z1.w};
        union { unsigned short u[8]; s16x8 v; } pk;
#pragma unroll
        for (int j = 0; j < 8; ++j) {
            float d = qv[j] - zv[j];
            lsum = fmaf(d, d, lsum);
            pk.u[j] = bfbits(qv[j]);
        }
        *(s16x8*)(qo + c0) = pk.v;
    }
#pragma unroll
    for (int off = 32; off > 0; off >>= 1) lsum += __shfl_down(lsum, off, 64);
    if ((tid & 63) == 0) sWS[tid >> 6] = lsum;
    __syncthreads();
    if (tid == 0) atomicAdd(loss_sum, sWS[0] + sWS[1] + sWS[2] + sWS[3]);
    float c0v = sHist[tid];       if (c0v != 0.f) atomicAdd(&counts[tid], c0v);
    float c1v = sHist[tid + 256]; if (c1v != 0.f) atomicAdd(&counts[tid + 256], c1v);
}

__global__ __launch_bounds__(512) void finalize_k(
    const float* __restrict__ counts, const float* __restrict__ loss_sum,
    float* __restrict__ d_out, int out_size)
{
    __shared__ float ws2[8];
    const int tid = threadIdx.x;
    float p = counts[tid] * (1.f / 131072.f);
    float e = p * logf(p + 1e-10f);
#pragma unroll
    for (int off = 32; off > 0; off >>= 1) e += __shfl_down(e, off, 64);
    const int lane = tid & 63, wid = tid >> 6;
    if (lane == 0) ws2[wid] = e;
    __syncthreads();
    if (tid == 0) {
        float s = 0.f;
        for (int i = 0; i < 8; ++i) s += ws2[i];
        d_out[0] = 1.25f * loss_sum[0] * (1.f / 8388608.f);  // (1+BETA)*mean
        d_out[out_size - 1] = expf(-s);
    }
}

extern "C" void kernel_launch(void* const* d_in, const int* in_sizes, int n_in,
                              void* d_out, int out_size, void* d_ws, size_t ws_size,
                              hipStream_t stream)
{
    const float* x        = (const float*)d_in[0];
    const float* enc_w1   = (const float*)d_in[1];
    const float* enc_b1   = (const float*)d_in[2];
    const float* enc_b2   = (const float*)d_in[4];
    const float* enc_b3   = (const float*)d_in[6];
    const float* pre_vq_b = (const float*)d_in[12];
    const float* cb       = (const float*)d_in[13];
    const float* dec_b1   = (const float*)d_in[15];
    const float* ct1_b    = (const float*)d_in[21];
    const float* ct2_w    = (const float*)d_in[22];
    const float* ct2_b    = (const float*)d_in[23];
    float* out = (float*)d_out;

    char* base = (char*)d_ws;
    bf16*  wb   = (bf16*)base;
    bf16*  Abf  = (bf16*)(base + ((size_t)2   << 20));
    bf16*  Bbf  = (bf16*)(base + ((size_t)40  << 20));
    bf16*  Qbf  = (bf16*)(base + ((size_t)78  << 20));
    bf16*  cbh  = (bf16*)(base + ((size_t)96  << 20));
    bf16*  cbl  = (bf16*)(base + ((size_t)96  << 20) + 65536);
    float* sc   = (float*)(base + ((size_t)96  << 20) + 131072);
    float* cnt  = sc + 512;
    float* lsum = cnt + 512;

    (void)hipMemsetAsync(cnt, 0, 513 * sizeof(float), stream);

    dim3 blk(256);
    dim3 g16(16, 128);

    wx_k<<<dim3(13, 8), blk, 0, stream>>>(
        (const float*)d_in[3], (const float*)d_in[5], (const float*)d_in[7],
        (const float*)d_in[8], (const float*)d_in[9], (const float*)d_in[10],
        (const float*)d_in[11], (const float*)d_in[14], (const float*)d_in[16],
        (const float*)d_in[17], (const float*)d_in[18], (const float*)d_in[19],
        (const float*)d_in[20], wb);
    cbprep_k<<<2, blk, 0, stream>>>(cb, cbh, cbl, sc);

    enc12_k<<<g16, blk, 0, stream>>>(x, enc_w1, enc_b1, wb + 0 * 65536, enc_b2, Bbf);
    encmid_k<<<g16, blk, 0, stream>>>(Bbf, wb + 1 * 65536, enc_b3,
        wb + 2 * 65536, wb + 3 * 65536, wb + 4 * 65536, wb + 5 * 65536, Abf);

    vqf_k<<<1024, blk, 0, stream>>>(Abf, wb + 6 * 65536, pre_vq_b, cb,
                                    cbh, cbl, sc, Qbf, cnt, lsum);

    decmid_k<<<g16, blk, 0, stream>>>(Qbf, wb + 7 * 65536, dec_b1,
        wb + 8 * 65536, wb + 9 * 65536, wb + 10 * 65536, wb + 11 * 65536,
        wb + 12 * 65536, ct1_b, Bbf);

    ct2_k<<<dim3(8, 128), blk, 0, stream>>>(Bbf, ct2_w, ct2_b, out + 1);
    finalize_k<<<1, 512, 0, stream>>>(cnt, lsum, out, out_size);
}

// Round 13
// 368.988 us; speedup vs baseline: 1.9346x; 1.2047x over previous
//
#include <hip/hip_runtime.h>
#include <hip/hip_bf16.h>
#include <math.h>

using bf16 = __hip_bfloat16;
typedef __attribute__((ext_vector_type(4))) float f32x4;
typedef __attribute__((ext_vector_type(8))) short s16x8;

#define MFMA16(a,b,c) __builtin_amdgcn_mfma_f32_16x16x32_bf16((a),(b),(c),0,0,0)

// ---------------------------------------------------------------------------
// VQ-VAE forward. B=128, L=4096, H=128, RH=64, D=64, K=512.
// Round-9 structure (proven 357.6us) + ct1 LDS store-bounce in decmid.
// ---------------------------------------------------------------------------

__device__ inline float bf2f(unsigned short u) {
    union { float f; unsigned v; } c; c.v = ((unsigned)u) << 16; return c.f;
}
__device__ inline unsigned short bfbits(float f) {
    union { bf16 h; unsigned short u; } c; c.h = __float2bfloat16(f); return c.u;
}
__device__ inline s16x8 relu8(s16x8 v) {
#pragma unroll
    for (int j = 0; j < 8; ++j)
        v[j] = (short)(((unsigned short)v[j] & 0x8000u) ? 0 : (unsigned short)v[j]);
    return v;
}
__device__ inline uint2 pack4(float a, float b, float c, float d) {
    uint2 p;
    p.x = (unsigned)bfbits(a) | ((unsigned)bfbits(b) << 16);
    p.y = (unsigned)bfbits(c) | ((unsigned)bfbits(d) << 16);
    return p;
}

// ===========================================================================
// encmid: enc3 (128->128 K3) + res1 + res2 + final relu.  Bbf -> Abf.
// sY 80x272B @0; sX 96x272B @21760; sH 80x144B aliases sX. 3 blocks/CU.
// ===========================================================================
__global__ __launch_bounds__(256, 3) void encmid_k(
    const bf16* __restrict__ in, const bf16* __restrict__ w3t,
    const float* __restrict__ b3, const bf16* __restrict__ r1w1,
    const bf16* __restrict__ r1w2, const bf16* __restrict__ r2w1,
    const bf16* __restrict__ r2w2, bf16* __restrict__ out)
{
    __shared__ __align__(16) char smem[47872];
    char* sY = smem;
    char* sX = smem + 21760;
    char* sH = smem + 21760;
    const int tid = threadIdx.x;
    const int b   = blockIdx.y;
    const int l0  = blockIdx.x * 64;
    const bf16* inb = in + (size_t)b * 1024 * 128;

    for (int i = tid; i < 96 * 16; i += 256) {
        int t = i >> 4, c0 = (i & 15) * 8;
        int g = l0 - 16 + t;
        s16x8 v = {};
        if (g >= 0 && g < 1024) v = *(const s16x8*)(inb + (size_t)g * 128 + c0);
        *(s16x8*)(sX + ((t * 136 + c0) << 1)) = v;
    }
    __syncthreads();

    const int lane = tid & 63;
    const int wid  = __builtin_amdgcn_readfirstlane(tid >> 6);
    const int lr   = lane & 15;
    const int kg   = lane >> 4;
    const f32x4 zf4 = {0.f, 0.f, 0.f, 0.f};

    // ---- phase 1: enc3 -> sY (80 rows x 128 co), bias, OOR-zero ----
    {
        const int co0 = wid * 32;
        f32x4 acc[2][5];
#pragma unroll
        for (int cf = 0; cf < 2; ++cf)
#pragma unroll
            for (int lf = 0; lf < 5; ++lf) acc[cf][lf] = zf4;
#pragma unroll
        for (int k = 0; k < 3; ++k) {
            const bf16* Ab = w3t + (size_t)k * 128 * 128;
#pragma unroll
            for (int ks = 0; ks < 4; ++ks) {
                s16x8 af[2];
#pragma unroll
                for (int cf = 0; cf < 2; ++cf)
                    af[cf] = *(const s16x8*)(Ab + (co0 + cf * 16 + lr) * 128 + ks * 32 + kg * 8);
                s16x8 bfr[5];
#pragma unroll
                for (int lf = 0; lf < 5; ++lf) {
                    int tx = lf * 16 + lr + 7 + k;
                    bfr[lf] = *(const s16x8*)(sX + ((tx * 136 + ks * 32 + kg * 8) << 1));
                }
#pragma unroll
                for (int cf = 0; cf < 2; ++cf)
#pragma unroll
                    for (int lf = 0; lf < 5; ++lf)
                        acc[cf][lf] = MFMA16(af[cf], bfr[lf], acc[cf][lf]);
            }
        }
        __syncthreads();   // sX reads done before sH alias writes later
#pragma unroll
        for (int cf = 0; cf < 2; ++cf)
#pragma unroll
            for (int lf = 0; lf < 5; ++lf) {
                int row = lf * 16 + lr;
                int p   = l0 - 8 + row;
                int cb0 = co0 + cf * 16 + kg * 4;
                bool ok = (p >= 0 && p < 1024);
                float r[4];
#pragma unroll
                for (int j = 0; j < 4; ++j)
                    r[j] = ok ? (acc[cf][lf][j] + b3[cb0 + j]) : 0.f;
                *(uint2*)(sY + ((row * 136 + cb0) << 1)) = pack4(r[0], r[1], r[2], r[3]);
            }
    }
    __syncthreads();

    // ---- phases 2..5: two res blocks ----
#pragma unroll 1
    for (int blk2 = 0; blk2 < 2; ++blk2) {
        const bf16* w1 = blk2 ? r2w1 : r1w1;
        {
            const int co0 = wid * 16;
            f32x4 acc[5];
#pragma unroll
            for (int lf = 0; lf < 5; ++lf) acc[lf] = zf4;
#pragma unroll
            for (int k = 0; k < 3; ++k) {
                const bf16* Ab = w1 + (size_t)k * 64 * 128;
#pragma unroll
                for (int ks = 0; ks < 4; ++ks) {
                    s16x8 a = *(const s16x8*)(Ab + (co0 + lr) * 128 + ks * 32 + kg * 8);
                    s16x8 bfr[5];
#pragma unroll
                    for (int lf = 0; lf < 5; ++lf) {
                        int ry = lf * 16 + lr + k - 1;
                        ry = (ry < 0) ? 0 : (ry > 79 ? 79 : ry);
                        bfr[lf] = relu8(*(const s16x8*)(sY + ((ry * 136 + ks * 32 + kg * 8) << 1)));
                    }
#pragma unroll
                    for (int lf = 0; lf < 5; ++lf)
                        acc[lf] = MFMA16(a, bfr[lf], acc[lf]);
                }
            }
#pragma unroll
            for (int lf = 0; lf < 5; ++lf) {
                int row = lf * 16 + lr;
                int ch0 = co0 + kg * 4;
                *(uint2*)(sH + ((row * 72 + ch0) << 1)) =
                    pack4(fmaxf(acc[lf][0], 0.f), fmaxf(acc[lf][1], 0.f),
                          fmaxf(acc[lf][2], 0.f), fmaxf(acc[lf][3], 0.f));
            }
        }
        __syncthreads();

        if (blk2 == 0) {
            const int co0 = wid * 32;
            f32x4 acc[2][5];
#pragma unroll
            for (int cf = 0; cf < 2; ++cf)
#pragma unroll
                for (int lf = 0; lf < 5; ++lf) acc[cf][lf] = zf4;
#pragma unroll
            for (int ks = 0; ks < 2; ++ks) {
                s16x8 af[2];
#pragma unroll
                for (int cf = 0; cf < 2; ++cf)
                    af[cf] = *(const s16x8*)(r1w2 + (size_t)(co0 + cf * 16 + lr) * 64 + ks * 32 + kg * 8);
                s16x8 bfr[5];
#pragma unroll
                for (int lf = 0; lf < 5; ++lf) {
                    int row = lf * 16 + lr;
                    bfr[lf] = *(const s16x8*)(sH + ((row * 72 + ks * 32 + kg * 8) << 1));
                }
#pragma unroll
                for (int cf = 0; cf < 2; ++cf)
#pragma unroll
                    for (int lf = 0; lf < 5; ++lf)
                        acc[cf][lf] = MFMA16(af[cf], bfr[lf], acc[cf][lf]);
            }
#pragma unroll
            for (int cf = 0; cf < 2; ++cf)
#pragma unroll
                for (int lf = 0; lf < 5; ++lf) {
                    int row = lf * 16 + lr;
                    int p   = l0 - 8 + row;
                    int cb0 = co0 + cf * 16 + kg * 4;
                    uint2 old = *(const uint2*)(sY + ((row * 136 + cb0) << 1));
                    bool ok = (p >= 0 && p < 1024);
                    float r0 = acc[cf][lf][0] + bf2f((unsigned short)(old.x & 0xffff));
                    float r1 = acc[cf][lf][1] + bf2f((unsigned short)(old.x >> 16));
                    float r2 = acc[cf][lf][2] + bf2f((unsigned short)(old.y & 0xffff));
                    float r3 = acc[cf][lf][3] + bf2f((unsigned short)(old.y >> 16));
                    uint2 pk = pack4(r0, r1, r2, r3);
                    if (!ok) { pk.x = 0u; pk.y = 0u; }
                    *(uint2*)(sY + ((row * 136 + cb0) << 1)) = pk;
                }
            __syncthreads();
        } else {
            const int co0 = wid * 32;
            f32x4 acc[2][4];
#pragma unroll
            for (int cf = 0; cf < 2; ++cf)
#pragma unroll
                for (int lf = 0; lf < 4; ++lf) acc[cf][lf] = zf4;
#pragma unroll
            for (int ks = 0; ks < 2; ++ks) {
                s16x8 af[2];
#pragma unroll
                for (int cf = 0; cf < 2; ++cf)
                    af[cf] = *(const s16x8*)(r2w2 + (size_t)(co0 + cf * 16 + lr) * 64 + ks * 32 + kg * 8);
                s16x8 bfr[4];
#pragma unroll
                for (int lf = 0; lf < 4; ++lf) {
                    int row = 8 + lf * 16 + lr;
                    bfr[lf] = *(const s16x8*)(sH + ((row * 72 + ks * 32 + kg * 8) << 1));
                }
#pragma unroll
                for (int cf = 0; cf < 2; ++cf)
#pragma unroll
                    for (int lf = 0; lf < 4; ++lf)
                        acc[cf][lf] = MFMA16(af[cf], bfr[lf], acc[cf][lf]);
            }
#pragma unroll
            for (int cf = 0; cf < 2; ++cf)
#pragma unroll
                for (int lf = 0; lf < 4; ++lf) {
                    int row = 8 + lf * 16 + lr;
                    int cb0 = co0 + cf * 16 + kg * 4;
                    uint2 old = *(const uint2*)(sY + ((row * 136 + cb0) << 1));
                    float r0 = fmaxf(acc[cf][lf][0] + bf2f((unsigned short)(old.x & 0xffff)), 0.f);
                    float r1 = fmaxf(acc[cf][lf][1] + bf2f((unsigned short)(old.x >> 16)), 0.f);
                    float r2 = fmaxf(acc[cf][lf][2] + bf2f((unsigned short)(old.y & 0xffff)), 0.f);
                    float r3 = fmaxf(acc[cf][lf][3] + bf2f((unsigned short)(old.y >> 16)), 0.f);
                    *(uint2*)(out + ((size_t)b * 1024 + l0 + lf * 16 + lr) * 128 + cb0) =
                        pack4(r0, r1, r2, r3);
                }
        }
    }
}

// ===========================================================================
// decmid: dec1 + res1 + res2(+relu) + ct1 convT (LDS-bounced stores).
// sY 80x272B @0; sQ 96x144B @21760; sH aliases sQ. 4 blocks/CU.
// ===========================================================================
__global__ __launch_bounds__(256, 4) void decmid_k(
    const bf16* __restrict__ qin, const bf16* __restrict__ dw1,
    const float* __restrict__ db1, const bf16* __restrict__ r1w1,
    const bf16* __restrict__ r1w2, const bf16* __restrict__ r2w1,
    const bf16* __restrict__ r2w2, const bf16* __restrict__ ct1w,
    const float* __restrict__ ct1b, bf16* __restrict__ out)
{
    __shared__ __align__(16) char smem[35584];
    char* sY = smem;
    char* sQ = smem + 21760;
    char* sH = smem + 21760;
    const int tid = threadIdx.x;
    const int b   = blockIdx.y;
    const int l0  = blockIdx.x * 64;
    const bf16* inb = qin + (size_t)b * 1024 * 64;

    for (int i = tid; i < 96 * 8; i += 256) {
        int t = i >> 3, c0 = (i & 7) * 8;
        int g = l0 - 16 + t;
        s16x8 v = {};
        if (g >= 0 && g < 1024) v = *(const s16x8*)(inb + (size_t)g * 64 + c0);
        *(s16x8*)(sQ + ((t * 72 + c0) << 1)) = v;
    }
    __syncthreads();

    const int lane = tid & 63;
    const int wid  = __builtin_amdgcn_readfirstlane(tid >> 6);
    const int lr   = lane & 15;
    const int kg   = lane >> 4;
    const f32x4 zf4 = {0.f, 0.f, 0.f, 0.f};

    // ---- phase 1: dec1 -> sY, bias, OOR-zero ----
    {
        const int co0 = wid * 32;
        f32x4 acc[2][5];
#pragma unroll
        for (int cf = 0; cf < 2; ++cf)
#pragma unroll
            for (int lf = 0; lf < 5; ++lf) acc[cf][lf] = zf4;
#pragma unroll
        for (int k = 0; k < 3; ++k) {
            const bf16* Ab = dw1 + (size_t)k * 128 * 64;
#pragma unroll
            for (int ks = 0; ks < 2; ++ks) {
                s16x8 af[2];
#pragma unroll
                for (int cf = 0; cf < 2; ++cf)
                    af[cf] = *(const s16x8*)(Ab + (co0 + cf * 16 + lr) * 64 + ks * 32 + kg * 8);
                s16x8 bfr[5];
#pragma unroll
                for (int lf = 0; lf < 5; ++lf) {
                    int tx = lf * 16 + lr + 7 + k;
                    bfr[lf] = *(const s16x8*)(sQ + ((tx * 72 + ks * 32 + kg * 8) << 1));
                }
#pragma unroll
                for (int cf = 0; cf < 2; ++cf)
#pragma unroll
                    for (int lf = 0; lf < 5; ++lf)
                        acc[cf][lf] = MFMA16(af[cf], bfr[lf], acc[cf][lf]);
            }
        }
        __syncthreads();   // sQ reads complete before sH alias overwrite
#pragma unroll
        for (int cf = 0; cf < 2; ++cf)
#pragma unroll
            for (int lf = 0; lf < 5; ++lf) {
                int row = lf * 16 + lr;
                int p   = l0 - 8 + row;
                int cb0 = co0 + cf * 16 + kg * 4;
                bool ok = (p >= 0 && p < 1024);
                float r[4];
#pragma unroll
                for (int j = 0; j < 4; ++j)
                    r[j] = ok ? (acc[cf][lf][j] + db1[cb0 + j]) : 0.f;
                *(uint2*)(sY + ((row * 136 + cb0) << 1)) = pack4(r[0], r[1], r[2], r[3]);
            }
    }
    __syncthreads();

    // ---- res blocks ----
#pragma unroll 1
    for (int blk2 = 0; blk2 < 2; ++blk2) {
        const bf16* w1 = blk2 ? r2w1 : r1w1;
        const bf16* w2 = blk2 ? r2w2 : r1w2;
        {
            const int co0 = wid * 16;
            f32x4 acc[5];
#pragma unroll
            for (int lf = 0; lf < 5; ++lf) acc[lf] = zf4;
#pragma unroll
            for (int k = 0; k < 3; ++k) {
                const bf16* Ab = w1 + (size_t)k * 64 * 128;
#pragma unroll
                for (int ks = 0; ks < 4; ++ks) {
                    s16x8 a = *(const s16x8*)(Ab + (co0 + lr) * 128 + ks * 32 + kg * 8);
                    s16x8 bfr[5];
#pragma unroll
                    for (int lf = 0; lf < 5; ++lf) {
                        int ry = lf * 16 + lr + k - 1;
                        ry = (ry < 0) ? 0 : (ry > 79 ? 79 : ry);
                        bfr[lf] = relu8(*(const s16x8*)(sY + ((ry * 136 + ks * 32 + kg * 8) << 1)));
                    }
#pragma unroll
                    for (int lf = 0; lf < 5; ++lf)
                        acc[lf] = MFMA16(a, bfr[lf], acc[lf]);
                }
            }
#pragma unroll
            for (int lf = 0; lf < 5; ++lf) {
                int row = lf * 16 + lr;
                int ch0 = co0 + kg * 4;
                *(uint2*)(sH + ((row * 72 + ch0) << 1)) =
                    pack4(fmaxf(acc[lf][0], 0.f), fmaxf(acc[lf][1], 0.f),
                          fmaxf(acc[lf][2], 0.f), fmaxf(acc[lf][3], 0.f));
            }
        }
        __syncthreads();
        {
            const int co0 = wid * 32;
            f32x4 acc[2][5];
#pragma unroll
            for (int cf = 0; cf < 2; ++cf)
#pragma unroll
                for (int lf = 0; lf < 5; ++lf) acc[cf][lf] = zf4;
#pragma unroll
            for (int ks = 0; ks < 2; ++ks) {
                s16x8 af[2];
#pragma unroll
                for (int cf = 0; cf < 2; ++cf)
                    af[cf] = *(const s16x8*)(w2 + (size_t)(co0 + cf * 16 + lr) * 64 + ks * 32 + kg * 8);
                s16x8 bfr[5];
#pragma unroll
                for (int lf = 0; lf < 5; ++lf) {
                    int row = lf * 16 + lr;
                    bfr[lf] = *(const s16x8*)(sH + ((row * 72 + ks * 32 + kg * 8) << 1));
                }
#pragma unroll
                for (int cf = 0; cf < 2; ++cf)
#pragma unroll
                    for (int lf = 0; lf < 5; ++lf)
                        acc[cf][lf] = MFMA16(af[cf], bfr[lf], acc[cf][lf]);
            }
#pragma unroll
            for (int cf = 0; cf < 2; ++cf)
#pragma unroll
                for (int lf = 0; lf < 5; ++lf) {
                    int row = lf * 16 + lr;
                    int p   = l0 - 8 + row;
                    int cb0 = co0 + cf * 16 + kg * 4;
                    uint2 old = *(const uint2*)(sY + ((row * 136 + cb0) << 1));
                    bool ok = (p >= 0 && p < 1024);
                    float r0 = acc[cf][lf][0] + bf2f((unsigned short)(old.x & 0xffff));
                    float r1 = acc[cf][lf][1] + bf2f((unsigned short)(old.x >> 16));
                    float r2 = acc[cf][lf][2] + bf2f((unsigned short)(old.y & 0xffff));
                    float r3 = acc[cf][lf][3] + bf2f((unsigned short)(old.y >> 16));
                    if (blk2 == 1) {
                        r0 = fmaxf(r0, 0.f); r1 = fmaxf(r1, 0.f);
                        r2 = fmaxf(r2, 0.f); r3 = fmaxf(r3, 0.f);
                    }
                    uint2 pk = pack4(r0, r1, r2, r3);
                    if (!ok) { pk.x = 0u; pk.y = 0u; }
                    *(uint2*)(sY + ((row * 136 + cb0) << 1)) = pk;
                }
        }
        __syncthreads();
    }

    // ---- ct1 convT (CO=64) + LDS store bounce ----
    {
        const int co0 = (wid & 1) * 32;
        const int mh  = wid >> 1;
        f32x4 acc[2][2][2];
#pragma unroll
        for (int g = 0; g < 2; ++g)
#pragma unroll
            for (int cf = 0; cf < 2; ++cf)
#pragma unroll
                for (int j = 0; j < 2; ++j) acc[g][cf][j] = zf4;
#pragma unroll
        for (int g = 0; g < 2; ++g)
#pragma unroll
            for (int k = 0; k < 2; ++k) {
                const bf16* Ab = ct1w + (size_t)(g * 2 + k) * 64 * 128;
                const int doff = (g == 0) ? (k - 1) : k;
#pragma unroll
                for (int ks = 0; ks < 4; ++ks) {
                    s16x8 af[2];
#pragma unroll
                    for (int cf = 0; cf < 2; ++cf)
                        af[cf] = *(const s16x8*)(Ab + (co0 + cf * 16 + lr) * 128 + ks * 32 + kg * 8);
                    s16x8 bfr[2];
#pragma unroll
                    for (int j = 0; j < 2; ++j) {
                        int ty = 8 + (mh * 2 + j) * 16 + lr + doff;
                        bfr[j] = *(const s16x8*)(sY + ((ty * 136 + ks * 32 + kg * 8) << 1));
                    }
#pragma unroll
                    for (int cf = 0; cf < 2; ++cf)
#pragma unroll
                        for (int j = 0; j < 2; ++j)
                            acc[g][cf][j] = MFMA16(af[cf], bfr[j], acc[g][cf][j]);
                }
            }
        __syncthreads();   // all sY reads done before bounce overwrite

        // bounce: sY region becomes [128 rows][64ch] linear (16KB)
#pragma unroll
        for (int g = 0; g < 2; ++g)
#pragma unroll
            for (int cf = 0; cf < 2; ++cf)
#pragma unroll
                for (int j = 0; j < 2; ++j) {
                    int m   = (mh * 2 + j) * 16 + lr;
                    int rr  = 2 * m + g;
                    int ch0 = co0 + cf * 16 + kg * 4;
                    float r[4];
#pragma unroll
                    for (int jj = 0; jj < 4; ++jj)
                        r[jj] = fmaxf(acc[g][cf][j][jj] + ct1b[ch0 + jj], 0.f);
                    *(uint2*)(sY + rr * 128 + ch0 * 2) = pack4(r[0], r[1], r[2], r[3]);
                }
        __syncthreads();

        bf16* ob = out + ((size_t)b * 2048 + 2 * l0) * 64;
        for (int i = tid; i < 1024; i += 256)
            *(s16x8*)(ob + i * 8) = *(const s16x8*)(sY + i * 16);
    }
}

// Fused enc1+enc2: x fp32 -> h1 (LDS, stride 72) -> enc2 GEMM -> bf16 relu.
__global__ __launch_bounds__(256) void enc12_k(
    const float* __restrict__ x, const float* __restrict__ w1,
    const float* __restrict__ b1, const bf16* __restrict__ w2t,
    const float* __restrict__ b2, bf16* __restrict__ out)
{
    __shared__ float sXf[268];
    __shared__ float sW1[256];
    __shared__ float sB1[64];
    __shared__ __align__(16) char sX[132 * 144];
    const int tid = threadIdx.x;
    const int b   = blockIdx.y;
    const int l0  = blockIdx.x * 64;
    const float* xb = x + (size_t)b * 4096;

    for (int i = tid; i < 266; i += 256) {
        int g = 4 * l0 - 3 + i;
        sXf[i] = (g >= 0 && g < 4096) ? xb[g] : 0.f;
    }
    if (tid < 256) sW1[tid] = w1[tid];
    if (tid < 64)  sB1[tid] = b1[tid];
    __syncthreads();

    for (int i = tid; i < 132 * 64; i += 256) {
        int t = i >> 6, c = i & 63;
        int p = (t < 66) ? 2 * (l0 + t) : 2 * (l0 + t - 66) - 1;
        float v = 0.f;
        if (p >= 0 && p < 2048) {
            int xi = 2 * p - 4 * l0 + 2;
            float a = sB1[c];
#pragma unroll
            for (int k = 0; k < 4; ++k) a = fmaf(sXf[xi + k], sW1[c * 4 + k], a);
            v = fmaxf(a, 0.f);
        }
        *(bf16*)(sX + ((t * 72 + c) << 1)) = __float2bfloat16(v);
    }
    __syncthreads();

    const int lane = tid & 63;
    const int wid  = __builtin_amdgcn_readfirstlane(tid >> 6);
    const int co0  = wid * 32;
    const int lr   = lane & 15;
    const int kg   = lane >> 4;

    f32x4 acc[2][4];
#pragma unroll
    for (int cf = 0; cf < 2; ++cf)
#pragma unroll
        for (int lf = 0; lf < 4; ++lf) acc[cf][lf] = (f32x4){0.f, 0.f, 0.f, 0.f};

#pragma unroll
    for (int k = 0; k < 4; ++k) {
        const int roff = (k == 0) ? 66 : (k == 1) ? 0 : (k == 2) ? 67 : 1;
        const bf16* Ab = w2t + (size_t)k * 128 * 64;
#pragma unroll
        for (int ks = 0; ks < 2; ++ks) {
            s16x8 af[2];
#pragma unroll
            for (int cf = 0; cf < 2; ++cf)
                af[cf] = *(const s16x8*)(Ab + (co0 + cf * 16 + lr) * 64 + ks * 32 + kg * 8);
            s16x8 bfr[4];
#pragma unroll
            for (int lf = 0; lf < 4; ++lf) {
                int t = roff + lf * 16 + lr;
                bfr[lf] = *(const s16x8*)(sX + ((t * 72 + ks * 32 + kg * 8) << 1));
            }
#pragma unroll
            for (int cf = 0; cf < 2; ++cf)
#pragma unroll
                for (int lf = 0; lf < 4; ++lf)
                    acc[cf][lf] = MFMA16(af[cf], bfr[lf], acc[cf][lf]);
        }
    }

#pragma unroll
    for (int cf = 0; cf < 2; ++cf)
#pragma unroll
        for (int lf = 0; lf < 4; ++lf) {
            int cb0  = co0 + cf * 16 + kg * 4;
            int lcol = lf * 16 + lr;
            float r[4];
#pragma unroll
            for (int j = 0; j < 4; ++j)
                r[j] = fmaxf(acc[cf][lf][j] + b2[cb0 + j], 0.f);
            *(uint2*)(out + ((size_t)b * 1024 + l0 + lcol) * 128 + cb0) =
                pack4(r[0], r[1], r[2], r[3]);
        }
}

// Final convT: 64->1 ch, x2 upsample; fp32 out.
__global__ __launch_bounds__(256) void ct2_k(
    const bf16* __restrict__ in, const float* __restrict__ w,
    const float* __restrict__ bias, float* __restrict__ out)
{
    __shared__ __align__(16) char sX[258 * 144];
    const int tid = threadIdx.x;
    const int b   = blockIdx.y;
    const int m0  = blockIdx.x * 256;
    const bf16* inb = in + (size_t)b * 2048 * 64;
    for (int i = tid; i < 258 * 8; i += 256) {
        int t = i >> 3, c0 = (i & 7) * 8;
        int g = m0 - 1 + t;
        s16x8 v = {};
        if (g >= 0 && g < 2048) v = *(const s16x8*)(inb + (size_t)g * 64 + c0);
        *(s16x8*)(sX + ((t * 72 + c0) << 1)) = v;
    }
    __syncthreads();
    float e = bias[0], o = bias[0];
#pragma unroll
    for (int c0 = 0; c0 < 64; c0 += 8) {
        s16x8 vm1 = *(const s16x8*)(sX + (((tid + 0) * 72 + c0) << 1));
        s16x8 v0  = *(const s16x8*)(sX + (((tid + 1) * 72 + c0) << 1));
        s16x8 vp1 = *(const s16x8*)(sX + (((tid + 2) * 72 + c0) << 1));
#pragma unroll
        for (int j = 0; j < 8; ++j) {
            int ci = c0 + j;
            float xm1 = bf2f((unsigned short)vm1[j]);
            float x0  = bf2f((unsigned short)v0[j]);
            float xp1 = bf2f((unsigned short)vp1[j]);
            e = fmaf(x0,  w[ci * 4 + 1], fmaf(xm1, w[ci * 4 + 3], e));
            o = fmaf(xp1, w[ci * 4 + 0], fmaf(x0,  w[ci * 4 + 2], o));
        }
    }
    int m = m0 + tid;
    out[(size_t)b * 4096 + 2 * m]     = e;
    out[(size_t)b * 4096 + 2 * m + 1] = o;
}

// Weight transform: fp32 conv weights -> bf16 [tap][co][ci] matrices.
__global__ __launch_bounds__(256) void wx_k(
    const float* ew2, const float* ew3, const float* er1a, const float* er1b,
    const float* er2a, const float* er2b, const float* pvw, const float* dw1,
    const float* dr1a, const float* dr1b, const float* dr2a, const float* dr2b,
    const float* ct1w, bf16* wb)
{
    const int job = blockIdx.x;
    bf16* dst = wb + (size_t)job * 65536;
    const float* src; int CO, CI, K;
    switch (job) {
        case 0:  src = ew2;  CO = 128; CI = 64;  K = 4; break;
        case 1:  src = ew3;  CO = 128; CI = 128; K = 3; break;
        case 2:  src = er1a; CO = 64;  CI = 128; K = 3; break;
        case 3:  src = er1b; CO = 128; CI = 64;  K = 1; break;
        case 4:  src = er2a; CO = 64;  CI = 128; K = 3; break;
        case 5:  src = er2b; CO = 128; CI = 64;  K = 1; break;
        case 6:  src = pvw;  CO = 64;  CI = 128; K = 1; break;
        case 7:  src = dw1;  CO = 128; CI = 64;  K = 3; break;
        case 8:  src = dr1a; CO = 64;  CI = 128; K = 3; break;
        case 9:  src = dr1b; CO = 128; CI = 64;  K = 1; break;
        case 10: src = dr2a; CO = 64;  CI = 128; K = 3; break;
        case 11: src = dr2b; CO = 128; CI = 64;  K = 1; break;
        default: src = ct1w; CO = 64;  CI = 128; K = 4; break;
    }
    const int tot = CO * CI * K;
    for (int i = blockIdx.y * 256 + threadIdx.x; i < tot; i += gridDim.y * 256) {
        if (job < 12) {
            int k = i / (CO * CI); int r = i - k * CO * CI;
            int co = r / CI; int ci = r - co * CI;
            dst[i] = __float2bfloat16(src[((size_t)co * CI + ci) * K + k]);
        } else {
            const int TAP[4] = {3, 1, 2, 0};
            int g = i / (64 * 128); int r = i - g * 64 * 128;
            int co = r / 128; int ci = r - co * 128;
            dst[i] = __float2bfloat16(src[((size_t)ci * 64 + co) * 4 + TAP[g]]);
        }
    }
}

// codebook prep: fp32 norms + hi/lo bf16 split
__global__ __launch_bounds__(256) void cbprep_k(
    const float* __restrict__ cb, bf16* __restrict__ cbh, bf16* __restrict__ cbl,
    float* __restrict__ sc)
{
    int k = blockIdx.x * 256 + threadIdx.x;
    const float* c = cb + (size_t)k * 64;
    float s = 0.f;
#pragma unroll
    for (int d = 0; d < 64; ++d) s = fmaf(c[d], c[d], s);
    sc[k] = s;
#pragma unroll
    for (int c0 = 0; c0 < 64; c0 += 8) {
        union { unsigned short u[8]; s16x8 v; } ph, pl;
#pragma unroll
        for (int j = 0; j < 8; ++j) {
            float v = c[c0 + j];
            unsigned short h = bfbits(v);
            ph.u[j] = h;
            pl.u[j] = bfbits(v - bf2f(h));
        }
        *(s16x8*)(cbh + (size_t)k * 64 + c0) = ph.v;
        *(s16x8*)(cbl + (size_t)k * 64 + c0) = pl.v;
    }
}

// Fused pre_vq + VQ. 1024 blocks x 128 positions. A tile / z tile alias.
__global__ __launch_bounds__(256, 4) void vqf_k(
    const bf16* __restrict__ A, const bf16* __restrict__ pvw,
    const float* __restrict__ pvb, const float* __restrict__ cbf,
    const bf16* __restrict__ cbh, const bf16* __restrict__ cbl,
    const float* __restrict__ sc, bf16* __restrict__ q,
    float* __restrict__ counts, float* __restrict__ loss_sum)
{
    __shared__ __align__(16) char sMem[34816];
    __shared__ float sSC[512];
    __shared__ float sHist[512];
    __shared__ int   sBK[128];
    __shared__ float sWS[4];
    const int tid = threadIdx.x;
    sSC[tid] = sc[tid]; sSC[tid + 256] = sc[tid + 256];
    sHist[tid] = 0.f;   sHist[tid + 256] = 0.f;

    const int n0 = blockIdx.x * 128;
    for (int i = tid; i < 128 * 16; i += 256) {
        int t = i >> 4, c0 = (i & 15) * 8;
        s16x8 v = *(const s16x8*)(A + (size_t)(n0 + t) * 128 + c0);
        *(s16x8*)(sMem + ((t * 136 + c0) << 1)) = v;
    }
    __syncthreads();

    const int lane = tid & 63, wid = tid >> 6;
    const int lr = lane & 15, kg = lane >> 4;
    const int pw0 = wid * 32;
    const f32x4 zf4 = {0.f, 0.f, 0.f, 0.f};

    f32x4 zacc[4][2];
#pragma unroll
    for (int cf = 0; cf < 4; ++cf)
#pragma unroll
        for (int lf = 0; lf < 2; ++lf) zacc[cf][lf] = zf4;
#pragma unroll
    for (int ks = 0; ks < 4; ++ks) {
        s16x8 af[4];
#pragma unroll
        for (int cf = 0; cf < 4; ++cf)
            af[cf] = *(const s16x8*)(pvw + (size_t)(cf * 16 + lr) * 128 + ks * 32 + kg * 8);
        s16x8 bfr[2];
#pragma unroll
        for (int lf = 0; lf < 2; ++lf) {
            int t = pw0 + lf * 16 + lr;
            bfr[lf] = *(const s16x8*)(sMem + ((t * 136 + ks * 32 + kg * 8) << 1));
        }
#pragma unroll
        for (int cf = 0; cf < 4; ++cf)
#pragma unroll
            for (int lf = 0; lf < 2; ++lf)
                zacc[cf][lf] = MFMA16(af[cf], bfr[lf], zacc[cf][lf]);
    }
    __syncthreads();

#pragma unroll
    for (int cf = 0; cf < 4; ++cf)
#pragma unroll
        for (int lf = 0; lf < 2; ++lf) {
            int pos = pw0 + lf * 16 + lr;
            int ch  = cf * 16 + kg * 4;
            float4 v = make_float4(zacc[cf][lf][0] + pvb[ch],
                                   zacc[cf][lf][1] + pvb[ch + 1],
                                   zacc[cf][lf][2] + pvb[ch + 2],
                                   zacc[cf][lf][3] + pvb[ch + 3]);
            *(float4*)(sMem + (pos * 68 + ch) * 4) = v;
        }
    __syncthreads();

    s16x8 bh[2][2], bl[2][2];
#pragma unroll
    for (int lf = 0; lf < 2; ++lf)
#pragma unroll
        for (int ks = 0; ks < 2; ++ks) {
            int t = pw0 + lf * 16 + lr;
            int ch = ks * 32 + kg * 8;
            float4 v0 = *(const float4*)(sMem + (t * 68 + ch) * 4);
            float4 v1 = *(const float4*)(sMem + (t * 68 + ch) * 4 + 16);
            float v[8] = {v0.x, v0.y, v0.z, v0.w, v1.x, v1.y, v1.z, v1.w};
            union { unsigned short u[8]; s16x8 s; } ph, pl;
#pragma unroll
            for (int j = 0; j < 8; ++j) {
                unsigned short h = bfbits(v[j]);
                ph.u[j] = h;
                pl.u[j] = bfbits(v[j] - bf2f(h));
            }
            bh[lf][ks] = ph.s; bl[lf][ks] = pl.s;
        }

    float bestd[2] = {3.4e38f, 3.4e38f};
    int   bestk[2] = {0, 0};
#pragma unroll 2
    for (int cf = 0; cf < 32; ++cf) {
        int code = cf * 16 + lr;
        const bf16* ph = cbh + code * 64 + kg * 8;
        const bf16* pl = cbl + code * 64 + kg * 8;
        s16x8 ah0 = *(const s16x8*)ph;
        s16x8 ah1 = *(const s16x8*)(ph + 32);
        s16x8 al0 = *(const s16x8*)pl;
        s16x8 al1 = *(const s16x8*)(pl + 32);
        float s0 = sSC[cf * 16 + kg * 4 + 0];
        float s1 = sSC[cf * 16 + kg * 4 + 1];
        float s2 = sSC[cf * 16 + kg * 4 + 2];
        float s3 = sSC[cf * 16 + kg * 4 + 3];
        int kb = cf * 16 + kg * 4;
#pragma unroll
        for (int lf = 0; lf < 2; ++lf) {
            f32x4 acc = MFMA16(ah0, bh[lf][0], zf4);
            acc = MFMA16(ah1, bh[lf][1], acc);
            acc = MFMA16(al0, bh[lf][0], acc);
            acc = MFMA16(al1, bh[lf][1], acc);
            acc = MFMA16(ah0, bl[lf][0], acc);
            acc = MFMA16(ah1, bl[lf][1], acc);
            float d0 = fmaf(acc[0], -2.f, s0);
            float d1 = fmaf(acc[1], -2.f, s1);
            float d2 = fmaf(acc[2], -2.f, s2);
            float d3 = fmaf(acc[3], -2.f, s3);
            if (d0 < bestd[lf]) { bestd[lf] = d0; bestk[lf] = kb; }
            if (d1 < bestd[lf]) { bestd[lf] = d1; bestk[lf] = kb + 1; }
            if (d2 < bestd[lf]) { bestd[lf] = d2; bestk[lf] = kb + 2; }
            if (d3 < bestd[lf]) { bestd[lf] = d3; bestk[lf] = kb + 3; }
        }
    }
#pragma unroll
    for (int lf = 0; lf < 2; ++lf) {
#pragma unroll
        for (int off = 16; off <= 32; off <<= 1) {
            float od = __shfl_xor(bestd[lf], off, 64);
            int   ok = __shfl_xor(bestk[lf], off, 64);
            if (od < bestd[lf] || (od == bestd[lf] && ok < bestk[lf])) {
                bestd[lf] = od; bestk[lf] = ok;
            }
        }
        if (kg == 0) sBK[pw0 + lf * 16 + lr] = bestk[lf];
    }
    __syncthreads();

    const int pos  = tid >> 1;
    const int half = tid & 1;
    const int k = sBK[pos];
    if (half == 0) atomicAdd(&sHist[k], 1.f);
    float lsum = 0.f;
    const float* qp = cbf + (size_t)k * 64 + half * 32;
    bf16* qo = q + (size_t)(n0 + pos) * 64 + half * 32;
#pragma unroll
    for (int c0 = 0; c0 < 32; c0 += 8) {
        int zb = (pos * 68 + half * 32 + c0) * 4;
        float4 z0 = *(const float4*)(sMem + zb);
        float4 z1 = *(const float4*)(sMem + zb + 16);
        float4 q0 = *(const float4*)(qp + c0);
        float4 q1 = *(const float4*)(qp + c0 + 4);
        float qv[8] = {q0.x, q0.y, q0.z, q0.w, q1.x, q1.y, q1.z, q1.w};
        float zv[8] = {z0.x, z0.y, z0.z, z0.w, z1.x, z1.y, z1.z, z1.w};
        union { unsigned short u[8]; s16x8 v; } pk;
#pragma unroll
        for (int j = 0; j < 8; ++j) {
            float d = qv[j] - zv[j];
            lsum = fmaf(d, d, lsum);
            pk.u[j] = bfbits(qv[j]);
        }
        *(s16x8*)(qo + c0) = pk.v;
    }
#pragma unroll
    for (int off = 32; off > 0; off >>= 1) lsum += __shfl_down(lsum, off, 64);
    if ((tid & 63) == 0) sWS[tid >> 6] = lsum;
    __syncthreads();
    if (tid == 0) atomicAdd(loss_sum, sWS[0] + sWS[1] + sWS[2] + sWS[3]);
    float c0v = sHist[tid];       if (c0v != 0.f) atomicAdd(&counts[tid], c0v);
    float c1v = sHist[tid + 256]; if (c1v != 0.f) atomicAdd(&counts[tid + 256], c1v);
}

__global__ __launch_bounds__(512) void finalize_k(
    const float* __restrict__ counts, const float* __restrict__ loss_sum,
    float* __restrict__ d_out, int out_size)
{
    __shared__ float ws2[8];
    const int tid = threadIdx.x;
    float p = counts[tid] * (1.f / 131072.f);
    float e = p * logf(p + 1e-10f);
#pragma unroll
    for (int off = 32; off > 0; off >>= 1) e += __shfl_down(e, off, 64);
    const int lane = tid & 63, wid = tid >> 6;
    if (lane == 0) ws2[wid] = e;
    __syncthreads();
    if (tid == 0) {
        float s = 0.f;
        for (int i = 0; i < 8; ++i) s += ws2[i];
        d_out[0] = 1.25f * loss_sum[0] * (1.f / 8388608.f);  // (1+BETA)*mean
        d_out[out_size - 1] = expf(-s);
    }
}

extern "C" void kernel_launch(void* const* d_in, const int* in_sizes, int n_in,
                              void* d_out, int out_size, void* d_ws, size_t ws_size,
                              hipStream_t stream)
{
    const float* x        = (const float*)d_in[0];
    const float* enc_w1   = (const float*)d_in[1];
    const float* enc_b1   = (const float*)d_in[2];
    const float* enc_b2   = (const float*)d_in[4];
    const float* enc_b3   = (const float*)d_in[6];
    const float* pre_vq_b = (const float*)d_in[12];
    const float* cb       = (const float*)d_in[13];
    const float* dec_b1   = (const float*)d_in[15];
    const float* ct1_b    = (const float*)d_in[21];
    const float* ct2_w    = (const float*)d_in[22];
    const float* ct2_b    = (const float*)d_in[23];
    float* out = (float*)d_out;

    char* base = (char*)d_ws;
    bf16*  wb   = (bf16*)base;
    bf16*  Abf  = (bf16*)(base + ((size_t)2   << 20));
    bf16*  Bbf  = (bf16*)(base + ((size_t)40  << 20));
    bf16*  Qbf  = (bf16*)(base + ((size_t)78  << 20));
    bf16*  cbh  = (bf16*)(base + ((size_t)96  << 20));
    bf16*  cbl  = (bf16*)(base + ((size_t)96  << 20) + 65536);
    float* sc   = (float*)(base + ((size_t)96  << 20) + 131072);
    float* cnt  = sc + 512;
    float* lsum = cnt + 512;

    (void)hipMemsetAsync(cnt, 0, 513 * sizeof(float), stream);

    dim3 blk(256);
    dim3 g16(16, 128);

    wx_k<<<dim3(13, 8), blk, 0, stream>>>(
        (const float*)d_in[3], (const float*)d_in[5], (const float*)d_in[7],
        (const float*)d_in[8], (const float*)d_in[9], (const float*)d_in[10],
        (const float*)d_in[11], (const float*)d_in[14], (const float*)d_in[16],
        (const float*)d_in[17], (const float*)d_in[18], (const float*)d_in[19],
        (const float*)d_in[20], wb);
    cbprep_k<<<2, blk, 0, stream>>>(cb, cbh, cbl, sc);

    enc12_k<<<g16, blk, 0, stream>>>(x, enc_w1, enc_b1, wb + 0 * 65536, enc_b2, Bbf);
    encmid_k<<<g16, blk, 0, stream>>>(Bbf, wb + 1 * 65536, enc_b3,
        wb + 2 * 65536, wb + 3 * 65536, wb + 4 * 65536, wb + 5 * 65536, Abf);

    vqf_k<<<1024, blk, 0, stream>>>(Abf, wb + 6 * 65536, pre_vq_b, cb,
                                    cbh, cbl, sc, Qbf, cnt, lsum);

    decmid_k<<<g16, blk, 0, stream>>>(Qbf, wb + 7 * 65536, dec_b1,
        wb + 8 * 65536, wb + 9 * 65536, wb + 10 * 65536, wb + 11 * 65536,
        wb + 12 * 65536, ct1_b, Bbf);

    ct2_k<<<dim3(8, 128), blk, 0, stream>>>(Bbf, ct2_w, ct2_b, out + 1);
    finalize_k<<<1, 512, 0, stream>>>(cnt, lsum, out, out_size);
}

// Round 14
// 363.034 us; speedup vs baseline: 1.9663x; 1.0164x over previous
//
#include <hip/hip_runtime.h>
#include <hip/hip_bf16.h>
#include <math.h>

using bf16 = __hip_bfloat16;
typedef __attribute__((ext_vector_type(4))) float f32x4;
typedef __attribute__((ext_vector_type(8))) short s16x8;

#define MFMA16(a,b,c) __builtin_amdgcn_mfma_f32_16x16x32_bf16((a),(b),(c),0,0,0)

// ---------------------------------------------------------------------------
// VQ-VAE forward. B=128, L=4096, H=128, RH=64, D=64, K=512.
// Round-9 structure: empirical optimum of the search (357.6 us).
// Channel-last bf16; padded LDS rows (136/72 elem strides); aliased regions.
// ---------------------------------------------------------------------------

__device__ inline float bf2f(unsigned short u) {
    union { float f; unsigned v; } c; c.v = ((unsigned)u) << 16; return c.f;
}
__device__ inline unsigned short bfbits(float f) {
    union { bf16 h; unsigned short u; } c; c.h = __float2bfloat16(f); return c.u;
}
__device__ inline s16x8 relu8(s16x8 v) {
#pragma unroll
    for (int j = 0; j < 8; ++j)
        v[j] = (short)(((unsigned short)v[j] & 0x8000u) ? 0 : (unsigned short)v[j]);
    return v;
}
__device__ inline uint2 pack4(float a, float b, float c, float d) {
    uint2 p;
    p.x = (unsigned)bfbits(a) | ((unsigned)bfbits(b) << 16);
    p.y = (unsigned)bfbits(c) | ((unsigned)bfbits(d) << 16);
    return p;
}

// ===========================================================================
// encmid: enc3 (128->128 K3) + res1 + res2 + final relu.  Bbf -> Abf.
// sY 80x272B @0; sX 96x272B @21760; sH 80x144B aliases sX. 3 blocks/CU.
// ===========================================================================
__global__ __launch_bounds__(256, 3) void encmid_k(
    const bf16* __restrict__ in, const bf16* __restrict__ w3t,
    const float* __restrict__ b3, const bf16* __restrict__ r1w1,
    const bf16* __restrict__ r1w2, const bf16* __restrict__ r2w1,
    const bf16* __restrict__ r2w2, bf16* __restrict__ out)
{
    __shared__ __align__(16) char smem[47872];
    char* sY = smem;
    char* sX = smem + 21760;
    char* sH = smem + 21760;
    const int tid = threadIdx.x;
    const int b   = blockIdx.y;
    const int l0  = blockIdx.x * 64;
    const bf16* inb = in + (size_t)b * 1024 * 128;

    for (int i = tid; i < 96 * 16; i += 256) {
        int t = i >> 4, c0 = (i & 15) * 8;
        int g = l0 - 16 + t;
        s16x8 v = {};
        if (g >= 0 && g < 1024) v = *(const s16x8*)(inb + (size_t)g * 128 + c0);
        *(s16x8*)(sX + ((t * 136 + c0) << 1)) = v;
    }
    __syncthreads();

    const int lane = tid & 63;
    const int wid  = __builtin_amdgcn_readfirstlane(tid >> 6);
    const int lr   = lane & 15;
    const int kg   = lane >> 4;
    const f32x4 zf4 = {0.f, 0.f, 0.f, 0.f};

    // ---- phase 1: enc3 -> sY (80 rows x 128 co), bias, OOR-zero ----
    {
        const int co0 = wid * 32;
        f32x4 acc[2][5];
#pragma unroll
        for (int cf = 0; cf < 2; ++cf)
#pragma unroll
            for (int lf = 0; lf < 5; ++lf) acc[cf][lf] = zf4;
#pragma unroll
        for (int k = 0; k < 3; ++k) {
            const bf16* Ab = w3t + (size_t)k * 128 * 128;
#pragma unroll
            for (int ks = 0; ks < 4; ++ks) {
                s16x8 af[2];
#pragma unroll
                for (int cf = 0; cf < 2; ++cf)
                    af[cf] = *(const s16x8*)(Ab + (co0 + cf * 16 + lr) * 128 + ks * 32 + kg * 8);
                s16x8 bfr[5];
#pragma unroll
                for (int lf = 0; lf < 5; ++lf) {
                    int tx = lf * 16 + lr + 7 + k;
                    bfr[lf] = *(const s16x8*)(sX + ((tx * 136 + ks * 32 + kg * 8) << 1));
                }
#pragma unroll
                for (int cf = 0; cf < 2; ++cf)
#pragma unroll
                    for (int lf = 0; lf < 5; ++lf)
                        acc[cf][lf] = MFMA16(af[cf], bfr[lf], acc[cf][lf]);
            }
        }
        __syncthreads();   // sX reads done before sH alias writes later
#pragma unroll
        for (int cf = 0; cf < 2; ++cf)
#pragma unroll
            for (int lf = 0; lf < 5; ++lf) {
                int row = lf * 16 + lr;
                int p   = l0 - 8 + row;
                int cb0 = co0 + cf * 16 + kg * 4;
                bool ok = (p >= 0 && p < 1024);
                float r[4];
#pragma unroll
                for (int j = 0; j < 4; ++j)
                    r[j] = ok ? (acc[cf][lf][j] + b3[cb0 + j]) : 0.f;
                *(uint2*)(sY + ((row * 136 + cb0) << 1)) = pack4(r[0], r[1], r[2], r[3]);
            }
    }
    __syncthreads();

    // ---- phases 2..5: two res blocks ----
#pragma unroll 1
    for (int blk2 = 0; blk2 < 2; ++blk2) {
        const bf16* w1 = blk2 ? r2w1 : r1w1;
        {
            const int co0 = wid * 16;
            f32x4 acc[5];
#pragma unroll
            for (int lf = 0; lf < 5; ++lf) acc[lf] = zf4;
#pragma unroll
            for (int k = 0; k < 3; ++k) {
                const bf16* Ab = w1 + (size_t)k * 64 * 128;
#pragma unroll
                for (int ks = 0; ks < 4; ++ks) {
                    s16x8 a = *(const s16x8*)(Ab + (co0 + lr) * 128 + ks * 32 + kg * 8);
                    s16x8 bfr[5];
#pragma unroll
                    for (int lf = 0; lf < 5; ++lf) {
                        int ry = lf * 16 + lr + k - 1;
                        ry = (ry < 0) ? 0 : (ry > 79 ? 79 : ry);
                        bfr[lf] = relu8(*(const s16x8*)(sY + ((ry * 136 + ks * 32 + kg * 8) << 1)));
                    }
#pragma unroll
                    for (int lf = 0; lf < 5; ++lf)
                        acc[lf] = MFMA16(a, bfr[lf], acc[lf]);
                }
            }
#pragma unroll
            for (int lf = 0; lf < 5; ++lf) {
                int row = lf * 16 + lr;
                int ch0 = co0 + kg * 4;
                *(uint2*)(sH + ((row * 72 + ch0) << 1)) =
                    pack4(fmaxf(acc[lf][0], 0.f), fmaxf(acc[lf][1], 0.f),
                          fmaxf(acc[lf][2], 0.f), fmaxf(acc[lf][3], 0.f));
            }
        }
        __syncthreads();

        if (blk2 == 0) {
            const int co0 = wid * 32;
            f32x4 acc[2][5];
#pragma unroll
            for (int cf = 0; cf < 2; ++cf)
#pragma unroll
                for (int lf = 0; lf < 5; ++lf) acc[cf][lf] = zf4;
#pragma unroll
            for (int ks = 0; ks < 2; ++ks) {
                s16x8 af[2];
#pragma unroll
                for (int cf = 0; cf < 2; ++cf)
                    af[cf] = *(const s16x8*)(r1w2 + (size_t)(co0 + cf * 16 + lr) * 64 + ks * 32 + kg * 8);
                s16x8 bfr[5];
#pragma unroll
                for (int lf = 0; lf < 5; ++lf) {
                    int row = lf * 16 + lr;
                    bfr[lf] = *(const s16x8*)(sH + ((row * 72 + ks * 32 + kg * 8) << 1));
                }
#pragma unroll
                for (int cf = 0; cf < 2; ++cf)
#pragma unroll
                    for (int lf = 0; lf < 5; ++lf)
                        acc[cf][lf] = MFMA16(af[cf], bfr[lf], acc[cf][lf]);
            }
#pragma unroll
            for (int cf = 0; cf < 2; ++cf)
#pragma unroll
                for (int lf = 0; lf < 5; ++lf) {
                    int row = lf * 16 + lr;
                    int p   = l0 - 8 + row;
                    int cb0 = co0 + cf * 16 + kg * 4;
                    uint2 old = *(const uint2*)(sY + ((row * 136 + cb0) << 1));
                    bool ok = (p >= 0 && p < 1024);
                    float r0 = acc[cf][lf][0] + bf2f((unsigned short)(old.x & 0xffff));
                    float r1 = acc[cf][lf][1] + bf2f((unsigned short)(old.x >> 16));
                    float r2 = acc[cf][lf][2] + bf2f((unsigned short)(old.y & 0xffff));
                    float r3 = acc[cf][lf][3] + bf2f((unsigned short)(old.y >> 16));
                    uint2 pk = pack4(r0, r1, r2, r3);
                    if (!ok) { pk.x = 0u; pk.y = 0u; }
                    *(uint2*)(sY + ((row * 136 + cb0) << 1)) = pk;
                }
            __syncthreads();
        } else {
            const int co0 = wid * 32;
            f32x4 acc[2][4];
#pragma unroll
            for (int cf = 0; cf < 2; ++cf)
#pragma unroll
                for (int lf = 0; lf < 4; ++lf) acc[cf][lf] = zf4;
#pragma unroll
            for (int ks = 0; ks < 2; ++ks) {
                s16x8 af[2];
#pragma unroll
                for (int cf = 0; cf < 2; ++cf)
                    af[cf] = *(const s16x8*)(r2w2 + (size_t)(co0 + cf * 16 + lr) * 64 + ks * 32 + kg * 8);
                s16x8 bfr[4];
#pragma unroll
                for (int lf = 0; lf < 4; ++lf) {
                    int row = 8 + lf * 16 + lr;
                    bfr[lf] = *(const s16x8*)(sH + ((row * 72 + ks * 32 + kg * 8) << 1));
                }
#pragma unroll
                for (int cf = 0; cf < 2; ++cf)
#pragma unroll
                    for (int lf = 0; lf < 4; ++lf)
                        acc[cf][lf] = MFMA16(af[cf], bfr[lf], acc[cf][lf]);
            }
#pragma unroll
            for (int cf = 0; cf < 2; ++cf)
#pragma unroll
                for (int lf = 0; lf < 4; ++lf) {
                    int row = 8 + lf * 16 + lr;
                    int cb0 = co0 + cf * 16 + kg * 4;
                    uint2 old = *(const uint2*)(sY + ((row * 136 + cb0) << 1));
                    float r0 = fmaxf(acc[cf][lf][0] + bf2f((unsigned short)(old.x & 0xffff)), 0.f);
                    float r1 = fmaxf(acc[cf][lf][1] + bf2f((unsigned short)(old.x >> 16)), 0.f);
                    float r2 = fmaxf(acc[cf][lf][2] + bf2f((unsigned short)(old.y & 0xffff)), 0.f);
                    float r3 = fmaxf(acc[cf][lf][3] + bf2f((unsigned short)(old.y >> 16)), 0.f);
                    *(uint2*)(out + ((size_t)b * 1024 + l0 + lf * 16 + lr) * 128 + cb0) =
                        pack4(r0, r1, r2, r3);
                }
        }
    }
}

// ===========================================================================
// decmid: dec1 + res1 + res2(+relu) + ct1 convT.  Qbf -> (b,2048,64) bf16.
// sY 80x272B @0; sQ 96x144B @21760; sH aliases sQ. 4 blocks/CU.
// ===========================================================================
__global__ __launch_bounds__(256, 4) void decmid_k(
    const bf16* __restrict__ qin, const bf16* __restrict__ dw1,
    const float* __restrict__ db1, const bf16* __restrict__ r1w1,
    const bf16* __restrict__ r1w2, const bf16* __restrict__ r2w1,
    const bf16* __restrict__ r2w2, const bf16* __restrict__ ct1w,
    const float* __restrict__ ct1b, bf16* __restrict__ out)
{
    __shared__ __align__(16) char smem[35584];
    char* sY = smem;
    char* sQ = smem + 21760;
    char* sH = smem + 21760;
    const int tid = threadIdx.x;
    const int b   = blockIdx.y;
    const int l0  = blockIdx.x * 64;
    const bf16* inb = qin + (size_t)b * 1024 * 64;

    for (int i = tid; i < 96 * 8; i += 256) {
        int t = i >> 3, c0 = (i & 7) * 8;
        int g = l0 - 16 + t;
        s16x8 v = {};
        if (g >= 0 && g < 1024) v = *(const s16x8*)(inb + (size_t)g * 64 + c0);
        *(s16x8*)(sQ + ((t * 72 + c0) << 1)) = v;
    }
    __syncthreads();

    const int lane = tid & 63;
    const int wid  = __builtin_amdgcn_readfirstlane(tid >> 6);
    const int lr   = lane & 15;
    const int kg   = lane >> 4;
    const f32x4 zf4 = {0.f, 0.f, 0.f, 0.f};

    // ---- phase 1: dec1 -> sY, bias, OOR-zero ----
    {
        const int co0 = wid * 32;
        f32x4 acc[2][5];
#pragma unroll
        for (int cf = 0; cf < 2; ++cf)
#pragma unroll
            for (int lf = 0; lf < 5; ++lf) acc[cf][lf] = zf4;
#pragma unroll
        for (int k = 0; k < 3; ++k) {
            const bf16* Ab = dw1 + (size_t)k * 128 * 64;
#pragma unroll
            for (int ks = 0; ks < 2; ++ks) {
                s16x8 af[2];
#pragma unroll
                for (int cf = 0; cf < 2; ++cf)
                    af[cf] = *(const s16x8*)(Ab + (co0 + cf * 16 + lr) * 64 + ks * 32 + kg * 8);
                s16x8 bfr[5];
#pragma unroll
                for (int lf = 0; lf < 5; ++lf) {
                    int tx = lf * 16 + lr + 7 + k;
                    bfr[lf] = *(const s16x8*)(sQ + ((tx * 72 + ks * 32 + kg * 8) << 1));
                }
#pragma unroll
                for (int cf = 0; cf < 2; ++cf)
#pragma unroll
                    for (int lf = 0; lf < 5; ++lf)
                        acc[cf][lf] = MFMA16(af[cf], bfr[lf], acc[cf][lf]);
            }
        }
        __syncthreads();   // sQ reads complete before sH alias overwrite
#pragma unroll
        for (int cf = 0; cf < 2; ++cf)
#pragma unroll
            for (int lf = 0; lf < 5; ++lf) {
                int row = lf * 16 + lr;
                int p   = l0 - 8 + row;
                int cb0 = co0 + cf * 16 + kg * 4;
                bool ok = (p >= 0 && p < 1024);
                float r[4];
#pragma unroll
                for (int j = 0; j < 4; ++j)
                    r[j] = ok ? (acc[cf][lf][j] + db1[cb0 + j]) : 0.f;
                *(uint2*)(sY + ((row * 136 + cb0) << 1)) = pack4(r[0], r[1], r[2], r[3]);
            }
    }
    __syncthreads();

    // ---- res blocks ----
#pragma unroll 1
    for (int blk2 = 0; blk2 < 2; ++blk2) {
        const bf16* w1 = blk2 ? r2w1 : r1w1;
        const bf16* w2 = blk2 ? r2w2 : r1w2;
        {
            const int co0 = wid * 16;
            f32x4 acc[5];
#pragma unroll
            for (int lf = 0; lf < 5; ++lf) acc[lf] = zf4;
#pragma unroll
            for (int k = 0; k < 3; ++k) {
                const bf16* Ab = w1 + (size_t)k * 64 * 128;
#pragma unroll
                for (int ks = 0; ks < 4; ++ks) {
                    s16x8 a = *(const s16x8*)(Ab + (co0 + lr) * 128 + ks * 32 + kg * 8);
                    s16x8 bfr[5];
#pragma unroll
                    for (int lf = 0; lf < 5; ++lf) {
                        int ry = lf * 16 + lr + k - 1;
                        ry = (ry < 0) ? 0 : (ry > 79 ? 79 : ry);
                        bfr[lf] = relu8(*(const s16x8*)(sY + ((ry * 136 + ks * 32 + kg * 8) << 1)));
                    }
#pragma unroll
                    for (int lf = 0; lf < 5; ++lf)
                        acc[lf] = MFMA16(a, bfr[lf], acc[lf]);
                }
            }
#pragma unroll
            for (int lf = 0; lf < 5; ++lf) {
                int row = lf * 16 + lr;
                int ch0 = co0 + kg * 4;
                *(uint2*)(sH + ((row * 72 + ch0) << 1)) =
                    pack4(fmaxf(acc[lf][0], 0.f), fmaxf(acc[lf][1], 0.f),
                          fmaxf(acc[lf][2], 0.f), fmaxf(acc[lf][3], 0.f));
            }
        }
        __syncthreads();
        {
            const int co0 = wid * 32;
            f32x4 acc[2][5];
#pragma unroll
            for (int cf = 0; cf < 2; ++cf)
#pragma unroll
                for (int lf = 0; lf < 5; ++lf) acc[cf][lf] = zf4;
#pragma unroll
            for (int ks = 0; ks < 2; ++ks) {
                s16x8 af[2];
#pragma unroll
                for (int cf = 0; cf < 2; ++cf)
                    af[cf] = *(const s16x8*)(w2 + (size_t)(co0 + cf * 16 + lr) * 64 + ks * 32 + kg * 8);
                s16x8 bfr[5];
#pragma unroll
                for (int lf = 0; lf < 5; ++lf) {
                    int row = lf * 16 + lr;
                    bfr[lf] = *(const s16x8*)(sH + ((row * 72 + ks * 32 + kg * 8) << 1));
                }
#pragma unroll
                for (int cf = 0; cf < 2; ++cf)
#pragma unroll
                    for (int lf = 0; lf < 5; ++lf)
                        acc[cf][lf] = MFMA16(af[cf], bfr[lf], acc[cf][lf]);
            }
#pragma unroll
            for (int cf = 0; cf < 2; ++cf)
#pragma unroll
                for (int lf = 0; lf < 5; ++lf) {
                    int row = lf * 16 + lr;
                    int p   = l0 - 8 + row;
                    int cb0 = co0 + cf * 16 + kg * 4;
                    uint2 old = *(const uint2*)(sY + ((row * 136 + cb0) << 1));
                    bool ok = (p >= 0 && p < 1024);
                    float r0 = acc[cf][lf][0] + bf2f((unsigned short)(old.x & 0xffff));
                    float r1 = acc[cf][lf][1] + bf2f((unsigned short)(old.x >> 16));
                    float r2 = acc[cf][lf][2] + bf2f((unsigned short)(old.y & 0xffff));
                    float r3 = acc[cf][lf][3] + bf2f((unsigned short)(old.y >> 16));
                    if (blk2 == 1) {
                        r0 = fmaxf(r0, 0.f); r1 = fmaxf(r1, 0.f);
                        r2 = fmaxf(r2, 0.f); r3 = fmaxf(r3, 0.f);
                    }
                    uint2 pk = pack4(r0, r1, r2, r3);
                    if (!ok) { pk.x = 0u; pk.y = 0u; }
                    *(uint2*)(sY + ((row * 136 + cb0) << 1)) = pk;
                }
        }
        __syncthreads();
    }

    // ---- ct1 convT (CO=64): direct uint2 stores ----
    {
        const int co0 = (wid & 1) * 32;
        const int mh  = wid >> 1;
        f32x4 acc[2][2][2];
#pragma unroll
        for (int g = 0; g < 2; ++g)
#pragma unroll
            for (int cf = 0; cf < 2; ++cf)
#pragma unroll
                for (int j = 0; j < 2; ++j) acc[g][cf][j] = zf4;
#pragma unroll
        for (int g = 0; g < 2; ++g)
#pragma unroll
            for (int k = 0; k < 2; ++k) {
                const bf16* Ab = ct1w + (size_t)(g * 2 + k) * 64 * 128;
                const int doff = (g == 0) ? (k - 1) : k;
#pragma unroll
                for (int ks = 0; ks < 4; ++ks) {
                    s16x8 af[2];
#pragma unroll
                    for (int cf = 0; cf < 2; ++cf)
                        af[cf] = *(const s16x8*)(Ab + (co0 + cf * 16 + lr) * 128 + ks * 32 + kg * 8);
                    s16x8 bfr[2];
#pragma unroll
                    for (int j = 0; j < 2; ++j) {
                        int ty = 8 + (mh * 2 + j) * 16 + lr + doff;
                        bfr[j] = *(const s16x8*)(sY + ((ty * 136 + ks * 32 + kg * 8) << 1));
                    }
#pragma unroll
                    for (int cf = 0; cf < 2; ++cf)
#pragma unroll
                        for (int j = 0; j < 2; ++j)
                            acc[g][cf][j] = MFMA16(af[cf], bfr[j], acc[g][cf][j]);
                }
            }
#pragma unroll
        for (int g = 0; g < 2; ++g)
#pragma unroll
            for (int cf = 0; cf < 2; ++cf)
#pragma unroll
                for (int j = 0; j < 2; ++j) {
                    int m   = (mh * 2 + j) * 16 + lr;
                    int cb0 = co0 + cf * 16 + kg * 4;
                    float r[4];
#pragma unroll
                    for (int jj = 0; jj < 4; ++jj)
                        r[jj] = fmaxf(acc[g][cf][j][jj] + ct1b[cb0 + jj], 0.f);
                    *(uint2*)(out + ((size_t)b * 2048 + 2 * (l0 + m) + g) * 64 + cb0) =
                        pack4(r[0], r[1], r[2], r[3]);
                }
    }
}

// Fused enc1+enc2: x fp32 -> h1 (LDS, stride 72) -> enc2 GEMM -> bf16 relu.
__global__ __launch_bounds__(256) void enc12_k(
    const float* __restrict__ x, const float* __restrict__ w1,
    const float* __restrict__ b1, const bf16* __restrict__ w2t,
    const float* __restrict__ b2, bf16* __restrict__ out)
{
    __shared__ float sXf[268];
    __shared__ float sW1[256];
    __shared__ float sB1[64];
    __shared__ __align__(16) char sX[132 * 144];
    const int tid = threadIdx.x;
    const int b   = blockIdx.y;
    const int l0  = blockIdx.x * 64;
    const float* xb = x + (size_t)b * 4096;

    for (int i = tid; i < 266; i += 256) {
        int g = 4 * l0 - 3 + i;
        sXf[i] = (g >= 0 && g < 4096) ? xb[g] : 0.f;
    }
    if (tid < 256) sW1[tid] = w1[tid];
    if (tid < 64)  sB1[tid] = b1[tid];
    __syncthreads();

    for (int i = tid; i < 132 * 64; i += 256) {
        int t = i >> 6, c = i & 63;
        int p = (t < 66) ? 2 * (l0 + t) : 2 * (l0 + t - 66) - 1;
        float v = 0.f;
        if (p >= 0 && p < 2048) {
            int xi = 2 * p - 4 * l0 + 2;
            float a = sB1[c];
#pragma unroll
            for (int k = 0; k < 4; ++k) a = fmaf(sXf[xi + k], sW1[c * 4 + k], a);
            v = fmaxf(a, 0.f);
        }
        *(bf16*)(sX + ((t * 72 + c) << 1)) = __float2bfloat16(v);
    }
    __syncthreads();

    const int lane = tid & 63;
    const int wid  = __builtin_amdgcn_readfirstlane(tid >> 6);
    const int co0  = wid * 32;
    const int lr   = lane & 15;
    const int kg   = lane >> 4;

    f32x4 acc[2][4];
#pragma unroll
    for (int cf = 0; cf < 2; ++cf)
#pragma unroll
        for (int lf = 0; lf < 4; ++lf) acc[cf][lf] = (f32x4){0.f, 0.f, 0.f, 0.f};

#pragma unroll
    for (int k = 0; k < 4; ++k) {
        const int roff = (k == 0) ? 66 : (k == 1) ? 0 : (k == 2) ? 67 : 1;
        const bf16* Ab = w2t + (size_t)k * 128 * 64;
#pragma unroll
        for (int ks = 0; ks < 2; ++ks) {
            s16x8 af[2];
#pragma unroll
            for (int cf = 0; cf < 2; ++cf)
                af[cf] = *(const s16x8*)(Ab + (co0 + cf * 16 + lr) * 64 + ks * 32 + kg * 8);
            s16x8 bfr[4];
#pragma unroll
            for (int lf = 0; lf < 4; ++lf) {
                int t = roff + lf * 16 + lr;
                bfr[lf] = *(const s16x8*)(sX + ((t * 72 + ks * 32 + kg * 8) << 1));
            }
#pragma unroll
            for (int cf = 0; cf < 2; ++cf)
#pragma unroll
                for (int lf = 0; lf < 4; ++lf)
                    acc[cf][lf] = MFMA16(af[cf], bfr[lf], acc[cf][lf]);
        }
    }

#pragma unroll
    for (int cf = 0; cf < 2; ++cf)
#pragma unroll
        for (int lf = 0; lf < 4; ++lf) {
            int cb0  = co0 + cf * 16 + kg * 4;
            int lcol = lf * 16 + lr;
            float r[4];
#pragma unroll
            for (int j = 0; j < 4; ++j)
                r[j] = fmaxf(acc[cf][lf][j] + b2[cb0 + j], 0.f);
            *(uint2*)(out + ((size_t)b * 1024 + l0 + lcol) * 128 + cb0) =
                pack4(r[0], r[1], r[2], r[3]);
        }
}

// Final convT: 64->1 ch, x2 upsample; fp32 out.
__global__ __launch_bounds__(256) void ct2_k(
    const bf16* __restrict__ in, const float* __restrict__ w,
    const float* __restrict__ bias, float* __restrict__ out)
{
    __shared__ __align__(16) char sX[258 * 144];
    const int tid = threadIdx.x;
    const int b   = blockIdx.y;
    const int m0  = blockIdx.x * 256;
    const bf16* inb = in + (size_t)b * 2048 * 64;
    for (int i = tid; i < 258 * 8; i += 256) {
        int t = i >> 3, c0 = (i & 7) * 8;
        int g = m0 - 1 + t;
        s16x8 v = {};
        if (g >= 0 && g < 2048) v = *(const s16x8*)(inb + (size_t)g * 64 + c0);
        *(s16x8*)(sX + ((t * 72 + c0) << 1)) = v;
    }
    __syncthreads();
    float e = bias[0], o = bias[0];
#pragma unroll
    for (int c0 = 0; c0 < 64; c0 += 8) {
        s16x8 vm1 = *(const s16x8*)(sX + (((tid + 0) * 72 + c0) << 1));
        s16x8 v0  = *(const s16x8*)(sX + (((tid + 1) * 72 + c0) << 1));
        s16x8 vp1 = *(const s16x8*)(sX + (((tid + 2) * 72 + c0) << 1));
#pragma unroll
        for (int j = 0; j < 8; ++j) {
            int ci = c0 + j;
            float xm1 = bf2f((unsigned short)vm1[j]);
            float x0  = bf2f((unsigned short)v0[j]);
            float xp1 = bf2f((unsigned short)vp1[j]);
            e = fmaf(x0,  w[ci * 4 + 1], fmaf(xm1, w[ci * 4 + 3], e));
            o = fmaf(xp1, w[ci * 4 + 0], fmaf(x0,  w[ci * 4 + 2], o));
        }
    }
    int m = m0 + tid;
    out[(size_t)b * 4096 + 2 * m]     = e;
    out[(size_t)b * 4096 + 2 * m + 1] = o;
}

// Weight transform: fp32 conv weights -> bf16 [tap][co][ci] matrices.
__global__ __launch_bounds__(256) void wx_k(
    const float* ew2, const float* ew3, const float* er1a, const float* er1b,
    const float* er2a, const float* er2b, const float* pvw, const float* dw1,
    const float* dr1a, const float* dr1b, const float* dr2a, const float* dr2b,
    const float* ct1w, bf16* wb)
{
    const int job = blockIdx.x;
    bf16* dst = wb + (size_t)job * 65536;
    const float* src; int CO, CI, K;
    switch (job) {
        case 0:  src = ew2;  CO = 128; CI = 64;  K = 4; break;
        case 1:  src = ew3;  CO = 128; CI = 128; K = 3; break;
        case 2:  src = er1a; CO = 64;  CI = 128; K = 3; break;
        case 3:  src = er1b; CO = 128; CI = 64;  K = 1; break;
        case 4:  src = er2a; CO = 64;  CI = 128; K = 3; break;
        case 5:  src = er2b; CO = 128; CI = 64;  K = 1; break;
        case 6:  src = pvw;  CO = 64;  CI = 128; K = 1; break;
        case 7:  src = dw1;  CO = 128; CI = 64;  K = 3; break;
        case 8:  src = dr1a; CO = 64;  CI = 128; K = 3; break;
        case 9:  src = dr1b; CO = 128; CI = 64;  K = 1; break;
        case 10: src = dr2a; CO = 64;  CI = 128; K = 3; break;
        case 11: src = dr2b; CO = 128; CI = 64;  K = 1; break;
        default: src = ct1w; CO = 64;  CI = 128; K = 4; break;
    }
    const int tot = CO * CI * K;
    for (int i = blockIdx.y * 256 + threadIdx.x; i < tot; i += gridDim.y * 256) {
        if (job < 12) {
            int k = i / (CO * CI); int r = i - k * CO * CI;
            int co = r / CI; int ci = r - co * CI;
            dst[i] = __float2bfloat16(src[((size_t)co * CI + ci) * K + k]);
        } else {
            const int TAP[4] = {3, 1, 2, 0};
            int g = i / (64 * 128); int r = i - g * 64 * 128;
            int co = r / 128; int ci = r - co * 128;
            dst[i] = __float2bfloat16(src[((size_t)ci * 64 + co) * 4 + TAP[g]]);
        }
    }
}

// codebook prep: fp32 norms + hi/lo bf16 split
__global__ __launch_bounds__(256) void cbprep_k(
    const float* __restrict__ cb, bf16* __restrict__ cbh, bf16* __restrict__ cbl,
    float* __restrict__ sc)
{
    int k = blockIdx.x * 256 + threadIdx.x;
    const float* c = cb + (size_t)k * 64;
    float s = 0.f;
#pragma unroll
    for (int d = 0; d < 64; ++d) s = fmaf(c[d], c[d], s);
    sc[k] = s;
#pragma unroll
    for (int c0 = 0; c0 < 64; c0 += 8) {
        union { unsigned short u[8]; s16x8 v; } ph, pl;
#pragma unroll
        for (int j = 0; j < 8; ++j) {
            float v = c[c0 + j];
            unsigned short h = bfbits(v);
            ph.u[j] = h;
            pl.u[j] = bfbits(v - bf2f(h));
        }
        *(s16x8*)(cbh + (size_t)k * 64 + c0) = ph.v;
        *(s16x8*)(cbl + (size_t)k * 64 + c0) = pl.v;
    }
}

// Fused pre_vq + VQ. 1024 blocks x 128 positions. A tile / z tile alias.
__global__ __launch_bounds__(256, 4) void vqf_k(
    const bf16* __restrict__ A, const bf16* __restrict__ pvw,
    const float* __restrict__ pvb, const float* __restrict__ cbf,
    const bf16* __restrict__ cbh, const bf16* __restrict__ cbl,
    const float* __restrict__ sc, bf16* __restrict__ q,
    float* __restrict__ counts, float* __restrict__ loss_sum)
{
    __shared__ __align__(16) char sMem[34816];
    __shared__ float sSC[512];
    __shared__ float sHist[512];
    __shared__ int   sBK[128];
    __shared__ float sWS[4];
    const int tid = threadIdx.x;
    sSC[tid] = sc[tid]; sSC[tid + 256] = sc[tid + 256];
    sHist[tid] = 0.f;   sHist[tid + 256] = 0.f;

    const int n0 = blockIdx.x * 128;
    for (int i = tid; i < 128 * 16; i += 256) {
        int t = i >> 4, c0 = (i & 15) * 8;
        s16x8 v = *(const s16x8*)(A + (size_t)(n0 + t) * 128 + c0);
        *(s16x8*)(sMem + ((t * 136 + c0) << 1)) = v;
    }
    __syncthreads();

    const int lane = tid & 63, wid = tid >> 6;
    const int lr = lane & 15, kg = lane >> 4;
    const int pw0 = wid * 32;
    const f32x4 zf4 = {0.f, 0.f, 0.f, 0.f};

    f32x4 zacc[4][2];
#pragma unroll
    for (int cf = 0; cf < 4; ++cf)
#pragma unroll
        for (int lf = 0; lf < 2; ++lf) zacc[cf][lf] = zf4;
#pragma unroll
    for (int ks = 0; ks < 4; ++ks) {
        s16x8 af[4];
#pragma unroll
        for (int cf = 0; cf < 4; ++cf)
            af[cf] = *(const s16x8*)(pvw + (size_t)(cf * 16 + lr) * 128 + ks * 32 + kg * 8);
        s16x8 bfr[2];
#pragma unroll
        for (int lf = 0; lf < 2; ++lf) {
            int t = pw0 + lf * 16 + lr;
            bfr[lf] = *(const s16x8*)(sMem + ((t * 136 + ks * 32 + kg * 8) << 1));
        }
#pragma unroll
        for (int cf = 0; cf < 4; ++cf)
#pragma unroll
            for (int lf = 0; lf < 2; ++lf)
                zacc[cf][lf] = MFMA16(af[cf], bfr[lf], zacc[cf][lf]);
    }
    __syncthreads();

#pragma unroll
    for (int cf = 0; cf < 4; ++cf)
#pragma unroll
        for (int lf = 0; lf < 2; ++lf) {
            int pos = pw0 + lf * 16 + lr;
            int ch  = cf * 16 + kg * 4;
            float4 v = make_float4(zacc[cf][lf][0] + pvb[ch],
                                   zacc[cf][lf][1] + pvb[ch + 1],
                                   zacc[cf][lf][2] + pvb[ch + 2],
                                   zacc[cf][lf][3] + pvb[ch + 3]);
            *(float4*)(sMem + (pos * 68 + ch) * 4) = v;
        }
    __syncthreads();

    s16x8 bh[2][2], bl[2][2];
#pragma unroll
    for (int lf = 0; lf < 2; ++lf)
#pragma unroll
        for (int ks = 0; ks < 2; ++ks) {
            int t = pw0 + lf * 16 + lr;
            int ch = ks * 32 + kg * 8;
            float4 v0 = *(const float4*)(sMem + (t * 68 + ch) * 4);
            float4 v1 = *(const float4*)(sMem + (t * 68 + ch) * 4 + 16);
            float v[8] = {v0.x, v0.y, v0.z, v0.w, v1.x, v1.y, v1.z, v1.w};
            union { unsigned short u[8]; s16x8 s; } ph, pl;
#pragma unroll
            for (int j = 0; j < 8; ++j) {
                unsigned short h = bfbits(v[j]);
                ph.u[j] = h;
                pl.u[j] = bfbits(v[j] - bf2f(h));
            }
            bh[lf][ks] = ph.s; bl[lf][ks] = pl.s;
        }

    float bestd[2] = {3.4e38f, 3.4e38f};
    int   bestk[2] = {0, 0};
#pragma unroll 2
    for (int cf = 0; cf < 32; ++cf) {
        int code = cf * 16 + lr;
        const bf16* ph = cbh + code * 64 + kg * 8;
        const bf16* pl = cbl + code * 64 + kg * 8;
        s16x8 ah0 = *(const s16x8*)ph;
        s16x8 ah1 = *(const s16x8*)(ph + 32);
        s16x8 al0 = *(const s16x8*)pl;
        s16x8 al1 = *(const s16x8*)(pl + 32);
        float s0 = sSC[cf * 16 + kg * 4 + 0];
        float s1 = sSC[cf * 16 + kg * 4 + 1];
        float s2 = sSC[cf * 16 + kg * 4 + 2];
        float s3 = sSC[cf * 16 + kg * 4 + 3];
        int kb = cf * 16 + kg * 4;
#pragma unroll
        for (int lf = 0; lf < 2; ++lf) {
            f32x4 acc = MFMA16(ah0, bh[lf][0], zf4);
            acc = MFMA16(ah1, bh[lf][1], acc);
            acc = MFMA16(al0, bh[lf][0], acc);
            acc = MFMA16(al1, bh[lf][1], acc);
            acc = MFMA16(ah0, bl[lf][0], acc);
            acc = MFMA16(ah1, bl[lf][1], acc);
            float d0 = fmaf(acc[0], -2.f, s0);
            float d1 = fmaf(acc[1], -2.f, s1);
            float d2 = fmaf(acc[2], -2.f, s2);
            float d3 = fmaf(acc[3], -2.f, s3);
            if (d0 < bestd[lf]) { bestd[lf] = d0; bestk[lf] = kb; }
            if (d1 < bestd[lf]) { bestd[lf] = d1; bestk[lf] = kb + 1; }
            if (d2 < bestd[lf]) { bestd[lf] = d2; bestk[lf] = kb + 2; }
            if (d3 < bestd[lf]) { bestd[lf] = d3; bestk[lf] = kb + 3; }
        }
    }
#pragma unroll
    for (int lf = 0; lf < 2; ++lf) {
#pragma unroll
        for (int off = 16; off <= 32; off <<= 1) {
            float od = __shfl_xor(bestd[lf], off, 64);
            int   ok = __shfl_xor(bestk[lf], off, 64);
            if (od < bestd[lf] || (od == bestd[lf] && ok < bestk[lf])) {
                bestd[lf] = od; bestk[lf] = ok;
            }
        }
        if (kg == 0) sBK[pw0 + lf * 16 + lr] = bestk[lf];
    }
    __syncthreads();

    const int pos  = tid >> 1;
    const int half = tid & 1;
    const int k = sBK[pos];
    if (half == 0) atomicAdd(&sHist[k], 1.f);
    float lsum = 0.f;
    const float* qp = cbf + (size_t)k * 64 + half * 32;
    bf16* qo = q + (size_t)(n0 + pos) * 64 + half * 32;
#pragma unroll
    for (int c0 = 0; c0 < 32; c0 += 8) {
        int zb = (pos * 68 + half * 32 + c0) * 4;
        float4 z0 = *(const float4*)(sMem + zb);
        float4 z1 = *(const float4*)(sMem + zb + 16);
        float4 q0 = *(const float4*)(qp + c0);
        float4 q1 = *(const float4*)(qp + c0 + 4);
        float qv[8] = {q0.x, q0.y, q0.z, q0.w, q1.x, q1.y, q1.z, q1.w};
        float zv[8] = {z0.x, z0.y, z0.z, z0.w, z1.x, z1.y, z1.z, z1.w};
        union { unsigned short u[8]; s16x8 v; } pk;
#pragma unroll
        for (int j = 0; j < 8; ++j) {
            float d = qv[j] - zv[j];
            lsum = fmaf(d, d, lsum);
            pk.u[j] = bfbits(qv[j]);
        }
        *(s16x8*)(qo + c0) = pk.v;
    }
#pragma unroll
    for (int off = 32; off > 0; off >>= 1) lsum += __shfl_down(lsum, off, 64);
    if ((tid & 63) == 0) sWS[tid >> 6] = lsum;
    __syncthreads();
    if (tid == 0) atomicAdd(loss_sum, sWS[0] + sWS[1] + sWS[2] + sWS[3]);
    float c0v = sHist[tid];       if (c0v != 0.f) atomicAdd(&counts[tid], c0v);
    float c1v = sHist[tid + 256]; if (c1v != 0.f) atomicAdd(&counts[tid + 256], c1v);
}

__global__ __launch_bounds__(512) void finalize_k(
    const float* __restrict__ counts, const float* __restrict__ loss_sum,
    float* __restrict__ d_out, int out_size)
{
    __shared__ float ws2[8];
    const int tid = threadIdx.x;
    float p = counts[tid] * (1.f / 131072.f);
    float e = p * logf(p + 1e-10f);
#pragma unroll
    for (int off = 32; off > 0; off >>= 1) e += __shfl_down(e, off, 64);
    const int lane = tid & 63, wid = tid >> 6;
    if (lane == 0) ws2[wid] = e;
    __syncthreads();
    if (tid == 0) {
        float s = 0.f;
        for (int i = 0; i < 8; ++i) s += ws2[i];
        d_out[0] = 1.25f * loss_sum[0] * (1.f / 8388608.f);  // (1+BETA)*mean
        d_out[out_size - 1] = expf(-s);
    }
}

extern "C" void kernel_launch(void* const* d_in, const int* in_sizes, int n_in,
                              void* d_out, int out_size, void* d_ws, size_t ws_size,
                              hipStream_t stream)
{
    const float* x        = (const float*)d_in[0];
    const float* enc_w1   = (const float*)d_in[1];
    const float* enc_b1   = (const float*)d_in[2];
    const float* enc_b2   = (const float*)d_in[4];
    const float* enc_b3   = (const float*)d_in[6];
    const float* pre_vq_b = (const float*)d_in[12];
    const float* cb       = (const float*)d_in[13];
    const float* dec_b1   = (const float*)d_in[15];
    const float* ct1_b    = (const float*)d_in[21];
    const float* ct2_w    = (const float*)d_in[22];
    const float* ct2_b    = (const float*)d_in[23];
    float* out = (float*)d_out;

    char* base = (char*)d_ws;
    bf16*  wb   = (bf16*)base;
    bf16*  Abf  = (bf16*)(base + ((size_t)2   << 20));
    bf16*  Bbf  = (bf16*)(base + ((size_t)40  << 20));
    bf16*  Qbf  = (bf16*)(base + ((size_t)78  << 20));
    bf16*  cbh  = (bf16*)(base + ((size_t)96  << 20));
    bf16*  cbl  = (bf16*)(base + ((size_t)96  << 20) + 65536);
    float* sc   = (float*)(base + ((size_t)96  << 20) + 131072);
    float* cnt  = sc + 512;
    float* lsum = cnt + 512;

    (void)hipMemsetAsync(cnt, 0, 513 * sizeof(float), stream);

    dim3 blk(256);
    dim3 g16(16, 128);

    wx_k<<<dim3(13, 8), blk, 0, stream>>>(
        (const float*)d_in[3], (const float*)d_in[5], (const float*)d_in[7],
        (const float*)d_in[8], (const float*)d_in[9], (const float*)d_in[10],
        (const float*)d_in[11], (const float*)d_in[14], (const float*)d_in[16],
        (const float*)d_in[17], (const float*)d_in[18], (const float*)d_in[19],
        (const float*)d_in[20], wb);
    cbprep_k<<<2, blk, 0, stream>>>(cb, cbh, cbl, sc);

    enc12_k<<<g16, blk, 0, stream>>>(x, enc_w1, enc_b1, wb + 0 * 65536, enc_b2, Bbf);
    encmid_k<<<g16, blk, 0, stream>>>(Bbf, wb + 1 * 65536, enc_b3,
        wb + 2 * 65536, wb + 3 * 65536, wb + 4 * 65536, wb + 5 * 65536, Abf);

    vqf_k<<<1024, blk, 0, stream>>>(Abf, wb + 6 * 65536, pre_vq_b, cb,
                                    cbh, cbl, sc, Qbf, cnt, lsum);

    decmid_k<<<g16, blk, 0, stream>>>(Qbf, wb + 7 * 65536, dec_b1,
        wb + 8 * 65536, wb + 9 * 65536, wb + 10 * 65536, wb + 11 * 65536,
        wb + 12 * 65536, ct1_b, Bbf);

    ct2_k<<<dim3(8, 128), blk, 0, stream>>>(Bbf, ct2_w, ct2_b, out + 1);
    finalize_k<<<1, 512, 0, stream>>>(cnt, lsum, out, out_size);
}

// Round 15
// 354.551 us; speedup vs baseline: 2.0133x; 1.0239x over previous
//
#include <hip/hip_runtime.h>
#include <hip/hip_bf16.h>
#include <math.h>

using bf16 = __hip_bfloat16;
typedef __attribute__((ext_vector_type(4))) float f32x4;
typedef __attribute__((ext_vector_type(8))) short s16x8;

#define MFMA16(a,b,c) __builtin_amdgcn_mfma_f32_16x16x32_bf16((a),(b),(c),0,0,0)

// ---------------------------------------------------------------------------
// VQ-VAE forward. B=128, L=4096, H=128, RH=64, D=64, K=512.
// Round-9 structure; decmid launch_bounds 4->3 to eliminate VGPR spills.
// ---------------------------------------------------------------------------

__device__ inline float bf2f(unsigned short u) {
    union { float f; unsigned v; } c; c.v = ((unsigned)u) << 16; return c.f;
}
__device__ inline unsigned short bfbits(float f) {
    union { bf16 h; unsigned short u; } c; c.h = __float2bfloat16(f); return c.u;
}
__device__ inline s16x8 relu8(s16x8 v) {
#pragma unroll
    for (int j = 0; j < 8; ++j)
        v[j] = (short)(((unsigned short)v[j] & 0x8000u) ? 0 : (unsigned short)v[j]);
    return v;
}
__device__ inline uint2 pack4(float a, float b, float c, float d) {
    uint2 p;
    p.x = (unsigned)bfbits(a) | ((unsigned)bfbits(b) << 16);
    p.y = (unsigned)bfbits(c) | ((unsigned)bfbits(d) << 16);
    return p;
}

// ===========================================================================
// encmid: enc3 (128->128 K3) + res1 + res2 + final relu.  Bbf -> Abf.
// sY 80x272B @0; sX 96x272B @21760; sH 80x144B aliases sX. 3 blocks/CU.
// ===========================================================================
__global__ __launch_bounds__(256, 3) void encmid_k(
    const bf16* __restrict__ in, const bf16* __restrict__ w3t,
    const float* __restrict__ b3, const bf16* __restrict__ r1w1,
    const bf16* __restrict__ r1w2, const bf16* __restrict__ r2w1,
    const bf16* __restrict__ r2w2, bf16* __restrict__ out)
{
    __shared__ __align__(16) char smem[47872];
    char* sY = smem;
    char* sX = smem + 21760;
    char* sH = smem + 21760;
    const int tid = threadIdx.x;
    const int b   = blockIdx.y;
    const int l0  = blockIdx.x * 64;
    const bf16* inb = in + (size_t)b * 1024 * 128;

    for (int i = tid; i < 96 * 16; i += 256) {
        int t = i >> 4, c0 = (i & 15) * 8;
        int g = l0 - 16 + t;
        s16x8 v = {};
        if (g >= 0 && g < 1024) v = *(const s16x8*)(inb + (size_t)g * 128 + c0);
        *(s16x8*)(sX + ((t * 136 + c0) << 1)) = v;
    }
    __syncthreads();

    const int lane = tid & 63;
    const int wid  = __builtin_amdgcn_readfirstlane(tid >> 6);
    const int lr   = lane & 15;
    const int kg   = lane >> 4;
    const f32x4 zf4 = {0.f, 0.f, 0.f, 0.f};

    // ---- phase 1: enc3 -> sY (80 rows x 128 co), bias, OOR-zero ----
    {
        const int co0 = wid * 32;
        f32x4 acc[2][5];
#pragma unroll
        for (int cf = 0; cf < 2; ++cf)
#pragma unroll
            for (int lf = 0; lf < 5; ++lf) acc[cf][lf] = zf4;
#pragma unroll
        for (int k = 0; k < 3; ++k) {
            const bf16* Ab = w3t + (size_t)k * 128 * 128;
#pragma unroll
            for (int ks = 0; ks < 4; ++ks) {
                s16x8 af[2];
#pragma unroll
                for (int cf = 0; cf < 2; ++cf)
                    af[cf] = *(const s16x8*)(Ab + (co0 + cf * 16 + lr) * 128 + ks * 32 + kg * 8);
                s16x8 bfr[5];
#pragma unroll
                for (int lf = 0; lf < 5; ++lf) {
                    int tx = lf * 16 + lr + 7 + k;
                    bfr[lf] = *(const s16x8*)(sX + ((tx * 136 + ks * 32 + kg * 8) << 1));
                }
#pragma unroll
                for (int cf = 0; cf < 2; ++cf)
#pragma unroll
                    for (int lf = 0; lf < 5; ++lf)
                        acc[cf][lf] = MFMA16(af[cf], bfr[lf], acc[cf][lf]);
            }
        }
        __syncthreads();   // sX reads done before sH alias writes later
#pragma unroll
        for (int cf = 0; cf < 2; ++cf)
#pragma unroll
            for (int lf = 0; lf < 5; ++lf) {
                int row = lf * 16 + lr;
                int p   = l0 - 8 + row;
                int cb0 = co0 + cf * 16 + kg * 4;
                bool ok = (p >= 0 && p < 1024);
                float r[4];
#pragma unroll
                for (int j = 0; j < 4; ++j)
                    r[j] = ok ? (acc[cf][lf][j] + b3[cb0 + j]) : 0.f;
                *(uint2*)(sY + ((row * 136 + cb0) << 1)) = pack4(r[0], r[1], r[2], r[3]);
            }
    }
    __syncthreads();

    // ---- phases 2..5: two res blocks ----
#pragma unroll 1
    for (int blk2 = 0; blk2 < 2; ++blk2) {
        const bf16* w1 = blk2 ? r2w1 : r1w1;
        {
            const int co0 = wid * 16;
            f32x4 acc[5];
#pragma unroll
            for (int lf = 0; lf < 5; ++lf) acc[lf] = zf4;
#pragma unroll
            for (int k = 0; k < 3; ++k) {
                const bf16* Ab = w1 + (size_t)k * 64 * 128;
#pragma unroll
                for (int ks = 0; ks < 4; ++ks) {
                    s16x8 a = *(const s16x8*)(Ab + (co0 + lr) * 128 + ks * 32 + kg * 8);
                    s16x8 bfr[5];
#pragma unroll
                    for (int lf = 0; lf < 5; ++lf) {
                        int ry = lf * 16 + lr + k - 1;
                        ry = (ry < 0) ? 0 : (ry > 79 ? 79 : ry);
                        bfr[lf] = relu8(*(const s16x8*)(sY + ((ry * 136 + ks * 32 + kg * 8) << 1)));
                    }
#pragma unroll
                    for (int lf = 0; lf < 5; ++lf)
                        acc[lf] = MFMA16(a, bfr[lf], acc[lf]);
                }
            }
#pragma unroll
            for (int lf = 0; lf < 5; ++lf) {
                int row = lf * 16 + lr;
                int ch0 = co0 + kg * 4;
                *(uint2*)(sH + ((row * 72 + ch0) << 1)) =
                    pack4(fmaxf(acc[lf][0], 0.f), fmaxf(acc[lf][1], 0.f),
                          fmaxf(acc[lf][2], 0.f), fmaxf(acc[lf][3], 0.f));
            }
        }
        __syncthreads();

        if (blk2 == 0) {
            const int co0 = wid * 32;
            f32x4 acc[2][5];
#pragma unroll
            for (int cf = 0; cf < 2; ++cf)
#pragma unroll
                for (int lf = 0; lf < 5; ++lf) acc[cf][lf] = zf4;
#pragma unroll
            for (int ks = 0; ks < 2; ++ks) {
                s16x8 af[2];
#pragma unroll
                for (int cf = 0; cf < 2; ++cf)
                    af[cf] = *(const s16x8*)(r1w2 + (size_t)(co0 + cf * 16 + lr) * 64 + ks * 32 + kg * 8);
                s16x8 bfr[5];
#pragma unroll
                for (int lf = 0; lf < 5; ++lf) {
                    int row = lf * 16 + lr;
                    bfr[lf] = *(const s16x8*)(sH + ((row * 72 + ks * 32 + kg * 8) << 1));
                }
#pragma unroll
                for (int cf = 0; cf < 2; ++cf)
#pragma unroll
                    for (int lf = 0; lf < 5; ++lf)
                        acc[cf][lf] = MFMA16(af[cf], bfr[lf], acc[cf][lf]);
            }
#pragma unroll
            for (int cf = 0; cf < 2; ++cf)
#pragma unroll
                for (int lf = 0; lf < 5; ++lf) {
                    int row = lf * 16 + lr;
                    int p   = l0 - 8 + row;
                    int cb0 = co0 + cf * 16 + kg * 4;
                    uint2 old = *(const uint2*)(sY + ((row * 136 + cb0) << 1));
                    bool ok = (p >= 0 && p < 1024);
                    float r0 = acc[cf][lf][0] + bf2f((unsigned short)(old.x & 0xffff));
                    float r1 = acc[cf][lf][1] + bf2f((unsigned short)(old.x >> 16));
                    float r2 = acc[cf][lf][2] + bf2f((unsigned short)(old.y & 0xffff));
                    float r3 = acc[cf][lf][3] + bf2f((unsigned short)(old.y >> 16));
                    uint2 pk = pack4(r0, r1, r2, r3);
                    if (!ok) { pk.x = 0u; pk.y = 0u; }
                    *(uint2*)(sY + ((row * 136 + cb0) << 1)) = pk;
                }
            __syncthreads();
        } else {
            const int co0 = wid * 32;
            f32x4 acc[2][4];
#pragma unroll
            for (int cf = 0; cf < 2; ++cf)
#pragma unroll
                for (int lf = 0; lf < 4; ++lf) acc[cf][lf] = zf4;
#pragma unroll
            for (int ks = 0; ks < 2; ++ks) {
                s16x8 af[2];
#pragma unroll
                for (int cf = 0; cf < 2; ++cf)
                    af[cf] = *(const s16x8*)(r2w2 + (size_t)(co0 + cf * 16 + lr) * 64 + ks * 32 + kg * 8);
                s16x8 bfr[4];
#pragma unroll
                for (int lf = 0; lf < 4; ++lf) {
                    int row = 8 + lf * 16 + lr;
                    bfr[lf] = *(const s16x8*)(sH + ((row * 72 + ks * 32 + kg * 8) << 1));
                }
#pragma unroll
                for (int cf = 0; cf < 2; ++cf)
#pragma unroll
                    for (int lf = 0; lf < 4; ++lf)
                        acc[cf][lf] = MFMA16(af[cf], bfr[lf], acc[cf][lf]);
            }
#pragma unroll
            for (int cf = 0; cf < 2; ++cf)
#pragma unroll
                for (int lf = 0; lf < 4; ++lf) {
                    int row = 8 + lf * 16 + lr;
                    int cb0 = co0 + cf * 16 + kg * 4;
                    uint2 old = *(const uint2*)(sY + ((row * 136 + cb0) << 1));
                    float r0 = fmaxf(acc[cf][lf][0] + bf2f((unsigned short)(old.x & 0xffff)), 0.f);
                    float r1 = fmaxf(acc[cf][lf][1] + bf2f((unsigned short)(old.x >> 16)), 0.f);
                    float r2 = fmaxf(acc[cf][lf][2] + bf2f((unsigned short)(old.y & 0xffff)), 0.f);
                    float r3 = fmaxf(acc[cf][lf][3] + bf2f((unsigned short)(old.y >> 16)), 0.f);
                    *(uint2*)(out + ((size_t)b * 1024 + l0 + lf * 16 + lr) * 128 + cb0) =
                        pack4(r0, r1, r2, r3);
                }
        }
    }
}

// ===========================================================================
// decmid: dec1 + res1 + res2(+relu) + ct1 convT.  Qbf -> (b,2048,64) bf16.
// sY 80x272B @0; sQ 96x144B @21760; sH aliases sQ. 3 blocks/CU (no spills).
// ===========================================================================
__global__ __launch_bounds__(256, 3) void decmid_k(
    const bf16* __restrict__ qin, const bf16* __restrict__ dw1,
    const float* __restrict__ db1, const bf16* __restrict__ r1w1,
    const bf16* __restrict__ r1w2, const bf16* __restrict__ r2w1,
    const bf16* __restrict__ r2w2, const bf16* __restrict__ ct1w,
    const float* __restrict__ ct1b, bf16* __restrict__ out)
{
    __shared__ __align__(16) char smem[35584];
    char* sY = smem;
    char* sQ = smem + 21760;
    char* sH = smem + 21760;
    const int tid = threadIdx.x;
    const int b   = blockIdx.y;
    const int l0  = blockIdx.x * 64;
    const bf16* inb = qin + (size_t)b * 1024 * 64;

    for (int i = tid; i < 96 * 8; i += 256) {
        int t = i >> 3, c0 = (i & 7) * 8;
        int g = l0 - 16 + t;
        s16x8 v = {};
        if (g >= 0 && g < 1024) v = *(const s16x8*)(inb + (size_t)g * 64 + c0);
        *(s16x8*)(sQ + ((t * 72 + c0) << 1)) = v;
    }
    __syncthreads();

    const int lane = tid & 63;
    const int wid  = __builtin_amdgcn_readfirstlane(tid >> 6);
    const int lr   = lane & 15;
    const int kg   = lane >> 4;
    const f32x4 zf4 = {0.f, 0.f, 0.f, 0.f};

    // ---- phase 1: dec1 -> sY, bias, OOR-zero ----
    {
        const int co0 = wid * 32;
        f32x4 acc[2][5];
#pragma unroll
        for (int cf = 0; cf < 2; ++cf)
#pragma unroll
            for (int lf = 0; lf < 5; ++lf) acc[cf][lf] = zf4;
#pragma unroll
        for (int k = 0; k < 3; ++k) {
            const bf16* Ab = dw1 + (size_t)k * 128 * 64;
#pragma unroll
            for (int ks = 0; ks < 2; ++ks) {
                s16x8 af[2];
#pragma unroll
                for (int cf = 0; cf < 2; ++cf)
                    af[cf] = *(const s16x8*)(Ab + (co0 + cf * 16 + lr) * 64 + ks * 32 + kg * 8);
                s16x8 bfr[5];
#pragma unroll
                for (int lf = 0; lf < 5; ++lf) {
                    int tx = lf * 16 + lr + 7 + k;
                    bfr[lf] = *(const s16x8*)(sQ + ((tx * 72 + ks * 32 + kg * 8) << 1));
                }
#pragma unroll
                for (int cf = 0; cf < 2; ++cf)
#pragma unroll
                    for (int lf = 0; lf < 5; ++lf)
                        acc[cf][lf] = MFMA16(af[cf], bfr[lf], acc[cf][lf]);
            }
        }
        __syncthreads();   // sQ reads complete before sH alias overwrite
#pragma unroll
        for (int cf = 0; cf < 2; ++cf)
#pragma unroll
            for (int lf = 0; lf < 5; ++lf) {
                int row = lf * 16 + lr;
                int p   = l0 - 8 + row;
                int cb0 = co0 + cf * 16 + kg * 4;
                bool ok = (p >= 0 && p < 1024);
                float r[4];
#pragma unroll
                for (int j = 0; j < 4; ++j)
                    r[j] = ok ? (acc[cf][lf][j] + db1[cb0 + j]) : 0.f;
                *(uint2*)(sY + ((row * 136 + cb0) << 1)) = pack4(r[0], r[1], r[2], r[3]);
            }
    }
    __syncthreads();

    // ---- res blocks ----
#pragma unroll 1
    for (int blk2 = 0; blk2 < 2; ++blk2) {
        const bf16* w1 = blk2 ? r2w1 : r1w1;
        const bf16* w2 = blk2 ? r2w2 : r1w2;
        {
            const int co0 = wid * 16;
            f32x4 acc[5];
#pragma unroll
            for (int lf = 0; lf < 5; ++lf) acc[lf] = zf4;
#pragma unroll
            for (int k = 0; k < 3; ++k) {
                const bf16* Ab = w1 + (size_t)k * 64 * 128;
#pragma unroll
                for (int ks = 0; ks < 4; ++ks) {
                    s16x8 a = *(const s16x8*)(Ab + (co0 + lr) * 128 + ks * 32 + kg * 8);
                    s16x8 bfr[5];
#pragma unroll
                    for (int lf = 0; lf < 5; ++lf) {
                        int ry = lf * 16 + lr + k - 1;
                        ry = (ry < 0) ? 0 : (ry > 79 ? 79 : ry);
                        bfr[lf] = relu8(*(const s16x8*)(sY + ((ry * 136 + ks * 32 + kg * 8) << 1)));
                    }
#pragma unroll
                    for (int lf = 0; lf < 5; ++lf)
                        acc[lf] = MFMA16(a, bfr[lf], acc[lf]);
                }
            }
#pragma unroll
            for (int lf = 0; lf < 5; ++lf) {
                int row = lf * 16 + lr;
                int ch0 = co0 + kg * 4;
                *(uint2*)(sH + ((row * 72 + ch0) << 1)) =
                    pack4(fmaxf(acc[lf][0], 0.f), fmaxf(acc[lf][1], 0.f),
                          fmaxf(acc[lf][2], 0.f), fmaxf(acc[lf][3], 0.f));
            }
        }
        __syncthreads();
        {
            const int co0 = wid * 32;
            f32x4 acc[2][5];
#pragma unroll
            for (int cf = 0; cf < 2; ++cf)
#pragma unroll
                for (int lf = 0; lf < 5; ++lf) acc[cf][lf] = zf4;
#pragma unroll
            for (int ks = 0; ks < 2; ++ks) {
                s16x8 af[2];
#pragma unroll
                for (int cf = 0; cf < 2; ++cf)
                    af[cf] = *(const s16x8*)(w2 + (size_t)(co0 + cf * 16 + lr) * 64 + ks * 32 + kg * 8);
                s16x8 bfr[5];
#pragma unroll
                for (int lf = 0; lf < 5; ++lf) {
                    int row = lf * 16 + lr;
                    bfr[lf] = *(const s16x8*)(sH + ((row * 72 + ks * 32 + kg * 8) << 1));
                }
#pragma unroll
                for (int cf = 0; cf < 2; ++cf)
#pragma unroll
                    for (int lf = 0; lf < 5; ++lf)
                        acc[cf][lf] = MFMA16(af[cf], bfr[lf], acc[cf][lf]);
            }
#pragma unroll
            for (int cf = 0; cf < 2; ++cf)
#pragma unroll
                for (int lf = 0; lf < 5; ++lf) {
                    int row = lf * 16 + lr;
                    int p   = l0 - 8 + row;
                    int cb0 = co0 + cf * 16 + kg * 4;
                    uint2 old = *(const uint2*)(sY + ((row * 136 + cb0) << 1));
                    bool ok = (p >= 0 && p < 1024);
                    float r0 = acc[cf][lf][0] + bf2f((unsigned short)(old.x & 0xffff));
                    float r1 = acc[cf][lf][1] + bf2f((unsigned short)(old.x >> 16));
                    float r2 = acc[cf][lf][2] + bf2f((unsigned short)(old.y & 0xffff));
                    float r3 = acc[cf][lf][3] + bf2f((unsigned short)(old.y >> 16));
                    if (blk2 == 1) {
                        r0 = fmaxf(r0, 0.f); r1 = fmaxf(r1, 0.f);
                        r2 = fmaxf(r2, 0.f); r3 = fmaxf(r3, 0.f);
                    }
                    uint2 pk = pack4(r0, r1, r2, r3);
                    if (!ok) { pk.x = 0u; pk.y = 0u; }
                    *(uint2*)(sY + ((row * 136 + cb0) << 1)) = pk;
                }
        }
        __syncthreads();
    }

    // ---- ct1 convT (CO=64): direct uint2 stores ----
    {
        const int co0 = (wid & 1) * 32;
        const int mh  = wid >> 1;
        f32x4 acc[2][2][2];
#pragma unroll
        for (int g = 0; g < 2; ++g)
#pragma unroll
            for (int cf = 0; cf < 2; ++cf)
#pragma unroll
                for (int j = 0; j < 2; ++j) acc[g][cf][j] = zf4;
#pragma unroll
        for (int g = 0; g < 2; ++g)
#pragma unroll
            for (int k = 0; k < 2; ++k) {
                const bf16* Ab = ct1w + (size_t)(g * 2 + k) * 64 * 128;
                const int doff = (g == 0) ? (k - 1) : k;
#pragma unroll
                for (int ks = 0; ks < 4; ++ks) {
                    s16x8 af[2];
#pragma unroll
                    for (int cf = 0; cf < 2; ++cf)
                        af[cf] = *(const s16x8*)(Ab + (co0 + cf * 16 + lr) * 128 + ks * 32 + kg * 8);
                    s16x8 bfr[2];
#pragma unroll
                    for (int j = 0; j < 2; ++j) {
                        int ty = 8 + (mh * 2 + j) * 16 + lr + doff;
                        bfr[j] = *(const s16x8*)(sY + ((ty * 136 + ks * 32 + kg * 8) << 1));
                    }
#pragma unroll
                    for (int cf = 0; cf < 2; ++cf)
#pragma unroll
                        for (int j = 0; j < 2; ++j)
                            acc[g][cf][j] = MFMA16(af[cf], bfr[j], acc[g][cf][j]);
                }
            }
#pragma unroll
        for (int g = 0; g < 2; ++g)
#pragma unroll
            for (int cf = 0; cf < 2; ++cf)
#pragma unroll
                for (int j = 0; j < 2; ++j) {
                    int m   = (mh * 2 + j) * 16 + lr;
                    int cb0 = co0 + cf * 16 + kg * 4;
                    float r[4];
#pragma unroll
                    for (int jj = 0; jj < 4; ++jj)
                        r[jj] = fmaxf(acc[g][cf][j][jj] + ct1b[cb0 + jj], 0.f);
                    *(uint2*)(out + ((size_t)b * 2048 + 2 * (l0 + m) + g) * 64 + cb0) =
                        pack4(r[0], r[1], r[2], r[3]);
                }
    }
}

// Fused enc1+enc2: x fp32 -> h1 (LDS, stride 72) -> enc2 GEMM -> bf16 relu.
__global__ __launch_bounds__(256) void enc12_k(
    const float* __restrict__ x, const float* __restrict__ w1,
    const float* __restrict__ b1, const bf16* __restrict__ w2t,
    const float* __restrict__ b2, bf16* __restrict__ out)
{
    __shared__ float sXf[268];
    __shared__ float sW1[256];
    __shared__ float sB1[64];
    __shared__ __align__(16) char sX[132 * 144];
    const int tid = threadIdx.x;
    const int b   = blockIdx.y;
    const int l0  = blockIdx.x * 64;
    const float* xb = x + (size_t)b * 4096;

    for (int i = tid; i < 266; i += 256) {
        int g = 4 * l0 - 3 + i;
        sXf[i] = (g >= 0 && g < 4096) ? xb[g] : 0.f;
    }
    if (tid < 256) sW1[tid] = w1[tid];
    if (tid < 64)  sB1[tid] = b1[tid];
    __syncthreads();

    for (int i = tid; i < 132 * 64; i += 256) {
        int t = i >> 6, c = i & 63;
        int p = (t < 66) ? 2 * (l0 + t) : 2 * (l0 + t - 66) - 1;
        float v = 0.f;
        if (p >= 0 && p < 2048) {
            int xi = 2 * p - 4 * l0 + 2;
            float a = sB1[c];
#pragma unroll
            for (int k = 0; k < 4; ++k) a = fmaf(sXf[xi + k], sW1[c * 4 + k], a);
            v = fmaxf(a, 0.f);
        }
        *(bf16*)(sX + ((t * 72 + c) << 1)) = __float2bfloat16(v);
    }
    __syncthreads();

    const int lane = tid & 63;
    const int wid  = __builtin_amdgcn_readfirstlane(tid >> 6);
    const int co0  = wid * 32;
    const int lr   = lane & 15;
    const int kg   = lane >> 4;

    f32x4 acc[2][4];
#pragma unroll
    for (int cf = 0; cf < 2; ++cf)
#pragma unroll
        for (int lf = 0; lf < 4; ++lf) acc[cf][lf] = (f32x4){0.f, 0.f, 0.f, 0.f};

#pragma unroll
    for (int k = 0; k < 4; ++k) {
        const int roff = (k == 0) ? 66 : (k == 1) ? 0 : (k == 2) ? 67 : 1;
        const bf16* Ab = w2t + (size_t)k * 128 * 64;
#pragma unroll
        for (int ks = 0; ks < 2; ++ks) {
            s16x8 af[2];
#pragma unroll
            for (int cf = 0; cf < 2; ++cf)
                af[cf] = *(const s16x8*)(Ab + (co0 + cf * 16 + lr) * 64 + ks * 32 + kg * 8);
            s16x8 bfr[4];
#pragma unroll
            for (int lf = 0; lf < 4; ++lf) {
                int t = roff + lf * 16 + lr;
                bfr[lf] = *(const s16x8*)(sX + ((t * 72 + ks * 32 + kg * 8) << 1));
            }
#pragma unroll
            for (int cf = 0; cf < 2; ++cf)
#pragma unroll
                for (int lf = 0; lf < 4; ++lf)
                    acc[cf][lf] = MFMA16(af[cf], bfr[lf], acc[cf][lf]);
        }
    }

#pragma unroll
    for (int cf = 0; cf < 2; ++cf)
#pragma unroll
        for (int lf = 0; lf < 4; ++lf) {
            int cb0  = co0 + cf * 16 + kg * 4;
            int lcol = lf * 16 + lr;
            float r[4];
#pragma unroll
            for (int j = 0; j < 4; ++j)
                r[j] = fmaxf(acc[cf][lf][j] + b2[cb0 + j], 0.f);
            *(uint2*)(out + ((size_t)b * 1024 + l0 + lcol) * 128 + cb0) =
                pack4(r[0], r[1], r[2], r[3]);
        }
}

// Final convT: 64->1 ch, x2 upsample; fp32 out.
__global__ __launch_bounds__(256) void ct2_k(
    const bf16* __restrict__ in, const float* __restrict__ w,
    const float* __restrict__ bias, float* __restrict__ out)
{
    __shared__ __align__(16) char sX[258 * 144];
    const int tid = threadIdx.x;
    const int b   = blockIdx.y;
    const int m0  = blockIdx.x * 256;
    const bf16* inb = in + (size_t)b * 2048 * 64;
    for (int i = tid; i < 258 * 8; i += 256) {
        int t = i >> 3, c0 = (i & 7) * 8;
        int g = m0 - 1 + t;
        s16x8 v = {};
        if (g >= 0 && g < 2048) v = *(const s16x8*)(inb + (size_t)g * 64 + c0);
        *(s16x8*)(sX + ((t * 72 + c0) << 1)) = v;
    }
    __syncthreads();
    float e = bias[0], o = bias[0];
#pragma unroll
    for (int c0 = 0; c0 < 64; c0 += 8) {
        s16x8 vm1 = *(const s16x8*)(sX + (((tid + 0) * 72 + c0) << 1));
        s16x8 v0  = *(const s16x8*)(sX + (((tid + 1) * 72 + c0) << 1));
        s16x8 vp1 = *(const s16x8*)(sX + (((tid + 2) * 72 + c0) << 1));
#pragma unroll
        for (int j = 0; j < 8; ++j) {
            int ci = c0 + j;
            float xm1 = bf2f((unsigned short)vm1[j]);
            float x0  = bf2f((unsigned short)v0[j]);
            float xp1 = bf2f((unsigned short)vp1[j]);
            e = fmaf(x0,  w[ci * 4 + 1], fmaf(xm1, w[ci * 4 + 3], e));
            o = fmaf(xp1, w[ci * 4 + 0], fmaf(x0,  w[ci * 4 + 2], o));
        }
    }
    int m = m0 + tid;
    out[(size_t)b * 4096 + 2 * m]     = e;
    out[(size_t)b * 4096 + 2 * m + 1] = o;
}

// Weight transform: fp32 conv weights -> bf16 [tap][co][ci] matrices.
__global__ __launch_bounds__(256) void wx_k(
    const float* ew2, const float* ew3, const float* er1a, const float* er1b,
    const float* er2a, const float* er2b, const float* pvw, const float* dw1,
    const float* dr1a, const float* dr1b, const float* dr2a, const float* dr2b,
    const float* ct1w, bf16* wb)
{
    const int job = blockIdx.x;
    bf16* dst = wb + (size_t)job * 65536;
    const float* src; int CO, CI, K;
    switch (job) {
        case 0:  src = ew2;  CO = 128; CI = 64;  K = 4; break;
        case 1:  src = ew3;  CO = 128; CI = 128; K = 3; break;
        case 2:  src = er1a; CO = 64;  CI = 128; K = 3; break;
        case 3:  src = er1b; CO = 128; CI = 64;  K = 1; break;
        case 4:  src = er2a; CO = 64;  CI = 128; K = 3; break;
        case 5:  src = er2b; CO = 128; CI = 64;  K = 1; break;
        case 6:  src = pvw;  CO = 64;  CI = 128; K = 1; break;
        case 7:  src = dw1;  CO = 128; CI = 64;  K = 3; break;
        case 8:  src = dr1a; CO = 64;  CI = 128; K = 3; break;
        case 9:  src = dr1b; CO = 128; CI = 64;  K = 1; break;
        case 10: src = dr2a; CO = 64;  CI = 128; K = 3; break;
        case 11: src = dr2b; CO = 128; CI = 64;  K = 1; break;
        default: src = ct1w; CO = 64;  CI = 128; K = 4; break;
    }
    const int tot = CO * CI * K;
    for (int i = blockIdx.y * 256 + threadIdx.x; i < tot; i += gridDim.y * 256) {
        if (job < 12) {
            int k = i / (CO * CI); int r = i - k * CO * CI;
            int co = r / CI; int ci = r - co * CI;
            dst[i] = __float2bfloat16(src[((size_t)co * CI + ci) * K + k]);
        } else {
            const int TAP[4] = {3, 1, 2, 0};
            int g = i / (64 * 128); int r = i - g * 64 * 128;
            int co = r / 128; int ci = r - co * 128;
            dst[i] = __float2bfloat16(src[((size_t)ci * 64 + co) * 4 + TAP[g]]);
        }
    }
}

// codebook prep: fp32 norms + hi/lo bf16 split
__global__ __launch_bounds__(256) void cbprep_k(
    const float* __restrict__ cb, bf16* __restrict__ cbh, bf16* __restrict__ cbl,
    float* __restrict__ sc)
{
    int k = blockIdx.x * 256 + threadIdx.x;
    const float* c = cb + (size_t)k * 64;
    float s = 0.f;
#pragma unroll
    for (int d = 0; d < 64; ++d) s = fmaf(c[d], c[d], s);
    sc[k] = s;
#pragma unroll
    for (int c0 = 0; c0 < 64; c0 += 8) {
        union { unsigned short u[8]; s16x8 v; } ph, pl;
#pragma unroll
        for (int j = 0; j < 8; ++j) {
            float v = c[c0 + j];
            unsigned short h = bfbits(v);
            ph.u[j] = h;
            pl.u[j] = bfbits(v - bf2f(h));
        }
        *(s16x8*)(cbh + (size_t)k * 64 + c0) = ph.v;
        *(s16x8*)(cbl + (size_t)k * 64 + c0) = pl.v;
    }
}

// Fused pre_vq + VQ. 1024 blocks x 128 positions. A tile / z tile alias.
__global__ __launch_bounds__(256, 4) void vqf_k(
    const bf16* __restrict__ A, const bf16* __restrict__ pvw,
    const float* __restrict__ pvb, const float* __restrict__ cbf,
    const bf16* __restrict__ cbh, const bf16* __restrict__ cbl,
    const float* __restrict__ sc, bf16* __restrict__ q,
    float* __restrict__ counts, float* __restrict__ loss_sum)
{
    __shared__ __align__(16) char sMem[34816];
    __shared__ float sSC[512];
    __shared__ float sHist[512];
    __shared__ int   sBK[128];
    __shared__ float sWS[4];
    const int tid = threadIdx.x;
    sSC[tid] = sc[tid]; sSC[tid + 256] = sc[tid + 256];
    sHist[tid] = 0.f;   sHist[tid + 256] = 0.f;

    const int n0 = blockIdx.x * 128;
    for (int i = tid; i < 128 * 16; i += 256) {
        int t = i >> 4, c0 = (i & 15) * 8;
        s16x8 v = *(const s16x8*)(A + (size_t)(n0 + t) * 128 + c0);
        *(s16x8*)(sMem + ((t * 136 + c0) << 1)) = v;
    }
    __syncthreads();

    const int lane = tid & 63, wid = tid >> 6;
    const int lr = lane & 15, kg = lane >> 4;
    const int pw0 = wid * 32;
    const f32x4 zf4 = {0.f, 0.f, 0.f, 0.f};

    f32x4 zacc[4][2];
#pragma unroll
    for (int cf = 0; cf < 4; ++cf)
#pragma unroll
        for (int lf = 0; lf < 2; ++lf) zacc[cf][lf] = zf4;
#pragma unroll
    for (int ks = 0; ks < 4; ++ks) {
        s16x8 af[4];
#pragma unroll
        for (int cf = 0; cf < 4; ++cf)
            af[cf] = *(const s16x8*)(pvw + (size_t)(cf * 16 + lr) * 128 + ks * 32 + kg * 8);
        s16x8 bfr[2];
#pragma unroll
        for (int lf = 0; lf < 2; ++lf) {
            int t = pw0 + lf * 16 + lr;
            bfr[lf] = *(const s16x8*)(sMem + ((t * 136 + ks * 32 + kg * 8) << 1));
        }
#pragma unroll
        for (int cf = 0; cf < 4; ++cf)
#pragma unroll
            for (int lf = 0; lf < 2; ++lf)
                zacc[cf][lf] = MFMA16(af[cf], bfr[lf], zacc[cf][lf]);
    }
    __syncthreads();

#pragma unroll
    for (int cf = 0; cf < 4; ++cf)
#pragma unroll
        for (int lf = 0; lf < 2; ++lf) {
            int pos = pw0 + lf * 16 + lr;
            int ch  = cf * 16 + kg * 4;
            float4 v = make_float4(zacc[cf][lf][0] + pvb[ch],
                                   zacc[cf][lf][1] + pvb[ch + 1],
                                   zacc[cf][lf][2] + pvb[ch + 2],
                                   zacc[cf][lf][3] + pvb[ch + 3]);
            *(float4*)(sMem + (pos * 68 + ch) * 4) = v;
        }
    __syncthreads();

    s16x8 bh[2][2], bl[2][2];
#pragma unroll
    for (int lf = 0; lf < 2; ++lf)
#pragma unroll
        for (int ks = 0; ks < 2; ++ks) {
            int t = pw0 + lf * 16 + lr;
            int ch = ks * 32 + kg * 8;
            float4 v0 = *(const float4*)(sMem + (t * 68 + ch) * 4);
            float4 v1 = *(const float4*)(sMem + (t * 68 + ch) * 4 + 16);
            float v[8] = {v0.x, v0.y, v0.z, v0.w, v1.x, v1.y, v1.z, v1.w};
            union { unsigned short u[8]; s16x8 s; } ph, pl;
#pragma unroll
            for (int j = 0; j < 8; ++j) {
                unsigned short h = bfbits(v[j]);
                ph.u[j] = h;
                pl.u[j] = bfbits(v[j] - bf2f(h));
            }
            bh[lf][ks] = ph.s; bl[lf][ks] = pl.s;
        }

    float bestd[2] = {3.4e38f, 3.4e38f};
    int   bestk[2] = {0, 0};
#pragma unroll 2
    for (int cf = 0; cf < 32; ++cf) {
        int code = cf * 16 + lr;
        const bf16* ph = cbh + code * 64 + kg * 8;
        const bf16* pl = cbl + code * 64 + kg * 8;
        s16x8 ah0 = *(const s16x8*)ph;
        s16x8 ah1 = *(const s16x8*)(ph + 32);
        s16x8 al0 = *(const s16x8*)pl;
        s16x8 al1 = *(const s16x8*)(pl + 32);
        float s0 = sSC[cf * 16 + kg * 4 + 0];
        float s1 = sSC[cf * 16 + kg * 4 + 1];
        float s2 = sSC[cf * 16 + kg * 4 + 2];
        float s3 = sSC[cf * 16 + kg * 4 + 3];
        int kb = cf * 16 + kg * 4;
#pragma unroll
        for (int lf = 0; lf < 2; ++lf) {
            f32x4 acc = MFMA16(ah0, bh[lf][0], zf4);
            acc = MFMA16(ah1, bh[lf][1], acc);
            acc = MFMA16(al0, bh[lf][0], acc);
            acc = MFMA16(al1, bh[lf][1], acc);
            acc = MFMA16(ah0, bl[lf][0], acc);
            acc = MFMA16(ah1, bl[lf][1], acc);
            float d0 = fmaf(acc[0], -2.f, s0);
            float d1 = fmaf(acc[1], -2.f, s1);
            float d2 = fmaf(acc[2], -2.f, s2);
            float d3 = fmaf(acc[3], -2.f, s3);
            if (d0 < bestd[lf]) { bestd[lf] = d0; bestk[lf] = kb; }
            if (d1 < bestd[lf]) { bestd[lf] = d1; bestk[lf] = kb + 1; }
            if (d2 < bestd[lf]) { bestd[lf] = d2; bestk[lf] = kb + 2; }
            if (d3 < bestd[lf]) { bestd[lf] = d3; bestk[lf] = kb + 3; }
        }
    }
#pragma unroll
    for (int lf = 0; lf < 2; ++lf) {
#pragma unroll
        for (int off = 16; off <= 32; off <<= 1) {
            float od = __shfl_xor(bestd[lf], off, 64);
            int   ok = __shfl_xor(bestk[lf], off, 64);
            if (od < bestd[lf] || (od == bestd[lf] && ok < bestk[lf])) {
                bestd[lf] = od; bestk[lf] = ok;
            }
        }
        if (kg == 0) sBK[pw0 + lf * 16 + lr] = bestk[lf];
    }
    __syncthreads();

    const int pos  = tid >> 1;
    const int half = tid & 1;
    const int k = sBK[pos];
    if (half == 0) atomicAdd(&sHist[k], 1.f);
    float lsum = 0.f;
    const float* qp = cbf + (size_t)k * 64 + half * 32;
    bf16* qo = q + (size_t)(n0 + pos) * 64 + half * 32;
#pragma unroll
    for (int c0 = 0; c0 < 32; c0 += 8) {
        int zb = (pos * 68 + half * 32 + c0) * 4;
        float4 z0 = *(const float4*)(sMem + zb);
        float4 z1 = *(const float4*)(sMem + zb + 16);
        float4 q0 = *(const float4*)(qp + c0);
        float4 q1 = *(const float4*)(qp + c0 + 4);
        float qv[8] = {q0.x, q0.y, q0.z, q0.w, q1.x, q1.y, q1.z, q1.w};
        float zv[8] = {z0.x, z0.y, z0.z, z0.w, z1.x, z1.y, z1.z, z1.w};
        union { unsigned short u[8]; s16x8 v; } pk;
#pragma unroll
        for (int j = 0; j < 8; ++j) {
            float d = qv[j] - zv[j];
            lsum = fmaf(d, d, lsum);
            pk.u[j] = bfbits(qv[j]);
        }
        *(s16x8*)(qo + c0) = pk.v;
    }
#pragma unroll
    for (int off = 32; off > 0; off >>= 1) lsum += __shfl_down(lsum, off, 64);
    if ((tid & 63) == 0) sWS[tid >> 6] = lsum;
    __syncthreads();
    if (tid == 0) atomicAdd(loss_sum, sWS[0] + sWS[1] + sWS[2] + sWS[3]);
    float c0v = sHist[tid];       if (c0v != 0.f) atomicAdd(&counts[tid], c0v);
    float c1v = sHist[tid + 256]; if (c1v != 0.f) atomicAdd(&counts[tid + 256], c1v);
}

__global__ __launch_bounds__(512) void finalize_k(
    const float* __restrict__ counts, const float* __restrict__ loss_sum,
    float* __restrict__ d_out, int out_size)
{
    __shared__ float ws2[8];
    const int tid = threadIdx.x;
    float p = counts[tid] * (1.f / 131072.f);
    float e = p * logf(p + 1e-10f);
#pragma unroll
    for (int off = 32; off > 0; off >>= 1) e += __shfl_down(e, off, 64);
    const int lane = tid & 63, wid = tid >> 6;
    if (lane == 0) ws2[wid] = e;
    __syncthreads();
    if (tid == 0) {
        float s = 0.f;
        for (int i = 0; i < 8; ++i) s += ws2[i];
        d_out[0] = 1.25f * loss_sum[0] * (1.f / 8388608.f);  // (1+BETA)*mean
        d_out[out_size - 1] = expf(-s);
    }
}

extern "C" void kernel_launch(void* const* d_in, const int* in_sizes, int n_in,
                              void* d_out, int out_size, void* d_ws, size_t ws_size,
                              hipStream_t stream)
{
    const float* x        = (const float*)d_in[0];
    const float* enc_w1   = (const float*)d_in[1];
    const float* enc_b1   = (const float*)d_in[2];
    const float* enc_b2   = (const float*)d_in[4];
    const float* enc_b3   = (const float*)d_in[6];
    const float* pre_vq_b = (const float*)d_in[12];
    const float* cb       = (const float*)d_in[13];
    const float* dec_b1   = (const float*)d_in[15];
    const float* ct1_b    = (const float*)d_in[21];
    const float* ct2_w    = (const float*)d_in[22];
    const float* ct2_b    = (const float*)d_in[23];
    float* out = (float*)d_out;

    char* base = (char*)d_ws;
    bf16*  wb   = (bf16*)base;
    bf16*  Abf  = (bf16*)(base + ((size_t)2   << 20));
    bf16*  Bbf  = (bf16*)(base + ((size_t)40  << 20));
    bf16*  Qbf  = (bf16*)(base + ((size_t)78  << 20));
    bf16*  cbh  = (bf16*)(base + ((size_t)96  << 20));
    bf16*  cbl  = (bf16*)(base + ((size_t)96  << 20) + 65536);
    float* sc   = (float*)(base + ((size_t)96  << 20) + 131072);
    float* cnt  = sc + 512;
    float* lsum = cnt + 512;

    (void)hipMemsetAsync(cnt, 0, 513 * sizeof(float), stream);

    dim3 blk(256);
    dim3 g16(16, 128);

    wx_k<<<dim3(13, 8), blk, 0, stream>>>(
        (const float*)d_in[3], (const float*)d_in[5], (const float*)d_in[7],
        (const float*)d_in[8], (const float*)d_in[9], (const float*)d_in[10],
        (const float*)d_in[11], (const float*)d_in[14], (const float*)d_in[16],
        (const float*)d_in[17], (const float*)d_in[18], (const float*)d_in[19],
        (const float*)d_in[20], wb);
    cbprep_k<<<2, blk, 0, stream>>>(cb, cbh, cbl, sc);

    enc12_k<<<g16, blk, 0, stream>>>(x, enc_w1, enc_b1, wb + 0 * 65536, enc_b2, Bbf);
    encmid_k<<<g16, blk, 0, stream>>>(Bbf, wb + 1 * 65536, enc_b3,
        wb + 2 * 65536, wb + 3 * 65536, wb + 4 * 65536, wb + 5 * 65536, Abf);

    vqf_k<<<1024, blk, 0, stream>>>(Abf, wb + 6 * 65536, pre_vq_b, cb,
                                    cbh, cbl, sc, Qbf, cnt, lsum);

    decmid_k<<<g16, blk, 0, stream>>>(Qbf, wb + 7 * 65536, dec_b1,
        wb + 8 * 65536, wb + 9 * 65536, wb + 10 * 65536, wb + 11 * 65536,
        wb + 12 * 65536, ct1_b, Bbf);

    ct2_k<<<dim3(8, 128), blk, 0, stream>>>(Bbf, ct2_w, ct2_b, out + 1);
    finalize_k<<<1, 512, 0, stream>>>(cnt, lsum, out, out_size);
}

// Round 16
// 353.327 us; speedup vs baseline: 2.0203x; 1.0035x over previous
//
#include <hip/hip_runtime.h>
#include <hip/hip_bf16.h>
#include <math.h>

using bf16 = __hip_bfloat16;
typedef __attribute__((ext_vector_type(4))) float f32x4;
typedef __attribute__((ext_vector_type(8))) short s16x8;

#define MFMA16(a,b,c) __builtin_amdgcn_mfma_f32_16x16x32_bf16((a),(b),(c),0,0,0)

// ---------------------------------------------------------------------------
// VQ-VAE forward. B=128, L=4096, H=128, RH=64, D=64, K=512.
// Round-15 inner loops + round-12 minimal halo windows, launch_bounds(256,3)
// (no VGPR squeeze). encmid 37.5KB -> 4 blocks/CU; decmid 29.4KB -> 5.
// ---------------------------------------------------------------------------

__device__ inline float bf2f(unsigned short u) {
    union { float f; unsigned v; } c; c.v = ((unsigned)u) << 16; return c.f;
}
__device__ inline unsigned short bfbits(float f) {
    union { bf16 h; unsigned short u; } c; c.h = __float2bfloat16(f); return c.u;
}
__device__ inline s16x8 relu8(s16x8 v) {
#pragma unroll
    for (int j = 0; j < 8; ++j)
        v[j] = (short)(((unsigned short)v[j] & 0x8000u) ? 0 : (unsigned short)v[j]);
    return v;
}
__device__ inline uint2 pack4(float a, float b, float c, float d) {
    uint2 p;
    p.x = (unsigned)bfbits(a) | ((unsigned)bfbits(b) << 16);
    p.y = (unsigned)bfbits(c) | ((unsigned)bfbits(d) << 16);
    return p;
}

// ===========================================================================
// encmid: enc3 (128->128 K3) + res1 + res2 + final relu.  Bbf -> Abf.
// Y row r <-> pos l0-2+r, r in [0,68). X row t <-> pos l0-3+t, t in [0,70).
// sY 68x272B @0 (18496); sX 70x272B @18496 (19040); sH 68x144B aliases sX.
// Total 37536B -> 4 blocks/CU (LDS-limited); VGPR free at bounds(256,3).
// ===========================================================================
__global__ __launch_bounds__(256, 3) void encmid_k(
    const bf16* __restrict__ in, const bf16* __restrict__ w3t,
    const float* __restrict__ b3, const bf16* __restrict__ r1w1,
    const bf16* __restrict__ r1w2, const bf16* __restrict__ r2w1,
    const bf16* __restrict__ r2w2, bf16* __restrict__ out)
{
    __shared__ __align__(16) char smem[37536];
    char* sY = smem;
    char* sX = smem + 18496;
    char* sH = smem + 18496;
    const int tid = threadIdx.x;
    const int b   = blockIdx.y;
    const int l0  = blockIdx.x * 64;
    const bf16* inb = in + (size_t)b * 1024 * 128;

    for (int i = tid; i < 70 * 16; i += 256) {
        int t = i >> 4, c0 = (i & 15) * 8;
        int g = l0 - 3 + t;
        s16x8 v = {};
        if (g >= 0 && g < 1024) v = *(const s16x8*)(inb + (size_t)g * 128 + c0);
        *(s16x8*)(sX + ((t * 136 + c0) << 1)) = v;
    }
    __syncthreads();

    const int lane = tid & 63;
    const int wid  = __builtin_amdgcn_readfirstlane(tid >> 6);
    const int lr   = lane & 15;
    const int kg   = lane >> 4;
    const f32x4 zf4 = {0.f, 0.f, 0.f, 0.f};

    // ---- phase 1: enc3 -> sY rows [0,68), bias, OOR-zero ----
    {
        const int co0 = wid * 32;
        f32x4 acc[2][5];
#pragma unroll
        for (int cf = 0; cf < 2; ++cf)
#pragma unroll
            for (int lf = 0; lf < 5; ++lf) acc[cf][lf] = zf4;
#pragma unroll
        for (int k = 0; k < 3; ++k) {
            const bf16* Ab = w3t + (size_t)k * 128 * 128;
#pragma unroll
            for (int ks = 0; ks < 4; ++ks) {
                s16x8 af[2];
#pragma unroll
                for (int cf = 0; cf < 2; ++cf)
                    af[cf] = *(const s16x8*)(Ab + (co0 + cf * 16 + lr) * 128 + ks * 32 + kg * 8);
                s16x8 bfr[5];
#pragma unroll
                for (int lf = 0; lf < 5; ++lf) {
                    int tx = lf * 16 + lr + k;         // t = r + k
                    tx = (tx > 69) ? 69 : tx;
                    bfr[lf] = *(const s16x8*)(sX + ((tx * 136 + ks * 32 + kg * 8) << 1));
                }
#pragma unroll
                for (int cf = 0; cf < 2; ++cf)
#pragma unroll
                    for (int lf = 0; lf < 5; ++lf)
                        acc[cf][lf] = MFMA16(af[cf], bfr[lf], acc[cf][lf]);
            }
        }
        __syncthreads();   // sX reads done before sH alias writes later
#pragma unroll
        for (int cf = 0; cf < 2; ++cf)
#pragma unroll
            for (int lf = 0; lf < 5; ++lf) {
                int row = lf * 16 + lr;
                if (row < 68) {
                    int p   = l0 - 2 + row;
                    int cb0 = co0 + cf * 16 + kg * 4;
                    bool ok = (p >= 0 && p < 1024);
                    float r[4];
#pragma unroll
                    for (int j = 0; j < 4; ++j)
                        r[j] = ok ? (acc[cf][lf][j] + b3[cb0 + j]) : 0.f;
                    *(uint2*)(sY + ((row * 136 + cb0) << 1)) = pack4(r[0], r[1], r[2], r[3]);
                }
            }
    }
    __syncthreads();

    // ---- phases 2..5: two res blocks ----
#pragma unroll 1
    for (int blk2 = 0; blk2 < 2; ++blk2) {
        const bf16* w1 = blk2 ? r2w1 : r1w1;
        {
            const int co0 = wid * 16;
            f32x4 acc[5];
#pragma unroll
            for (int lf = 0; lf < 5; ++lf) acc[lf] = zf4;
#pragma unroll
            for (int k = 0; k < 3; ++k) {
                const bf16* Ab = w1 + (size_t)k * 64 * 128;
#pragma unroll
                for (int ks = 0; ks < 4; ++ks) {
                    s16x8 a = *(const s16x8*)(Ab + (co0 + lr) * 128 + ks * 32 + kg * 8);
                    s16x8 bfr[5];
#pragma unroll
                    for (int lf = 0; lf < 5; ++lf) {
                        int ry = lf * 16 + lr + k - 1;
                        ry = (ry < 0) ? 0 : (ry > 67 ? 67 : ry);
                        bfr[lf] = relu8(*(const s16x8*)(sY + ((ry * 136 + ks * 32 + kg * 8) << 1)));
                    }
#pragma unroll
                    for (int lf = 0; lf < 5; ++lf)
                        acc[lf] = MFMA16(a, bfr[lf], acc[lf]);
                }
            }
#pragma unroll
            for (int lf = 0; lf < 5; ++lf) {
                int row = lf * 16 + lr;
                if (row < 68) {
                    int ch0 = co0 + kg * 4;
                    *(uint2*)(sH + ((row * 72 + ch0) << 1)) =
                        pack4(fmaxf(acc[lf][0], 0.f), fmaxf(acc[lf][1], 0.f),
                              fmaxf(acc[lf][2], 0.f), fmaxf(acc[lf][3], 0.f));
                }
            }
        }
        __syncthreads();

        if (blk2 == 0) {
            const int co0 = wid * 32;
            f32x4 acc[2][5];
#pragma unroll
            for (int cf = 0; cf < 2; ++cf)
#pragma unroll
                for (int lf = 0; lf < 5; ++lf) acc[cf][lf] = zf4;
#pragma unroll
            for (int ks = 0; ks < 2; ++ks) {
                s16x8 af[2];
#pragma unroll
                for (int cf = 0; cf < 2; ++cf)
                    af[cf] = *(const s16x8*)(r1w2 + (size_t)(co0 + cf * 16 + lr) * 64 + ks * 32 + kg * 8);
                s16x8 bfr[5];
#pragma unroll
                for (int lf = 0; lf < 5; ++lf) {
                    int row = lf * 16 + lr;
                    int rc  = (row > 67) ? 67 : row;
                    bfr[lf] = *(const s16x8*)(sH + ((rc * 72 + ks * 32 + kg * 8) << 1));
                }
#pragma unroll
                for (int cf = 0; cf < 2; ++cf)
#pragma unroll
                    for (int lf = 0; lf < 5; ++lf)
                        acc[cf][lf] = MFMA16(af[cf], bfr[lf], acc[cf][lf]);
            }
#pragma unroll
            for (int cf = 0; cf < 2; ++cf)
#pragma unroll
                for (int lf = 0; lf < 5; ++lf) {
                    int row = lf * 16 + lr;
                    if (row < 68) {
                        int p   = l0 - 2 + row;
                        int cb0 = co0 + cf * 16 + kg * 4;
                        uint2 old = *(const uint2*)(sY + ((row * 136 + cb0) << 1));
                        bool ok = (p >= 0 && p < 1024);
                        float r0 = acc[cf][lf][0] + bf2f((unsigned short)(old.x & 0xffff));
                        float r1 = acc[cf][lf][1] + bf2f((unsigned short)(old.x >> 16));
                        float r2 = acc[cf][lf][2] + bf2f((unsigned short)(old.y & 0xffff));
                        float r3 = acc[cf][lf][3] + bf2f((unsigned short)(old.y >> 16));
                        uint2 pk = pack4(r0, r1, r2, r3);
                        if (!ok) { pk.x = 0u; pk.y = 0u; }
                        *(uint2*)(sY + ((row * 136 + cb0) << 1)) = pk;
                    }
                }
            __syncthreads();
        } else {
            // final: out = relu(Y + w2*H) rows 2..65 -> global
            const int co0 = wid * 32;
            f32x4 acc[2][4];
#pragma unroll
            for (int cf = 0; cf < 2; ++cf)
#pragma unroll
                for (int lf = 0; lf < 4; ++lf) acc[cf][lf] = zf4;
#pragma unroll
            for (int ks = 0; ks < 2; ++ks) {
                s16x8 af[2];
#pragma unroll
                for (int cf = 0; cf < 2; ++cf)
                    af[cf] = *(const s16x8*)(r2w2 + (size_t)(co0 + cf * 16 + lr) * 64 + ks * 32 + kg * 8);
                s16x8 bfr[4];
#pragma unroll
                for (int lf = 0; lf < 4; ++lf) {
                    int row = 2 + lf * 16 + lr;
                    bfr[lf] = *(const s16x8*)(sH + ((row * 72 + ks * 32 + kg * 8) << 1));
                }
#pragma unroll
                for (int cf = 0; cf < 2; ++cf)
#pragma unroll
                    for (int lf = 0; lf < 4; ++lf)
                        acc[cf][lf] = MFMA16(af[cf], bfr[lf], acc[cf][lf]);
            }
#pragma unroll
            for (int cf = 0; cf < 2; ++cf)
#pragma unroll
                for (int lf = 0; lf < 4; ++lf) {
                    int row = 2 + lf * 16 + lr;
                    int cb0 = co0 + cf * 16 + kg * 4;
                    uint2 old = *(const uint2*)(sY + ((row * 136 + cb0) << 1));
                    float r0 = fmaxf(acc[cf][lf][0] + bf2f((unsigned short)(old.x & 0xffff)), 0.f);
                    float r1 = fmaxf(acc[cf][lf][1] + bf2f((unsigned short)(old.x >> 16)), 0.f);
                    float r2 = fmaxf(acc[cf][lf][2] + bf2f((unsigned short)(old.y & 0xffff)), 0.f);
                    float r3 = fmaxf(acc[cf][lf][3] + bf2f((unsigned short)(old.y >> 16)), 0.f);
                    *(uint2*)(out + ((size_t)b * 1024 + l0 + lf * 16 + lr) * 128 + cb0) =
                        pack4(r0, r1, r2, r3);
                }
        }
    }
}

// ===========================================================================
// decmid: dec1 + res1 + res2(+relu) + ct1 convT.  Qbf -> (b,2048,64) bf16.
// Y row r <-> pos l0-3+r, r in [0,70). Q row t <-> pos l0-4+t, t in [0,72).
// sY 70x272B @0 (19040); sQ 72x144B @19040 (10368); sH 70x144 aliases sQ.
// Total 29408B -> 5 blocks/CU (LDS-limited); VGPR free at bounds(256,3).
// ===========================================================================
__global__ __launch_bounds__(256, 3) void decmid_k(
    const bf16* __restrict__ qin, const bf16* __restrict__ dw1,
    const float* __restrict__ db1, const bf16* __restrict__ r1w1,
    const bf16* __restrict__ r1w2, const bf16* __restrict__ r2w1,
    const bf16* __restrict__ r2w2, const bf16* __restrict__ ct1w,
    const float* __restrict__ ct1b, bf16* __restrict__ out)
{
    __shared__ __align__(16) char smem[29408];
    char* sY = smem;
    char* sQ = smem + 19040;
    char* sH = smem + 19040;
    const int tid = threadIdx.x;
    const int b   = blockIdx.y;
    const int l0  = blockIdx.x * 64;
    const bf16* inb = qin + (size_t)b * 1024 * 64;

    for (int i = tid; i < 72 * 8; i += 256) {
        int t = i >> 3, c0 = (i & 7) * 8;
        int g = l0 - 4 + t;
        s16x8 v = {};
        if (g >= 0 && g < 1024) v = *(const s16x8*)(inb + (size_t)g * 64 + c0);
        *(s16x8*)(sQ + ((t * 72 + c0) << 1)) = v;
    }
    __syncthreads();

    const int lane = tid & 63;
    const int wid  = __builtin_amdgcn_readfirstlane(tid >> 6);
    const int lr   = lane & 15;
    const int kg   = lane >> 4;
    const f32x4 zf4 = {0.f, 0.f, 0.f, 0.f};

    // ---- phase 1: dec1 -> sY rows [0,70), bias, OOR-zero ----
    {
        const int co0 = wid * 32;
        f32x4 acc[2][5];
#pragma unroll
        for (int cf = 0; cf < 2; ++cf)
#pragma unroll
            for (int lf = 0; lf < 5; ++lf) acc[cf][lf] = zf4;
#pragma unroll
        for (int k = 0; k < 3; ++k) {
            const bf16* Ab = dw1 + (size_t)k * 128 * 64;
#pragma unroll
            for (int ks = 0; ks < 2; ++ks) {
                s16x8 af[2];
#pragma unroll
                for (int cf = 0; cf < 2; ++cf)
                    af[cf] = *(const s16x8*)(Ab + (co0 + cf * 16 + lr) * 64 + ks * 32 + kg * 8);
                s16x8 bfr[5];
#pragma unroll
                for (int lf = 0; lf < 5; ++lf) {
                    int tx = lf * 16 + lr + k;         // t = r + k
                    tx = (tx > 71) ? 71 : tx;
                    bfr[lf] = *(const s16x8*)(sQ + ((tx * 72 + ks * 32 + kg * 8) << 1));
                }
#pragma unroll
                for (int cf = 0; cf < 2; ++cf)
#pragma unroll
                    for (int lf = 0; lf < 5; ++lf)
                        acc[cf][lf] = MFMA16(af[cf], bfr[lf], acc[cf][lf]);
            }
        }
        __syncthreads();   // sQ reads complete before sH alias overwrite
#pragma unroll
        for (int cf = 0; cf < 2; ++cf)
#pragma unroll
            for (int lf = 0; lf < 5; ++lf) {
                int row = lf * 16 + lr;
                if (row < 70) {
                    int p   = l0 - 3 + row;
                    int cb0 = co0 + cf * 16 + kg * 4;
                    bool ok = (p >= 0 && p < 1024);
                    float r[4];
#pragma unroll
                    for (int j = 0; j < 4; ++j)
                        r[j] = ok ? (acc[cf][lf][j] + db1[cb0 + j]) : 0.f;
                    *(uint2*)(sY + ((row * 136 + cb0) << 1)) = pack4(r[0], r[1], r[2], r[3]);
                }
            }
    }
    __syncthreads();

    // ---- res blocks ----
#pragma unroll 1
    for (int blk2 = 0; blk2 < 2; ++blk2) {
        const bf16* w1 = blk2 ? r2w1 : r1w1;
        const bf16* w2 = blk2 ? r2w2 : r1w2;
        {
            const int co0 = wid * 16;
            f32x4 acc[5];
#pragma unroll
            for (int lf = 0; lf < 5; ++lf) acc[lf] = zf4;
#pragma unroll
            for (int k = 0; k < 3; ++k) {
                const bf16* Ab = w1 + (size_t)k * 64 * 128;
#pragma unroll
                for (int ks = 0; ks < 4; ++ks) {
                    s16x8 a = *(const s16x8*)(Ab + (co0 + lr) * 128 + ks * 32 + kg * 8);
                    s16x8 bfr[5];
#pragma unroll
                    for (int lf = 0; lf < 5; ++lf) {
                        int ry = lf * 16 + lr + k - 1;
                        ry = (ry < 0) ? 0 : (ry > 69 ? 69 : ry);
                        bfr[lf] = relu8(*(const s16x8*)(sY + ((ry * 136 + ks * 32 + kg * 8) << 1)));
                    }
#pragma unroll
                    for (int lf = 0; lf < 5; ++lf)
                        acc[lf] = MFMA16(a, bfr[lf], acc[lf]);
                }
            }
#pragma unroll
            for (int lf = 0; lf < 5; ++lf) {
                int row = lf * 16 + lr;
                if (row < 70) {
                    int ch0 = co0 + kg * 4;
                    *(uint2*)(sH + ((row * 72 + ch0) << 1)) =
                        pack4(fmaxf(acc[lf][0], 0.f), fmaxf(acc[lf][1], 0.f),
                              fmaxf(acc[lf][2], 0.f), fmaxf(acc[lf][3], 0.f));
                }
            }
        }
        __syncthreads();
        {
            const int co0 = wid * 32;
            f32x4 acc[2][5];
#pragma unroll
            for (int cf = 0; cf < 2; ++cf)
#pragma unroll
                for (int lf = 0; lf < 5; ++lf) acc[cf][lf] = zf4;
#pragma unroll
            for (int ks = 0; ks < 2; ++ks) {
                s16x8 af[2];
#pragma unroll
                for (int cf = 0; cf < 2; ++cf)
                    af[cf] = *(const s16x8*)(w2 + (size_t)(co0 + cf * 16 + lr) * 64 + ks * 32 + kg * 8);
                s16x8 bfr[5];
#pragma unroll
                for (int lf = 0; lf < 5; ++lf) {
                    int row = lf * 16 + lr;
                    int rc  = (row > 69) ? 69 : row;
                    bfr[lf] = *(const s16x8*)(sH + ((rc * 72 + ks * 32 + kg * 8) << 1));
                }
#pragma unroll
                for (int cf = 0; cf < 2; ++cf)
#pragma unroll
                    for (int lf = 0; lf < 5; ++lf)
                        acc[cf][lf] = MFMA16(af[cf], bfr[lf], acc[cf][lf]);
            }
#pragma unroll
            for (int cf = 0; cf < 2; ++cf)
#pragma unroll
                for (int lf = 0; lf < 5; ++lf) {
                    int row = lf * 16 + lr;
                    if (row < 70) {
                        int p   = l0 - 3 + row;
                        int cb0 = co0 + cf * 16 + kg * 4;
                        uint2 old = *(const uint2*)(sY + ((row * 136 + cb0) << 1));
                        bool ok = (p >= 0 && p < 1024);
                        float r0 = acc[cf][lf][0] + bf2f((unsigned short)(old.x & 0xffff));
                        float r1 = acc[cf][lf][1] + bf2f((unsigned short)(old.x >> 16));
                        float r2 = acc[cf][lf][2] + bf2f((unsigned short)(old.y & 0xffff));
                        float r3 = acc[cf][lf][3] + bf2f((unsigned short)(old.y >> 16));
                        if (blk2 == 1) {
                            r0 = fmaxf(r0, 0.f); r1 = fmaxf(r1, 0.f);
                            r2 = fmaxf(r2, 0.f); r3 = fmaxf(r3, 0.f);
                        }
                        uint2 pk = pack4(r0, r1, r2, r3);
                        if (!ok) { pk.x = 0u; pk.y = 0u; }
                        *(uint2*)(sY + ((row * 136 + cb0) << 1)) = pk;
                    }
                }
        }
        __syncthreads();
    }

    // ---- ct1 convT (CO=64): Y row for pos m+doff is m+3+doff; direct stores --
    {
        const int co0 = (wid & 1) * 32;
        const int mh  = wid >> 1;
        f32x4 acc[2][2][2];
#pragma unroll
        for (int g = 0; g < 2; ++g)
#pragma unroll
            for (int cf = 0; cf < 2; ++cf)
#pragma unroll
                for (int j = 0; j < 2; ++j) acc[g][cf][j] = zf4;
#pragma unroll
        for (int g = 0; g < 2; ++g)
#pragma unroll
            for (int k = 0; k < 2; ++k) {
                const bf16* Ab = ct1w + (size_t)(g * 2 + k) * 64 * 128;
                const int doff = (g == 0) ? (k - 1) : k;
#pragma unroll
                for (int ks = 0; ks < 4; ++ks) {
                    s16x8 af[2];
#pragma unroll
                    for (int cf = 0; cf < 2; ++cf)
                        af[cf] = *(const s16x8*)(Ab + (co0 + cf * 16 + lr) * 128 + ks * 32 + kg * 8);
                    s16x8 bfr[2];
#pragma unroll
                    for (int j = 0; j < 2; ++j) {
                        int ty = 3 + (mh * 2 + j) * 16 + lr + doff;
                        bfr[j] = *(const s16x8*)(sY + ((ty * 136 + ks * 32 + kg * 8) << 1));
                    }
#pragma unroll
                    for (int cf = 0; cf < 2; ++cf)
#pragma unroll
                        for (int j = 0; j < 2; ++j)
                            acc[g][cf][j] = MFMA16(af[cf], bfr[j], acc[g][cf][j]);
                }
            }
#pragma unroll
        for (int g = 0; g < 2; ++g)
#pragma unroll
            for (int cf = 0; cf < 2; ++cf)
#pragma unroll
                for (int j = 0; j < 2; ++j) {
                    int m   = (mh * 2 + j) * 16 + lr;
                    int cb0 = co0 + cf * 16 + kg * 4;
                    float r[4];
#pragma unroll
                    for (int jj = 0; jj < 4; ++jj)
                        r[jj] = fmaxf(acc[g][cf][j][jj] + ct1b[cb0 + jj], 0.f);
                    *(uint2*)(out + ((size_t)b * 2048 + 2 * (l0 + m) + g) * 64 + cb0) =
                        pack4(r[0], r[1], r[2], r[3]);
                }
    }
}

// Fused enc1+enc2: x fp32 -> h1 (LDS, stride 72) -> enc2 GEMM -> bf16 relu.
__global__ __launch_bounds__(256) void enc12_k(
    const float* __restrict__ x, const float* __restrict__ w1,
    const float* __restrict__ b1, const bf16* __restrict__ w2t,
    const float* __restrict__ b2, bf16* __restrict__ out)
{
    __shared__ float sXf[268];
    __shared__ float sW1[256];
    __shared__ float sB1[64];
    __shared__ __align__(16) char sX[132 * 144];
    const int tid = threadIdx.x;
    const int b   = blockIdx.y;
    const int l0  = blockIdx.x * 64;
    const float* xb = x + (size_t)b * 4096;

    for (int i = tid; i < 266; i += 256) {
        int g = 4 * l0 - 3 + i;
        sXf[i] = (g >= 0 && g < 4096) ? xb[g] : 0.f;
    }
    if (tid < 256) sW1[tid] = w1[tid];
    if (tid < 64)  sB1[tid] = b1[tid];
    __syncthreads();

    for (int i = tid; i < 132 * 64; i += 256) {
        int t = i >> 6, c = i & 63;
        int p = (t < 66) ? 2 * (l0 + t) : 2 * (l0 + t - 66) - 1;
        float v = 0.f;
        if (p >= 0 && p < 2048) {
            int xi = 2 * p - 4 * l0 + 2;
            float a = sB1[c];
#pragma unroll
            for (int k = 0; k < 4; ++k) a = fmaf(sXf[xi + k], sW1[c * 4 + k], a);
            v = fmaxf(a, 0.f);
        }
        *(bf16*)(sX + ((t * 72 + c) << 1)) = __float2bfloat16(v);
    }
    __syncthreads();

    const int lane = tid & 63;
    const int wid  = __builtin_amdgcn_readfirstlane(tid >> 6);
    const int co0  = wid * 32;
    const int lr   = lane & 15;
    const int kg   = lane >> 4;

    f32x4 acc[2][4];
#pragma unroll
    for (int cf = 0; cf < 2; ++cf)
#pragma unroll
        for (int lf = 0; lf < 4; ++lf) acc[cf][lf] = (f32x4){0.f, 0.f, 0.f, 0.f};

#pragma unroll
    for (int k = 0; k < 4; ++k) {
        const int roff = (k == 0) ? 66 : (k == 1) ? 0 : (k == 2) ? 67 : 1;
        const bf16* Ab = w2t + (size_t)k * 128 * 64;
#pragma unroll
        for (int ks = 0; ks < 2; ++ks) {
            s16x8 af[2];
#pragma unroll
            for (int cf = 0; cf < 2; ++cf)
                af[cf] = *(const s16x8*)(Ab + (co0 + cf * 16 + lr) * 64 + ks * 32 + kg * 8);
            s16x8 bfr[4];
#pragma unroll
            for (int lf = 0; lf < 4; ++lf) {
                int t = roff + lf * 16 + lr;
                bfr[lf] = *(const s16x8*)(sX + ((t * 72 + ks * 32 + kg * 8) << 1));
            }
#pragma unroll
            for (int cf = 0; cf < 2; ++cf)
#pragma unroll
                for (int lf = 0; lf < 4; ++lf)
                    acc[cf][lf] = MFMA16(af[cf], bfr[lf], acc[cf][lf]);
        }
    }

#pragma unroll
    for (int cf = 0; cf < 2; ++cf)
#pragma unroll
        for (int lf = 0; lf < 4; ++lf) {
            int cb0  = co0 + cf * 16 + kg * 4;
            int lcol = lf * 16 + lr;
            float r[4];
#pragma unroll
            for (int j = 0; j < 4; ++j)
                r[j] = fmaxf(acc[cf][lf][j] + b2[cb0 + j], 0.f);
            *(uint2*)(out + ((size_t)b * 1024 + l0 + lcol) * 128 + cb0) =
                pack4(r[0], r[1], r[2], r[3]);
        }
}

// Final convT: 64->1 ch, x2 upsample; fp32 out.
__global__ __launch_bounds__(256) void ct2_k(
    const bf16* __restrict__ in, const float* __restrict__ w,
    const float* __restrict__ bias, float* __restrict__ out)
{
    __shared__ __align__(16) char sX[258 * 144];
    const int tid = threadIdx.x;
    const int b   = blockIdx.y;
    const int m0  = blockIdx.x * 256;
    const bf16* inb = in + (size_t)b * 2048 * 64;
    for (int i = tid; i < 258 * 8; i += 256) {
        int t = i >> 3, c0 = (i & 7) * 8;
        int g = m0 - 1 + t;
        s16x8 v = {};
        if (g >= 0 && g < 2048) v = *(const s16x8*)(inb + (size_t)g * 64 + c0);
        *(s16x8*)(sX + ((t * 72 + c0) << 1)) = v;
    }
    __syncthreads();
    float e = bias[0], o = bias[0];
#pragma unroll
    for (int c0 = 0; c0 < 64; c0 += 8) {
        s16x8 vm1 = *(const s16x8*)(sX + (((tid + 0) * 72 + c0) << 1));
        s16x8 v0  = *(const s16x8*)(sX + (((tid + 1) * 72 + c0) << 1));
        s16x8 vp1 = *(const s16x8*)(sX + (((tid + 2) * 72 + c0) << 1));
#pragma unroll
        for (int j = 0; j < 8; ++j) {
            int ci = c0 + j;
            float xm1 = bf2f((unsigned short)vm1[j]);
            float x0  = bf2f((unsigned short)v0[j]);
            float xp1 = bf2f((unsigned short)vp1[j]);
            e = fmaf(x0,  w[ci * 4 + 1], fmaf(xm1, w[ci * 4 + 3], e));
            o = fmaf(xp1, w[ci * 4 + 0], fmaf(x0,  w[ci * 4 + 2], o));
        }
    }
    int m = m0 + tid;
    out[(size_t)b * 4096 + 2 * m]     = e;
    out[(size_t)b * 4096 + 2 * m + 1] = o;
}

// Weight transform: fp32 conv weights -> bf16 [tap][co][ci] matrices.
__global__ __launch_bounds__(256) void wx_k(
    const float* ew2, const float* ew3, const float* er1a, const float* er1b,
    const float* er2a, const float* er2b, const float* pvw, const float* dw1,
    const float* dr1a, const float* dr1b, const float* dr2a, const float* dr2b,
    const float* ct1w, bf16* wb)
{
    const int job = blockIdx.x;
    bf16* dst = wb + (size_t)job * 65536;
    const float* src; int CO, CI, K;
    switch (job) {
        case 0:  src = ew2;  CO = 128; CI = 64;  K = 4; break;
        case 1:  src = ew3;  CO = 128; CI = 128; K = 3; break;
        case 2:  src = er1a; CO = 64;  CI = 128; K = 3; break;
        case 3:  src = er1b; CO = 128; CI = 64;  K = 1; break;
        case 4:  src = er2a; CO = 64;  CI = 128; K = 3; break;
        case 5:  src = er2b; CO = 128; CI = 64;  K = 1; break;
        case 6:  src = pvw;  CO = 64;  CI = 128; K = 1; break;
        case 7:  src = dw1;  CO = 128; CI = 64;  K = 3; break;
        case 8:  src = dr1a; CO = 64;  CI = 128; K = 3; break;
        case 9:  src = dr1b; CO = 128; CI = 64;  K = 1; break;
        case 10: src = dr2a; CO = 64;  CI = 128; K = 3; break;
        case 11: src = dr2b; CO = 128; CI = 64;  K = 1; break;
        default: src = ct1w; CO = 64;  CI = 128; K = 4; break;
    }
    const int tot = CO * CI * K;
    for (int i = blockIdx.y * 256 + threadIdx.x; i < tot; i += gridDim.y * 256) {
        if (job < 12) {
            int k = i / (CO * CI); int r = i - k * CO * CI;
            int co = r / CI; int ci = r - co * CI;
            dst[i] = __float2bfloat16(src[((size_t)co * CI + ci) * K + k]);
        } else {
            const int TAP[4] = {3, 1, 2, 0};
            int g = i / (64 * 128); int r = i - g * 64 * 128;
            int co = r / 128; int ci = r - co * 128;
            dst[i] = __float2bfloat16(src[((size_t)ci * 64 + co) * 4 + TAP[g]]);
        }
    }
}

// codebook prep: fp32 norms + hi/lo bf16 split
__global__ __launch_bounds__(256) void cbprep_k(
    const float* __restrict__ cb, bf16* __restrict__ cbh, bf16* __restrict__ cbl,
    float* __restrict__ sc)
{
    int k = blockIdx.x * 256 + threadIdx.x;
    const float* c = cb + (size_t)k * 64;
    float s = 0.f;
#pragma unroll
    for (int d = 0; d < 64; ++d) s = fmaf(c[d], c[d], s);
    sc[k] = s;
#pragma unroll
    for (int c0 = 0; c0 < 64; c0 += 8) {
        union { unsigned short u[8]; s16x8 v; } ph, pl;
#pragma unroll
        for (int j = 0; j < 8; ++j) {
            float v = c[c0 + j];
            unsigned short h = bfbits(v);
            ph.u[j] = h;
            pl.u[j] = bfbits(v - bf2f(h));
        }
        *(s16x8*)(cbh + (size_t)k * 64 + c0) = ph.v;
        *(s16x8*)(cbl + (size_t)k * 64 + c0) = pl.v;
    }
}

// Fused pre_vq + VQ. 1024 blocks x 128 positions. A tile / z tile alias.
__global__ __launch_bounds__(256, 4) void vqf_k(
    const bf16* __restrict__ A, const bf16* __restrict__ pvw,
    const float* __restrict__ pvb, const float* __restrict__ cbf,
    const bf16* __restrict__ cbh, const bf16* __restrict__ cbl,
    const float* __restrict__ sc, bf16* __restrict__ q,
    float* __restrict__ counts, float* __restrict__ loss_sum)
{
    __shared__ __align__(16) char sMem[34816];
    __shared__ float sSC[512];
    __shared__ float sHist[512];
    __shared__ int   sBK[128];
    __shared__ float sWS[4];
    const int tid = threadIdx.x;
    sSC[tid] = sc[tid]; sSC[tid + 256] = sc[tid + 256];
    sHist[tid] = 0.f;   sHist[tid + 256] = 0.f;

    const int n0 = blockIdx.x * 128;
    for (int i = tid; i < 128 * 16; i += 256) {
        int t = i >> 4, c0 = (i & 15) * 8;
        s16x8 v = *(const s16x8*)(A + (size_t)(n0 + t) * 128 + c0);
        *(s16x8*)(sMem + ((t * 136 + c0) << 1)) = v;
    }
    __syncthreads();

    const int lane = tid & 63, wid = tid >> 6;
    const int lr = lane & 15, kg = lane >> 4;
    const int pw0 = wid * 32;
    const f32x4 zf4 = {0.f, 0.f, 0.f, 0.f};

    f32x4 zacc[4][2];
#pragma unroll
    for (int cf = 0; cf < 4; ++cf)
#pragma unroll
        for (int lf = 0; lf < 2; ++lf) zacc[cf][lf] = zf4;
#pragma unroll
    for (int ks = 0; ks < 4; ++ks) {
        s16x8 af[4];
#pragma unroll
        for (int cf = 0; cf < 4; ++cf)
            af[cf] = *(const s16x8*)(pvw + (size_t)(cf * 16 + lr) * 128 + ks * 32 + kg * 8);
        s16x8 bfr[2];
#pragma unroll
        for (int lf = 0; lf < 2; ++lf) {
            int t = pw0 + lf * 16 + lr;
            bfr[lf] = *(const s16x8*)(sMem + ((t * 136 + ks * 32 + kg * 8) << 1));
        }
#pragma unroll
        for (int cf = 0; cf < 4; ++cf)
#pragma unroll
            for (int lf = 0; lf < 2; ++lf)
                zacc[cf][lf] = MFMA16(af[cf], bfr[lf], zacc[cf][lf]);
    }
    __syncthreads();

#pragma unroll
    for (int cf = 0; cf < 4; ++cf)
#pragma unroll
        for (int lf = 0; lf < 2; ++lf) {
            int pos = pw0 + lf * 16 + lr;
            int ch  = cf * 16 + kg * 4;
            float4 v = make_float4(zacc[cf][lf][0] + pvb[ch],
                                   zacc[cf][lf][1] + pvb[ch + 1],
                                   zacc[cf][lf][2] + pvb[ch + 2],
                                   zacc[cf][lf][3] + pvb[ch + 3]);
            *(float4*)(sMem + (pos * 68 + ch) * 4) = v;
        }
    __syncthreads();

    s16x8 bh[2][2], bl[2][2];
#pragma unroll
    for (int lf = 0; lf < 2; ++lf)
#pragma unroll
        for (int ks = 0; ks < 2; ++ks) {
            int t = pw0 + lf * 16 + lr;
            int ch = ks * 32 + kg * 8;
            float4 v0 = *(const float4*)(sMem + (t * 68 + ch) * 4);
            float4 v1 = *(const float4*)(sMem + (t * 68 + ch) * 4 + 16);
            float v[8] = {v0.x, v0.y, v0.z, v0.w, v1.x, v1.y, v1.z, v1.w};
            union { unsigned short u[8]; s16x8 s; } ph, pl;
#pragma unroll
            for (int j = 0; j < 8; ++j) {
                unsigned short h = bfbits(v[j]);
                ph.u[j] = h;
                pl.u[j] = bfbits(v[j] - bf2f(h));
            }
            bh[lf][ks] = ph.s; bl[lf][ks] = pl.s;
        }

    float bestd[2] = {3.4e38f, 3.4e38f};
    int   bestk[2] = {0, 0};
#pragma unroll 2
    for (int cf = 0; cf < 32; ++cf) {
        int code = cf * 16 + lr;
        const bf16* ph = cbh + code * 64 + kg * 8;
        const bf16* pl = cbl + code * 64 + kg * 8;
        s16x8 ah0 = *(const s16x8*)ph;
        s16x8 ah1 = *(const s16x8*)(ph + 32);
        s16x8 al0 = *(const s16x8*)pl;
        s16x8 al1 = *(const s16x8*)(pl + 32);
        float s0 = sSC[cf * 16 + kg * 4 + 0];
        float s1 = sSC[cf * 16 + kg * 4 + 1];
        float s2 = sSC[cf * 16 + kg * 4 + 2];
        float s3 = sSC[cf * 16 + kg * 4 + 3];
        int kb = cf * 16 + kg * 4;
#pragma unroll
        for (int lf = 0; lf < 2; ++lf) {
            f32x4 acc = MFMA16(ah0, bh[lf][0], zf4);
            acc = MFMA16(ah1, bh[lf][1], acc);
            acc = MFMA16(al0, bh[lf][0], acc);
            acc = MFMA16(al1, bh[lf][1], acc);
            acc = MFMA16(ah0, bl[lf][0], acc);
            acc = MFMA16(ah1, bl[lf][1], acc);
            float d0 = fmaf(acc[0], -2.f, s0);
            float d1 = fmaf(acc[1], -2.f, s1);
            float d2 = fmaf(acc[2], -2.f, s2);
            float d3 = fmaf(acc[3], -2.f, s3);
            if (d0 < bestd[lf]) { bestd[lf] = d0; bestk[lf] = kb; }
            if (d1 < bestd[lf]) { bestd[lf] = d1; bestk[lf] = kb + 1; }
            if (d2 < bestd[lf]) { bestd[lf] = d2; bestk[lf] = kb + 2; }
            if (d3 < bestd[lf]) { bestd[lf] = d3; bestk[lf] = kb + 3; }
        }
    }
#pragma unroll
    for (int lf = 0; lf < 2; ++lf) {
#pragma unroll
        for (int off = 16; off <= 32; off <<= 1) {
            float od = __shfl_xor(bestd[lf], off, 64);
            int   ok = __shfl_xor(bestk[lf], off, 64);
            if (od < bestd[lf] || (od == bestd[lf] && ok < bestk[lf])) {
                bestd[lf] = od; bestk[lf] = ok;
            }
        }
        if (kg == 0) sBK[pw0 + lf * 16 + lr] = bestk[lf];
    }
    __syncthreads();

    const int pos  = tid >> 1;
    const int half = tid & 1;
    const int k = sBK[pos];
    if (half == 0) atomicAdd(&sHist[k], 1.f);
    float lsum = 0.f;
    const float* qp = cbf + (size_t)k * 64 + half * 32;
    bf16* qo = q + (size_t)(n0 + pos) * 64 + half * 32;
#pragma unroll
    for (int c0 = 0; c0 < 32; c0 += 8) {
        int zb = (pos * 68 + half * 32 + c0) * 4;
        float4 z0 = *(const float4*)(sMem + zb);
        float4 z1 = *(const float4*)(sMem + zb + 16);
        float4 q0 = *(const float4*)(qp + c0);
        float4 q1 = *(const float4*)(qp + c0 + 4);
        float qv[8] = {q0.x, q0.y, q0.z, q0.w, q1.x, q1.y, q1.z, q1.w};
        float zv[8] = {z0.x, z0.y, z0.z, z0.w, z1.x, z1.y, z1.z, z1.w};
        union { unsigned short u[8]; s16x8 v; } pk;
#pragma unroll
        for (int j = 0; j < 8; ++j) {
            float d = qv[j] - zv[j];
            lsum = fmaf(d, d, lsum);
            pk.u[j] = bfbits(qv[j]);
        }
        *(s16x8*)(qo + c0) = pk.v;
    }
#pragma unroll
    for (int off = 32; off > 0; off >>= 1) lsum += __shfl_down(lsum, off, 64);
    if ((tid & 63) == 0) sWS[tid >> 6] = lsum;
    __syncthreads();
    if (tid == 0) atomicAdd(loss_sum, sWS[0] + sWS[1] + sWS[2] + sWS[3]);
    float c0v = sHist[tid];       if (c0v != 0.f) atomicAdd(&counts[tid], c0v);
    float c1v = sHist[tid + 256]; if (c1v != 0.f) atomicAdd(&counts[tid + 256], c1v);
}

__global__ __launch_bounds__(512) void finalize_k(
    const float* __restrict__ counts, const float* __restrict__ loss_sum,
    float* __restrict__ d_out, int out_size)
{
    __shared__ float ws2[8];
    const int tid = threadIdx.x;
    float p = counts[tid] * (1.f / 131072.f);
    float e = p * logf(p + 1e-10f);
#pragma unroll
    for (int off = 32; off > 0; off >>= 1) e += __shfl_down(e, off, 64);
    const int lane = tid & 63, wid = tid >> 6;
    if (lane == 0) ws2[wid] = e;
    __syncthreads();
    if (tid == 0) {
        float s = 0.f;
        for (int i = 0; i < 8; ++i) s += ws2[i];
        d_out[0] = 1.25f * loss_sum[0] * (1.f / 8388608.f);  // (1+BETA)*mean
        d_out[out_size - 1] = expf(-s);
    }
}

extern "C" void kernel_launch(void* const* d_in, const int* in_sizes, int n_in,
                              void* d_out, int out_size, void* d_ws, size_t ws_size,
                              hipStream_t stream)
{
    const float* x        = (const float*)d_in[0];
    const float* enc_w1   = (const float*)d_in[1];
    const float* enc_b1   = (const float*)d_in[2];
    const float* enc_b2   = (const float*)d_in[4];
    const float* enc_b3   = (const float*)d_in[6];
    const float* pre_vq_b = (const float*)d_in[12];
    const float* cb       = (const float*)d_in[13];
    const float* dec_b1   = (const float*)d_in[15];
    const float* ct1_b    = (const float*)d_in[21];
    const float* ct2_w    = (const float*)d_in[22];
    const float* ct2_b    = (const float*)d_in[23];
    float* out = (float*)d_out;

    char* base = (char*)d_ws;
    bf16*  wb   = (bf16*)base;
    bf16*  Abf  = (bf16*)(base + ((size_t)2   << 20));
    bf16*  Bbf  = (bf16*)(base + ((size_t)40  << 20));
    bf16*  Qbf  = (bf16*)(base + ((size_t)78  << 20));
    bf16*  cbh  = (bf16*)(base + ((size_t)96  << 20));
    bf16*  cbl  = (bf16*)(base + ((size_t)96  << 20) + 65536);
    float* sc   = (float*)(base + ((size_t)96  << 20) + 131072);
    float* cnt  = sc + 512;
    float* lsum = cnt + 512;

    (void)hipMemsetAsync(cnt, 0, 513 * sizeof(float), stream);

    dim3 blk(256);
    dim3 g16(16, 128);

    wx_k<<<dim3(13, 8), blk, 0, stream>>>(
        (const float*)d_in[3], (const float*)d_in[5], (const float*)d_in[7],
        (const float*)d_in[8], (const float*)d_in[9], (const float*)d_in[10],
        (const float*)d_in[11], (const float*)d_in[14], (const float*)d_in[16],
        (const float*)d_in[17], (const float*)d_in[18], (const float*)d_in[19],
        (const float*)d_in[20], wb);
    cbprep_k<<<2, blk, 0, stream>>>(cb, cbh, cbl, sc);

    enc12_k<<<g16, blk, 0, stream>>>(x, enc_w1, enc_b1, wb + 0 * 65536, enc_b2, Bbf);
    encmid_k<<<g16, blk, 0, stream>>>(Bbf, wb + 1 * 65536, enc_b3,
        wb + 2 * 65536, wb + 3 * 65536, wb + 4 * 65536, wb + 5 * 65536, Abf);

    vqf_k<<<1024, blk, 0, stream>>>(Abf, wb + 6 * 65536, pre_vq_b, cb,
                                    cbh, cbl, sc, Qbf, cnt, lsum);

    decmid_k<<<g16, blk, 0, stream>>>(Qbf, wb + 7 * 65536, dec_b1,
        wb + 8 * 65536, wb + 9 * 65536, wb + 10 * 65536, wb + 11 * 65536,
        wb + 12 * 65536, ct1_b, Bbf);

    ct2_k<<<dim3(8, 128), blk, 0, stream>>>(Bbf, ct2_w, ct2_b, out + 1);
    finalize_k<<<1, 512, 0, stream>>>(cnt, lsum, out, out_size);
}